// Round 5
// baseline (1194.063 us; speedup 1.0000x reference)
//
#include <hip/hip_runtime.h>
#include <math.h>

#define NN 100000
#define EE 1600000
#define BB 64
#define FF 16
#define HH 128
#define GG 8
#define K0 19
#define BN_EPS 1e-5f
#define PCH 16

__device__ __forceinline__ float elu01f(float v) {
    return v > 0.f ? v : 0.1f * (__expf(v) - 1.f);
}

// ---------------- CSR build ----------------
// 4 edges/thread: 4 independent atomic chains in flight (latency-bound kernel)
__global__ __launch_bounds__(256) void k_count(const int* __restrict__ dst, int* __restrict__ cnt) {
    int base = (blockIdx.x * 256 + threadIdx.x) * 4;
    if (base + 3 < EE) {
        int4 d = *(const int4*)(dst + base);
        atomicAdd(&cnt[d.x], 1);
        atomicAdd(&cnt[d.y], 1);
        atomicAdd(&cnt[d.z], 1);
        atomicAdd(&cnt[d.w], 1);
    } else {
        for (int e = base; e < EE; ++e) atomicAdd(&cnt[dst[e]], 1);
    }
}

__global__ __launch_bounds__(256) void k_scan1(const int* __restrict__ cnt, int* __restrict__ excl,
                                               int* __restrict__ bsums) {
    __shared__ int sd[256];
    int tid = threadIdx.x;
    int base = blockIdx.x * 1024 + tid * 4;
    int v0 = 0, v1 = 0, v2 = 0, v3 = 0;
    if (base + 0 < NN) v0 = cnt[base + 0];
    if (base + 1 < NN) v1 = cnt[base + 1];
    if (base + 2 < NN) v2 = cnt[base + 2];
    if (base + 3 < NN) v3 = cnt[base + 3];
    sd[tid] = v0 + v1 + v2 + v3;
    __syncthreads();
    for (int off = 1; off < 256; off <<= 1) {
        int t = (tid >= off) ? sd[tid - off] : 0;
        __syncthreads();
        sd[tid] += t;
        __syncthreads();
    }
    if (tid == 255) bsums[blockIdx.x] = sd[255];
    int run = (tid > 0) ? sd[tid - 1] : 0;
    if (base + 0 < NN) { excl[base + 0] = run; run += v0; }
    if (base + 1 < NN) { excl[base + 1] = run; run += v1; }
    if (base + 2 < NN) { excl[base + 2] = run; run += v2; }
    if (base + 3 < NN) { excl[base + 3] = run; }
}

__global__ void k_scan2(int* bsums, int nb) {
    __shared__ int sd[128];
    int t = threadIdx.x;
    int v = (t < nb) ? bsums[t] : 0;
    sd[t] = v;
    __syncthreads();
    for (int off = 1; off < 128; off <<= 1) {
        int u = (t >= off) ? sd[t - off] : 0;
        __syncthreads();
        sd[t] += u;
        __syncthreads();
    }
    if (t < nb) bsums[t] = (t > 0) ? sd[t - 1] : 0;
}

__global__ __launch_bounds__(256) void k_scan3(const int* __restrict__ excl, const int* __restrict__ bsums,
                                               int* __restrict__ rp, int* __restrict__ cur) {
    int i = blockIdx.x * 256 + threadIdx.x;
    if (i < NN) {
        int v = excl[i] + bsums[i >> 10];
        rp[i] = v; cur[i] = v;
    }
    if (i == 0) rp[NN] = EE;
}

__global__ __launch_bounds__(256) void k_scatter(const int* __restrict__ srcA, const int* __restrict__ dstA,
                                                 int* __restrict__ cur, int* __restrict__ srcs) {
    int base = (blockIdx.x * 256 + threadIdx.x) * 4;
    if (base + 3 < EE) {
        int4 s = *(const int4*)(srcA + base);
        int4 d = *(const int4*)(dstA + base);
        int p0 = atomicAdd(&cur[d.x], 1);
        int p1 = atomicAdd(&cur[d.y], 1);
        int p2 = atomicAdd(&cur[d.z], 1);
        int p3 = atomicAdd(&cur[d.w], 1);
        srcs[p0] = s.x;
        srcs[p1] = s.y;
        srcs[p2] = s.z;
        srcs[p3] = s.w;
    } else {
        for (int e = base; e < EE; ++e) {
            int pos = atomicAdd(&cur[dstA[e]], 1);
            srcs[pos] = srcA[e];
        }
    }
}

// graph boundaries via binary search on sorted batch
__global__ void k_gptr(const int* __restrict__ batch, int* __restrict__ gptr) {
    int t = threadIdx.x;
    if (t > BB) return;
    int lo = 0, hi = NN;
    while (lo < hi) { int mid = (lo + hi) >> 1; if (batch[mid] < t) lo = mid + 1; else hi = mid; }
    gptr[t] = lo;
}

// ---------------- feature build + aggregation ----------------
__global__ __launch_bounds__(256) void k_buildx0(const float* __restrict__ h0, const float* __restrict__ coord,
                                                 float* __restrict__ x0) {
    int i = blockIdx.x * 256 + threadIdx.x;
    if (i >= NN * K0) return;
    int node = i / K0, k = i - node * K0;
    x0[i] = (k < FF) ? h0[node * FF + k] : coord[node * 3 + (k - FF)];
}

__global__ __launch_bounds__(256) void k_agg_small(const float* __restrict__ x, const int* __restrict__ rp,
                                                   const int* __restrict__ srcs, float* __restrict__ y) {
    int w = (blockIdx.x * 256 + threadIdx.x) >> 6;
    int lane = threadIdx.x & 63;
    if (w >= NN) return;
    int beg = rp[w], end = rp[w + 1];
    bool act = lane < K0;
    size_t li = act ? (size_t)lane : 0;
    float acc0 = 0.f, acc1 = 0.f;
    if (act) acc0 = x[(size_t)w * K0 + li];
    int p = beg;
    for (; p + 8 <= end; p += 8) {
        int s0 = srcs[p + 0], s1 = srcs[p + 1], s2 = srcs[p + 2], s3 = srcs[p + 3];
        int s4 = srcs[p + 4], s5 = srcs[p + 5], s6 = srcs[p + 6], s7 = srcs[p + 7];
        float v0 = x[(size_t)s0 * K0 + li];
        float v1 = x[(size_t)s1 * K0 + li];
        float v2 = x[(size_t)s2 * K0 + li];
        float v3 = x[(size_t)s3 * K0 + li];
        float v4 = x[(size_t)s4 * K0 + li];
        float v5 = x[(size_t)s5 * K0 + li];
        float v6 = x[(size_t)s6 * K0 + li];
        float v7 = x[(size_t)s7 * K0 + li];
        acc0 += (v0 + v1) + (v2 + v3);
        acc1 += (v4 + v5) + (v6 + v7);
    }
    for (; p < end; ++p) {
        int sn = srcs[p];
        acc0 += x[(size_t)sn * K0 + li];
    }
    if (act) y[(size_t)w * K0 + lane] = acc0 + acc1;
}

__global__ __launch_bounds__(256) void k_agg128(const float* __restrict__ x, const int* __restrict__ rp,
                                                const int* __restrict__ srcs, float* __restrict__ y) {
    int w = (blockIdx.x * 256 + threadIdx.x) >> 6;
    int lane = threadIdx.x & 63;
    if (w >= NN) return;
    const float2* x2 = (const float2*)x;
    float2* y2 = (float2*)y;
    int beg = rp[w], end = rp[w + 1];
    float2 a0 = x2[(size_t)w * 64 + lane];
    float2 a1 = {0.f, 0.f};
    int p = beg;
    for (; p + 8 <= end; p += 8) {
        int s0 = srcs[p + 0], s1 = srcs[p + 1], s2 = srcs[p + 2], s3 = srcs[p + 3];
        int s4 = srcs[p + 4], s5 = srcs[p + 5], s6 = srcs[p + 6], s7 = srcs[p + 7];
        float2 v0 = x2[(size_t)s0 * 64 + lane];
        float2 v1 = x2[(size_t)s1 * 64 + lane];
        float2 v2 = x2[(size_t)s2 * 64 + lane];
        float2 v3 = x2[(size_t)s3 * 64 + lane];
        float2 v4 = x2[(size_t)s4 * 64 + lane];
        float2 v5 = x2[(size_t)s5 * 64 + lane];
        float2 v6 = x2[(size_t)s6 * 64 + lane];
        float2 v7 = x2[(size_t)s7 * 64 + lane];
        a0.x += (v0.x + v1.x) + (v2.x + v3.x);
        a0.y += (v0.y + v1.y) + (v2.y + v3.y);
        a1.x += (v4.x + v5.x) + (v6.x + v7.x);
        a1.y += (v4.y + v5.y) + (v6.y + v7.y);
    }
    for (; p < end; ++p) {
        int sn = srcs[p];
        float2 v = x2[(size_t)sn * 64 + lane];
        a0.x += v.x; a0.y += v.y;
    }
    a0.x += a1.x; a0.y += a1.y;
    y2[(size_t)w * 64 + lane] = a0;
}

// ---------------- GEMM K=19 (layer-0 first MLP): 32 rows x 128 cols ----------------
template<int K, bool STATS>
__global__ __launch_bounds__(256) void k_gemm_small(const float* __restrict__ in, const float* __restrict__ W,
        const float* __restrict__ bias, float* __restrict__ out, float* __restrict__ ssum, float* __restrict__ ssq) {
    constexpr int SK = ((K + 3) / 4) * 4 + 4;
    __shared__ __align__(16) float yt[32 * SK];
    __shared__ float red[256];
    int tid = threadIdx.x;
    int row0 = blockIdx.x * 32;
    for (int t = tid; t < 32 * SK; t += 256) {
        int r = t / SK, k = t - r * SK;
        float v = 0.f;
        if (k < K) v = in[(size_t)(row0 + r) * K + k];
        yt[t] = v;
    }
    __syncthreads();
    int col = tid & 127;
    int rg = tid >> 7;
    float acc[16];
    #pragma unroll
    for (int r = 0; r < 16; r++) acc[r] = 0.f;
    const float* ybase = &yt[rg * 16 * SK];
    int kk = 0;
    for (; kk + 4 <= K; kk += 4) {
        float w0 = W[(kk + 0) * HH + col];
        float w1 = W[(kk + 1) * HH + col];
        float w2 = W[(kk + 2) * HH + col];
        float w3 = W[(kk + 3) * HH + col];
        #pragma unroll
        for (int r = 0; r < 16; r++) {
            const float4 v = *(const float4*)&ybase[r * SK + kk];
            acc[r] = fmaf(v.x, w0, acc[r]);
            acc[r] = fmaf(v.y, w1, acc[r]);
            acc[r] = fmaf(v.z, w2, acc[r]);
            acc[r] = fmaf(v.w, w3, acc[r]);
        }
    }
    if constexpr (K % 4 != 0) {
        float w[4];
        #pragma unroll
        for (int j = 0; j < 4; j++) w[j] = (kk + j < K) ? W[(kk + j) * HH + col] : 0.f;
        #pragma unroll
        for (int r = 0; r < 16; r++) {
            const float4 v = *(const float4*)&ybase[r * SK + kk];
            acc[r] = fmaf(v.x, w[0], acc[r]);
            acc[r] = fmaf(v.y, w[1], acc[r]);
            acc[r] = fmaf(v.z, w[2], acc[r]);
            acc[r] = fmaf(v.w, w[3], acc[r]);
        }
    }
    float bcol = bias[col];
    float s = 0.f, s2 = 0.f;
    #pragma unroll
    for (int r = 0; r < 16; r++) {
        float hv = acc[r] + bcol;
        out[(size_t)(row0 + rg * 16 + r) * HH + col] = hv;
        if (STATS) { s += hv; s2 = fmaf(hv, hv, s2); }
    }
    if (STATS) {
        red[tid] = s; __syncthreads();
        if (tid < 128) atomicAdd(&ssum[col], s + red[tid + 128]);
        __syncthreads();
        red[tid] = s2; __syncthreads();
        if (tid < 128) atomicAdd(&ssq[col], s2 + red[tid + 128]);
    }
}

// ---------------- GEMM K=128: 32 rows x 128 cols, 4x4 micro-tile/thread ----------------
template<bool STATS, bool BNIN, bool ELUOUT>
__global__ __launch_bounds__(256) void k_gemm128(const float* __restrict__ in, const float* __restrict__ W,
        const float* __restrict__ bias, const float* __restrict__ bnscale, const float* __restrict__ bnshift,
        float* __restrict__ out, float* __restrict__ ssum, float* __restrict__ ssq) {
    __shared__ __align__(16) float At[32 * 132];
    __shared__ float lsum[HH], lsq[HH];
    int tid = threadIdx.x;
    size_t row0 = (size_t)blockIdx.x * 32;
    if (STATS && tid < HH) { lsum[tid] = 0.f; lsq[tid] = 0.f; }
    // stage A tile (with optional BN+ReLU transform)
    {
        int r = tid >> 3;
        int kb = (tid & 7) * 16;
        const float4* s4 = (const float4*)(in + (row0 + r) * HH + kb);
        #pragma unroll
        for (int j = 0; j < 4; j++) {
            float4 v = s4[j];
            if (BNIN) {
                const float4 sc = *(const float4*)(bnscale + kb + j * 4);
                const float4 sh = *(const float4*)(bnshift + kb + j * 4);
                v.x = fmaxf(fmaf(v.x, sc.x, sh.x), 0.f);
                v.y = fmaxf(fmaf(v.y, sc.y, sh.y), 0.f);
                v.z = fmaxf(fmaf(v.z, sc.z, sh.z), 0.f);
                v.w = fmaxf(fmaf(v.w, sc.w, sh.w), 0.f);
            }
            *(float4*)(&At[r * 132 + kb + j * 4]) = v;
        }
    }
    __syncthreads();
    int colg = tid & 31, rowg = tid >> 5;
    int col0 = colg * 4;
    int r0 = rowg * 4;
    float acc[4][4];
    #pragma unroll
    for (int r = 0; r < 4; r++)
        #pragma unroll
        for (int c = 0; c < 4; c++) acc[r][c] = 0.f;
    const float* Abase = &At[r0 * 132];
    for (int k = 0; k < HH; k += 4) {
        float a_[4][4];
        #pragma unroll
        for (int r = 0; r < 4; r++) {
            float4 av = *(const float4*)(Abase + r * 132 + k);
            a_[r][0] = av.x; a_[r][1] = av.y; a_[r][2] = av.z; a_[r][3] = av.w;
        }
        #pragma unroll
        for (int j = 0; j < 4; j++) {
            float4 w = *(const float4*)(W + (size_t)(k + j) * HH + col0);
            #pragma unroll
            for (int r = 0; r < 4; r++) {
                acc[r][0] = fmaf(a_[r][j], w.x, acc[r][0]);
                acc[r][1] = fmaf(a_[r][j], w.y, acc[r][1]);
                acc[r][2] = fmaf(a_[r][j], w.z, acc[r][2]);
                acc[r][3] = fmaf(a_[r][j], w.w, acc[r][3]);
            }
        }
    }
    float4 bv = *(const float4*)(bias + col0);
    float s[4] = {0.f, 0.f, 0.f, 0.f}, s2[4] = {0.f, 0.f, 0.f, 0.f};
    #pragma unroll
    for (int r = 0; r < 4; r++) {
        float4 o;
        float hv0 = acc[r][0] + bv.x;
        float hv1 = acc[r][1] + bv.y;
        float hv2 = acc[r][2] + bv.z;
        float hv3 = acc[r][3] + bv.w;
        if (ELUOUT) { hv0 = elu01f(hv0); hv1 = elu01f(hv1); hv2 = elu01f(hv2); hv3 = elu01f(hv3); }
        o.x = hv0; o.y = hv1; o.z = hv2; o.w = hv3;
        *(float4*)(out + (row0 + r0 + r) * HH + col0) = o;
        if (STATS) {
            s[0] += hv0; s2[0] = fmaf(hv0, hv0, s2[0]);
            s[1] += hv1; s2[1] = fmaf(hv1, hv1, s2[1]);
            s[2] += hv2; s2[2] = fmaf(hv2, hv2, s2[2]);
            s[3] += hv3; s2[3] = fmaf(hv3, hv3, s2[3]);
        }
    }
    if (STATS) {
        #pragma unroll
        for (int c = 0; c < 4; c++) {
            atomicAdd(&lsum[col0 + c], s[c]);
            atomicAdd(&lsq[col0 + c], s2[c]);
        }
        __syncthreads();
        if (tid < HH) {
            atomicAdd(&ssum[tid], lsum[tid]);
            atomicAdd(&ssq[tid], lsq[tid]);
        }
    }
}

__global__ void k_bnfin(const float* ssum, const float* ssq, const float* __restrict__ gm,
                        const float* __restrict__ bt, float* scale, float* shift) {
    int c = threadIdx.x;
    float mu = ssum[c] * (1.f / NN);
    float var = fmaxf(ssq[c] * (1.f / NN) - mu * mu, 0.f);
    float a = gm[c] * rsqrtf(var + BN_EPS);
    scale[c] = a;
    shift[c] = fmaf(-mu, a, bt[c]);
}

// ---------------- pooling ----------------
__global__ __launch_bounds__(128) void k_pool_part(const float* __restrict__ x, const int* __restrict__ gptr,
                                                   float* __restrict__ psum, float* __restrict__ pmax) {
    int g = blockIdx.x >> 4;
    int ch = blockIdx.x & 15;
    int s = gptr[g], e = gptr[g + 1];
    int len = e - s;
    int per = (len + PCH - 1) / PCH;
    int lo = s + ch * per;
    int hi = min(lo + per, e);
    int c = threadIdx.x;
    float sm = 0.f, mx = -INFINITY;
    for (int i = lo; i < hi; ++i) {
        float v = x[(size_t)i * HH + c];
        sm += v; mx = fmaxf(mx, v);
    }
    psum[(size_t)blockIdx.x * HH + c] = sm;
    pmax[(size_t)blockIdx.x * HH + c] = mx;
}

__global__ __launch_bounds__(128) void k_pool_fin(const float* __restrict__ psum, const float* __restrict__ pmax,
                                                  const int* __restrict__ gptr, const float* __restrict__ g0,
                                                  float* __restrict__ z) {
    int g = blockIdx.x, c = threadIdx.x;
    float sm = 0.f, mx = -INFINITY;
    for (int ch = 0; ch < PCH; ++ch) {
        sm += psum[(size_t)(g * PCH + ch) * HH + c];
        mx = fmaxf(mx, pmax[(size_t)(g * PCH + ch) * HH + c]);
    }
    int cntn = gptr[g + 1] - gptr[g];
    float denom = (float)max(cntn, 1);
    z[g * 264 + c] = sm / denom;
    z[g * 264 + 128 + c] = mx;
    if (c < GG) z[g * 264 + 256 + c] = g0[g * GG + c];
}

// ---------------- classifier ----------------
__global__ __launch_bounds__(128) void k_cls1(const float* __restrict__ z, const float* __restrict__ cw1,
                                              const float* __restrict__ cb1, float* __restrict__ z1) {
    __shared__ float zr[264];
    int g = blockIdx.x, c = threadIdx.x;
    for (int t = c; t < 264; t += 128) zr[t] = z[g * 264 + t];
    __syncthreads();
    float acc = cb1[c];
    for (int k = 0; k < 264; ++k) acc = fmaf(zr[k], cw1[k * HH + c], acc);
    z1[g * HH + c] = elu01f(acc);
}

__global__ __launch_bounds__(128) void k_cls2(const float* __restrict__ z1, const float* __restrict__ cgm,
                                              const float* __restrict__ cbt, const float* __restrict__ cw2,
                                              const float* __restrict__ cb2, float* __restrict__ outp) {
    __shared__ float zn[HH * 65];
    int c = threadIdx.x;
    float s = 0.f, s2 = 0.f;
    for (int g = 0; g < BB; ++g) {
        float v = z1[g * HH + c];
        s += v; s2 = fmaf(v, v, s2);
    }
    float mu = s * (1.f / BB);
    float var = fmaxf(s2 * (1.f / BB) - mu * mu, 0.f);
    float a = cgm[c] * rsqrtf(var + BN_EPS);
    float sh = fmaf(-mu, a, cbt[c]);
    for (int g = 0; g < BB; ++g) zn[c * 65 + g] = fmaf(z1[g * HH + c], a, sh);
    __syncthreads();
    if (c < BB) {
        float l0 = cb2[0], l1 = cb2[1];
        for (int k = 0; k < HH; ++k) {
            float v = zn[k * 65 + c];
            l0 = fmaf(v, cw2[k * 2 + 0], l0);
            l1 = fmaf(v, cw2[k * 2 + 1], l1);
        }
        float m = fmaxf(l0, l1);
        float e0 = __expf(l0 - m), e1 = __expf(l1 - m);
        float inv = 1.f / (e0 + e1);
        outp[c * 2 + 0] = e0 * inv;
        outp[c * 2 + 1] = e1 * inv;
    }
}

extern "C" void kernel_launch(void* const* d_in, const int* in_sizes, int n_in,
                              void* d_out, int out_size, void* d_ws, size_t ws_size,
                              hipStream_t stream) {
    (void)in_sizes; (void)n_in; (void)out_size; (void)ws_size;
    const float* h0     = (const float*)d_in[0];
    const float* coord0 = (const float*)d_in[1];
    const float* g0     = (const float*)d_in[2];
    const int*   eidx   = (const int*)d_in[3];
    const int*   batch  = (const int*)d_in[4];
    const float* w1_0   = (const float*)d_in[5];
    const float* b1_0   = (const float*)d_in[6];
    const float* gm_0   = (const float*)d_in[7];
    const float* bt_0   = (const float*)d_in[8];
    const float* w2_0   = (const float*)d_in[9];
    const float* b2_0   = (const float*)d_in[10];
    const float* w1_r   = (const float*)d_in[11];
    const float* b1_r   = (const float*)d_in[12];
    const float* gm_r   = (const float*)d_in[13];
    const float* bt_r   = (const float*)d_in[14];
    const float* w2_r   = (const float*)d_in[15];
    const float* b2_r   = (const float*)d_in[16];
    const float* cw1    = (const float*)d_in[17];
    const float* cb1    = (const float*)d_in[18];
    const float* cgm    = (const float*)d_in[19];
    const float* cbt    = (const float*)d_in[20];
    const float* cw2    = (const float*)d_in[21];
    const float* cb2    = (const float*)d_in[22];
    float* outp = (float*)d_out;

    const int* esrc = eidx;
    const int* edst = eidx + EE;

    char* p = (char*)d_ws;
    auto alloc = [&](size_t bytes) { void* r = (void*)p; p += (bytes + 255) & ~(size_t)255; return r; };
    float* xb      = (float*)alloc((size_t)NN * HH * 4);
    float* yb      = (float*)alloc((size_t)NN * HH * 4);
    float* hb      = (float*)alloc((size_t)NN * HH * 4);
    int*   cnt     = (int*)alloc((size_t)NN * 4);
    int*   excl    = (int*)alloc((size_t)NN * 4);
    int*   rp      = (int*)alloc((size_t)(NN + 1) * 4);
    int*   cur     = (int*)alloc((size_t)NN * 4);
    int*   srcs    = (int*)alloc((size_t)EE * 4);
    int*   bsums   = (int*)alloc(128 * 4);
    int*   gptr    = (int*)alloc((BB + 1) * 4);
    float* bnstat  = (float*)alloc(2 * HH * 4);   // sum | sumsq
    float* bnscale = (float*)alloc(HH * 4);
    float* bnshift = (float*)alloc(HH * 4);
    float* psum    = (float*)alloc((size_t)BB * PCH * HH * 4);
    float* pmax    = (float*)alloc((size_t)BB * PCH * HH * 4);
    float* zb      = (float*)alloc((size_t)BB * 264 * 4);
    float* z1b     = (float*)alloc((size_t)BB * HH * 4);

    const int NB_SCAN1 = (NN + 1023) / 1024;        // 98
    const int NB_E4 = (EE / 4 + 255) / 256;         // 1563
    const int NB_N = (NN + 255) / 256;              // 391
    const int NB_AGG = (NN * 64 + 255) / 256;       // 25000
    const int NB_GEMM = NN / 32;                    // 3125
    const int NB_X0 = (NN * K0 + 255) / 256;

    // CSR build
    hipMemsetAsync(cnt, 0, (size_t)NN * 4, stream);
    k_count<<<NB_E4, 256, 0, stream>>>(edst, cnt);
    k_scan1<<<NB_SCAN1, 256, 0, stream>>>(cnt, excl, bsums);
    k_scan2<<<1, 128, 0, stream>>>(bsums, NB_SCAN1);
    k_scan3<<<NB_N, 256, 0, stream>>>(excl, bsums, rp, cur);
    k_scatter<<<NB_E4, 256, 0, stream>>>(esrc, edst, cur, srcs);
    k_gptr<<<1, 128, 0, stream>>>(batch, gptr);

    // layer 0: x0 [N,19]
    k_buildx0<<<NB_X0, 256, 0, stream>>>(h0, coord0, xb);
    k_agg_small<<<NB_AGG, 256, 0, stream>>>(xb, rp, srcs, yb);
    hipMemsetAsync(bnstat, 0, 2 * HH * 4, stream);
    k_gemm_small<K0, true><<<NB_GEMM, 256, 0, stream>>>(yb, w1_0, b1_0, hb, bnstat, bnstat + HH);
    k_bnfin<<<1, 128, 0, stream>>>(bnstat, bnstat + HH, gm_0, bt_0, bnscale, bnshift);
    k_gemm128<false, true, true><<<NB_GEMM, 256, 0, stream>>>(hb, w2_0, b2_0, bnscale, bnshift,
                                                              xb, nullptr, nullptr);

    // layers 1..2
    for (int i = 0; i < 2; ++i) {
        k_agg128<<<NB_AGG, 256, 0, stream>>>(xb, rp, srcs, yb);
        hipMemsetAsync(bnstat, 0, 2 * HH * 4, stream);
        k_gemm128<true, false, false><<<NB_GEMM, 256, 0, stream>>>(yb, w1_r + (size_t)i * HH * HH,
                b1_r + i * HH, nullptr, nullptr, hb, bnstat, bnstat + HH);
        k_bnfin<<<1, 128, 0, stream>>>(bnstat, bnstat + HH, gm_r + i * HH, bt_r + i * HH, bnscale, bnshift);
        k_gemm128<false, true, true><<<NB_GEMM, 256, 0, stream>>>(hb, w2_r + (size_t)i * HH * HH,
                b2_r + i * HH, bnscale, bnshift, xb, nullptr, nullptr);
    }

    // pooling + classifier
    k_pool_part<<<BB * PCH, 128, 0, stream>>>(xb, gptr, psum, pmax);
    k_pool_fin<<<BB, 128, 0, stream>>>(psum, pmax, gptr, g0, zb);
    k_cls1<<<BB, 128, 0, stream>>>(zb, cw1, cb1, z1b);
    k_cls2<<<1, 128, 0, stream>>>(z1b, cgm, cbt, cw2, cb2, outp);
}

// Round 6
// 1025.073 us; speedup vs baseline: 1.1649x; 1.1649x over previous
//
#include <hip/hip_runtime.h>
#include <math.h>

#define NN 100000
#define EE 1600000
#define BB 64
#define FF 16
#define HH 128
#define GG 8
#define K0 19
#define BN_EPS 1e-5f
#define PCH 16
#define BSHIFT 8
#define BNODES 256
#define NBINS 391          // ceil(NN/256)
#define BCAP 8192          // bin edges ~Poisson(4096), sigma 64 -> huge slack
#define ACH 2048           // edges per phase-A block

__device__ __forceinline__ float elu01f(float v) {
    return v > 0.f ? v : 0.1f * (__expf(v) - 1.f);
}

// ---------------- CSR build: 2-phase LDS counting sort ----------------
// Phase A: block-local bin sort; one global atomic per (block,bin); near-coalesced writes.
__global__ __launch_bounds__(256) void k_binA(const int* __restrict__ esrc, const int* __restrict__ edst,
                                              int* __restrict__ bincnt, uint2* __restrict__ binbuf) {
    __shared__ int hist[NBINS];
    __shared__ int gbase[NBINS];
    __shared__ int cur[NBINS];
    __shared__ int sc[512];
    __shared__ uint2 ebuf[ACH];
    __shared__ uint2 sorted[ACH];
    int tid = threadIdx.x;
    int e0 = blockIdx.x * ACH;
    int n = min(ACH, EE - e0);
    for (int i = tid; i < NBINS; i += 256) hist[i] = 0;
    __syncthreads();
    // pass 1: stage + histogram
    for (int i = tid; i < n; i += 256) {
        int s = esrc[e0 + i];
        int d = edst[e0 + i];
        ebuf[i] = make_uint2((unsigned)s, (unsigned)d);
        atomicAdd(&hist[d >> BSHIFT], 1);
    }
    __syncthreads();
    // inclusive scan of hist over 512 slots (256 threads x 2)
    sc[tid] = (tid < NBINS) ? hist[tid] : 0;
    sc[tid + 256] = (tid + 256 < NBINS) ? hist[tid + 256] : 0;
    __syncthreads();
    for (int off = 1; off < 512; off <<= 1) {
        int a0 = sc[tid], a1 = sc[tid + 256];
        int b0 = (tid >= off) ? sc[tid - off] : 0;
        int b1 = (tid + 256 >= off) ? sc[tid + 256 - off] : 0;
        __syncthreads();
        sc[tid] = a0 + b0;
        sc[tid + 256] = a1 + b1;
        __syncthreads();
    }
    // reserve global segments, init cursors to local starts
    for (int b = tid; b < NBINS; b += 256) {
        int c = hist[b];
        gbase[b] = (c > 0) ? atomicAdd(&bincnt[b], c) : 0;
        cur[b] = (b > 0) ? sc[b - 1] : 0;
    }
    __syncthreads();
    // pass 2: LDS scatter into bin-sorted order
    for (int i = tid; i < n; i += 256) {
        uint2 e = ebuf[i];
        int b = (int)(e.y >> BSHIFT);
        int pos = atomicAdd(&cur[b], 1);
        sorted[pos] = e;
    }
    __syncthreads();
    // pass 3: near-coalesced global write (consecutive i in same bin -> consecutive addr)
    for (int i = tid; i < n; i += 256) {
        uint2 e = sorted[i];
        int b = (int)(e.y >> BSHIFT);
        int ls = (b > 0) ? sc[b - 1] : 0;
        int gpos = gbase[b] + (i - ls);
        binbuf[(size_t)b * BCAP + gpos] = e;
    }
}

__global__ void k_binscan(const int* __restrict__ bincnt, int* __restrict__ binstart, int* __restrict__ rp) {
    __shared__ int sc[512];
    int t = threadIdx.x;
    sc[t] = (t < NBINS) ? bincnt[t] : 0;
    __syncthreads();
    for (int off = 1; off < 512; off <<= 1) {
        int v = (t >= off) ? sc[t - off] : 0;
        __syncthreads();
        sc[t] += v;
        __syncthreads();
    }
    if (t < NBINS) binstart[t] = (t > 0) ? sc[t - 1] : 0;
    if (t == 0) rp[NN] = EE;
}

// Phase B: per-bin CSR finalize; writes rp + srcs fully coalesced.
__global__ __launch_bounds__(256) void k_binB(const uint2* __restrict__ binbuf, const int* __restrict__ bincnt,
                                              const int* __restrict__ binstart,
                                              int* __restrict__ rp, int* __restrict__ srcs) {
    __shared__ int hist[BNODES];
    __shared__ int scx[BNODES];
    __shared__ int scur[BNODES];
    __shared__ int sbuf[BCAP];
    int b = blockIdx.x;
    int n = bincnt[b];
    int tid = threadIdx.x;
    hist[tid] = 0;
    __syncthreads();
    const uint2* eb = binbuf + (size_t)b * BCAP;
    for (int i = tid; i < n; i += 256)
        atomicAdd(&hist[eb[i].y & (BNODES - 1)], 1);
    __syncthreads();
    scx[tid] = hist[tid];
    __syncthreads();
    for (int off = 1; off < 256; off <<= 1) {
        int v = (tid >= off) ? scx[tid - off] : 0;
        __syncthreads();
        scx[tid] += v;
        __syncthreads();
    }
    int base = binstart[b];
    int excl = (tid > 0) ? scx[tid - 1] : 0;
    int node = (b << BSHIFT) + tid;
    if (node < NN) rp[node] = base + excl;
    scur[tid] = excl;
    __syncthreads();
    for (int i = tid; i < n; i += 256) {
        uint2 e = eb[i];
        int pos = atomicAdd(&scur[e.y & (BNODES - 1)], 1);
        sbuf[pos] = (int)e.x;
    }
    __syncthreads();
    for (int i = tid; i < n; i += 256) srcs[base + i] = sbuf[i];
}

// graph boundaries via binary search on sorted batch
__global__ void k_gptr(const int* __restrict__ batch, int* __restrict__ gptr) {
    int t = threadIdx.x;
    if (t > BB) return;
    int lo = 0, hi = NN;
    while (lo < hi) { int mid = (lo + hi) >> 1; if (batch[mid] < t) lo = mid + 1; else hi = mid; }
    gptr[t] = lo;
}

// ---------------- feature build + aggregation ----------------
__global__ __launch_bounds__(256) void k_buildx0(const float* __restrict__ h0, const float* __restrict__ coord,
                                                 float* __restrict__ x0) {
    int i = blockIdx.x * 256 + threadIdx.x;
    if (i >= NN * K0) return;
    int node = i / K0, k = i - node * K0;
    x0[i] = (k < FF) ? h0[node * FF + k] : coord[node * 3 + (k - FF)];
}

__global__ __launch_bounds__(256) void k_agg_small(const float* __restrict__ x, const int* __restrict__ rp,
                                                   const int* __restrict__ srcs, float* __restrict__ y) {
    int w = (blockIdx.x * 256 + threadIdx.x) >> 6;
    int lane = threadIdx.x & 63;
    if (w >= NN) return;
    int beg = rp[w], end = rp[w + 1];
    bool act = lane < K0;
    size_t li = act ? (size_t)lane : 0;
    float acc0 = 0.f, acc1 = 0.f;
    if (act) acc0 = x[(size_t)w * K0 + li];
    int p = beg;
    for (; p + 8 <= end; p += 8) {
        int s0 = srcs[p + 0], s1 = srcs[p + 1], s2 = srcs[p + 2], s3 = srcs[p + 3];
        int s4 = srcs[p + 4], s5 = srcs[p + 5], s6 = srcs[p + 6], s7 = srcs[p + 7];
        float v0 = x[(size_t)s0 * K0 + li];
        float v1 = x[(size_t)s1 * K0 + li];
        float v2 = x[(size_t)s2 * K0 + li];
        float v3 = x[(size_t)s3 * K0 + li];
        float v4 = x[(size_t)s4 * K0 + li];
        float v5 = x[(size_t)s5 * K0 + li];
        float v6 = x[(size_t)s6 * K0 + li];
        float v7 = x[(size_t)s7 * K0 + li];
        acc0 += (v0 + v1) + (v2 + v3);
        acc1 += (v4 + v5) + (v6 + v7);
    }
    for (; p < end; ++p) {
        int sn = srcs[p];
        acc0 += x[(size_t)sn * K0 + li];
    }
    if (act) y[(size_t)w * K0 + lane] = acc0 + acc1;
}

__global__ __launch_bounds__(256) void k_agg128(const float* __restrict__ x, const int* __restrict__ rp,
                                                const int* __restrict__ srcs, float* __restrict__ y) {
    int w = (blockIdx.x * 256 + threadIdx.x) >> 6;
    int lane = threadIdx.x & 63;
    if (w >= NN) return;
    const float2* x2 = (const float2*)x;
    float2* y2 = (float2*)y;
    int beg = rp[w], end = rp[w + 1];
    float2 a0 = x2[(size_t)w * 64 + lane];
    float2 a1 = {0.f, 0.f};
    int p = beg;
    for (; p + 8 <= end; p += 8) {
        int s0 = srcs[p + 0], s1 = srcs[p + 1], s2 = srcs[p + 2], s3 = srcs[p + 3];
        int s4 = srcs[p + 4], s5 = srcs[p + 5], s6 = srcs[p + 6], s7 = srcs[p + 7];
        float2 v0 = x2[(size_t)s0 * 64 + lane];
        float2 v1 = x2[(size_t)s1 * 64 + lane];
        float2 v2 = x2[(size_t)s2 * 64 + lane];
        float2 v3 = x2[(size_t)s3 * 64 + lane];
        float2 v4 = x2[(size_t)s4 * 64 + lane];
        float2 v5 = x2[(size_t)s5 * 64 + lane];
        float2 v6 = x2[(size_t)s6 * 64 + lane];
        float2 v7 = x2[(size_t)s7 * 64 + lane];
        a0.x += (v0.x + v1.x) + (v2.x + v3.x);
        a0.y += (v0.y + v1.y) + (v2.y + v3.y);
        a1.x += (v4.x + v5.x) + (v6.x + v7.x);
        a1.y += (v4.y + v5.y) + (v6.y + v7.y);
    }
    for (; p < end; ++p) {
        int sn = srcs[p];
        float2 v = x2[(size_t)sn * 64 + lane];
        a0.x += v.x; a0.y += v.y;
    }
    a0.x += a1.x; a0.y += a1.y;
    y2[(size_t)w * 64 + lane] = a0;
}

// ---------------- GEMM K=19 (layer-0 first MLP): 32 rows x 128 cols ----------------
template<int K, bool STATS>
__global__ __launch_bounds__(256) void k_gemm_small(const float* __restrict__ in, const float* __restrict__ W,
        const float* __restrict__ bias, float* __restrict__ out, float* __restrict__ ssum, float* __restrict__ ssq) {
    constexpr int SK = ((K + 3) / 4) * 4 + 4;
    __shared__ __align__(16) float yt[32 * SK];
    __shared__ float red[256];
    int tid = threadIdx.x;
    int row0 = blockIdx.x * 32;
    for (int t = tid; t < 32 * SK; t += 256) {
        int r = t / SK, k = t - r * SK;
        float v = 0.f;
        if (k < K) v = in[(size_t)(row0 + r) * K + k];
        yt[t] = v;
    }
    __syncthreads();
    int col = tid & 127;
    int rg = tid >> 7;
    float acc[16];
    #pragma unroll
    for (int r = 0; r < 16; r++) acc[r] = 0.f;
    const float* ybase = &yt[rg * 16 * SK];
    int kk = 0;
    for (; kk + 4 <= K; kk += 4) {
        float w0 = W[(kk + 0) * HH + col];
        float w1 = W[(kk + 1) * HH + col];
        float w2 = W[(kk + 2) * HH + col];
        float w3 = W[(kk + 3) * HH + col];
        #pragma unroll
        for (int r = 0; r < 16; r++) {
            const float4 v = *(const float4*)&ybase[r * SK + kk];
            acc[r] = fmaf(v.x, w0, acc[r]);
            acc[r] = fmaf(v.y, w1, acc[r]);
            acc[r] = fmaf(v.z, w2, acc[r]);
            acc[r] = fmaf(v.w, w3, acc[r]);
        }
    }
    if constexpr (K % 4 != 0) {
        float w[4];
        #pragma unroll
        for (int j = 0; j < 4; j++) w[j] = (kk + j < K) ? W[(kk + j) * HH + col] : 0.f;
        #pragma unroll
        for (int r = 0; r < 16; r++) {
            const float4 v = *(const float4*)&ybase[r * SK + kk];
            acc[r] = fmaf(v.x, w[0], acc[r]);
            acc[r] = fmaf(v.y, w[1], acc[r]);
            acc[r] = fmaf(v.z, w[2], acc[r]);
            acc[r] = fmaf(v.w, w[3], acc[r]);
        }
    }
    float bcol = bias[col];
    float s = 0.f, s2 = 0.f;
    #pragma unroll
    for (int r = 0; r < 16; r++) {
        float hv = acc[r] + bcol;
        out[(size_t)(row0 + rg * 16 + r) * HH + col] = hv;
        if (STATS) { s += hv; s2 = fmaf(hv, hv, s2); }
    }
    if (STATS) {
        red[tid] = s; __syncthreads();
        if (tid < 128) atomicAdd(&ssum[col], s + red[tid + 128]);
        __syncthreads();
        red[tid] = s2; __syncthreads();
        if (tid < 128) atomicAdd(&ssq[col], s2 + red[tid + 128]);
    }
}

// ---------------- GEMM K=128: 32 rows x 128 cols, 4x4 micro-tile/thread ----------------
template<bool STATS, bool BNIN, bool ELUOUT>
__global__ __launch_bounds__(256) void k_gemm128(const float* __restrict__ in, const float* __restrict__ W,
        const float* __restrict__ bias, const float* __restrict__ bnscale, const float* __restrict__ bnshift,
        float* __restrict__ out, float* __restrict__ ssum, float* __restrict__ ssq) {
    __shared__ __align__(16) float At[32 * 132];
    __shared__ float lsum[HH], lsq[HH];
    int tid = threadIdx.x;
    size_t row0 = (size_t)blockIdx.x * 32;
    if (STATS && tid < HH) { lsum[tid] = 0.f; lsq[tid] = 0.f; }
    {
        int r = tid >> 3;
        int kb = (tid & 7) * 16;
        const float4* s4 = (const float4*)(in + (row0 + r) * HH + kb);
        #pragma unroll
        for (int j = 0; j < 4; j++) {
            float4 v = s4[j];
            if (BNIN) {
                const float4 sc = *(const float4*)(bnscale + kb + j * 4);
                const float4 sh = *(const float4*)(bnshift + kb + j * 4);
                v.x = fmaxf(fmaf(v.x, sc.x, sh.x), 0.f);
                v.y = fmaxf(fmaf(v.y, sc.y, sh.y), 0.f);
                v.z = fmaxf(fmaf(v.z, sc.z, sh.z), 0.f);
                v.w = fmaxf(fmaf(v.w, sc.w, sh.w), 0.f);
            }
            *(float4*)(&At[r * 132 + kb + j * 4]) = v;
        }
    }
    __syncthreads();
    int colg = tid & 31, rowg = tid >> 5;
    int col0 = colg * 4;
    int r0 = rowg * 4;
    float acc[4][4];
    #pragma unroll
    for (int r = 0; r < 4; r++)
        #pragma unroll
        for (int c = 0; c < 4; c++) acc[r][c] = 0.f;
    const float* Abase = &At[r0 * 132];
    for (int k = 0; k < HH; k += 4) {
        float a_[4][4];
        #pragma unroll
        for (int r = 0; r < 4; r++) {
            float4 av = *(const float4*)(Abase + r * 132 + k);
            a_[r][0] = av.x; a_[r][1] = av.y; a_[r][2] = av.z; a_[r][3] = av.w;
        }
        #pragma unroll
        for (int j = 0; j < 4; j++) {
            float4 w = *(const float4*)(W + (size_t)(k + j) * HH + col0);
            #pragma unroll
            for (int r = 0; r < 4; r++) {
                acc[r][0] = fmaf(a_[r][j], w.x, acc[r][0]);
                acc[r][1] = fmaf(a_[r][j], w.y, acc[r][1]);
                acc[r][2] = fmaf(a_[r][j], w.z, acc[r][2]);
                acc[r][3] = fmaf(a_[r][j], w.w, acc[r][3]);
            }
        }
    }
    float4 bv = *(const float4*)(bias + col0);
    float s[4] = {0.f, 0.f, 0.f, 0.f}, s2[4] = {0.f, 0.f, 0.f, 0.f};
    #pragma unroll
    for (int r = 0; r < 4; r++) {
        float4 o;
        float hv0 = acc[r][0] + bv.x;
        float hv1 = acc[r][1] + bv.y;
        float hv2 = acc[r][2] + bv.z;
        float hv3 = acc[r][3] + bv.w;
        if (ELUOUT) { hv0 = elu01f(hv0); hv1 = elu01f(hv1); hv2 = elu01f(hv2); hv3 = elu01f(hv3); }
        o.x = hv0; o.y = hv1; o.z = hv2; o.w = hv3;
        *(float4*)(out + (row0 + r0 + r) * HH + col0) = o;
        if (STATS) {
            s[0] += hv0; s2[0] = fmaf(hv0, hv0, s2[0]);
            s[1] += hv1; s2[1] = fmaf(hv1, hv1, s2[1]);
            s[2] += hv2; s2[2] = fmaf(hv2, hv2, s2[2]);
            s[3] += hv3; s2[3] = fmaf(hv3, hv3, s2[3]);
        }
    }
    if (STATS) {
        #pragma unroll
        for (int c = 0; c < 4; c++) {
            atomicAdd(&lsum[col0 + c], s[c]);
            atomicAdd(&lsq[col0 + c], s2[c]);
        }
        __syncthreads();
        if (tid < HH) {
            atomicAdd(&ssum[tid], lsum[tid]);
            atomicAdd(&ssq[tid], lsq[tid]);
        }
    }
}

__global__ void k_bnfin(const float* ssum, const float* ssq, const float* __restrict__ gm,
                        const float* __restrict__ bt, float* scale, float* shift) {
    int c = threadIdx.x;
    float mu = ssum[c] * (1.f / NN);
    float var = fmaxf(ssq[c] * (1.f / NN) - mu * mu, 0.f);
    float a = gm[c] * rsqrtf(var + BN_EPS);
    scale[c] = a;
    shift[c] = fmaf(-mu, a, bt[c]);
}

// ---------------- pooling ----------------
__global__ __launch_bounds__(128) void k_pool_part(const float* __restrict__ x, const int* __restrict__ gptr,
                                                   float* __restrict__ psum, float* __restrict__ pmax) {
    int g = blockIdx.x >> 4;
    int ch = blockIdx.x & 15;
    int s = gptr[g], e = gptr[g + 1];
    int len = e - s;
    int per = (len + PCH - 1) / PCH;
    int lo = s + ch * per;
    int hi = min(lo + per, e);
    int c = threadIdx.x;
    float sm = 0.f, mx = -INFINITY;
    for (int i = lo; i < hi; ++i) {
        float v = x[(size_t)i * HH + c];
        sm += v; mx = fmaxf(mx, v);
    }
    psum[(size_t)blockIdx.x * HH + c] = sm;
    pmax[(size_t)blockIdx.x * HH + c] = mx;
}

__global__ __launch_bounds__(128) void k_pool_fin(const float* __restrict__ psum, const float* __restrict__ pmax,
                                                  const int* __restrict__ gptr, const float* __restrict__ g0,
                                                  float* __restrict__ z) {
    int g = blockIdx.x, c = threadIdx.x;
    float sm = 0.f, mx = -INFINITY;
    for (int ch = 0; ch < PCH; ++ch) {
        sm += psum[(size_t)(g * PCH + ch) * HH + c];
        mx = fmaxf(mx, pmax[(size_t)(g * PCH + ch) * HH + c]);
    }
    int cntn = gptr[g + 1] - gptr[g];
    float denom = (float)max(cntn, 1);
    z[g * 264 + c] = sm / denom;
    z[g * 264 + 128 + c] = mx;
    if (c < GG) z[g * 264 + 256 + c] = g0[g * GG + c];
}

// ---------------- classifier ----------------
__global__ __launch_bounds__(128) void k_cls1(const float* __restrict__ z, const float* __restrict__ cw1,
                                              const float* __restrict__ cb1, float* __restrict__ z1) {
    __shared__ float zr[264];
    int g = blockIdx.x, c = threadIdx.x;
    for (int t = c; t < 264; t += 128) zr[t] = z[g * 264 + t];
    __syncthreads();
    float acc = cb1[c];
    for (int k = 0; k < 264; ++k) acc = fmaf(zr[k], cw1[k * HH + c], acc);
    z1[g * HH + c] = elu01f(acc);
}

__global__ __launch_bounds__(128) void k_cls2(const float* __restrict__ z1, const float* __restrict__ cgm,
                                              const float* __restrict__ cbt, const float* __restrict__ cw2,
                                              const float* __restrict__ cb2, float* __restrict__ outp) {
    __shared__ float zn[HH * 65];
    int c = threadIdx.x;
    float s = 0.f, s2 = 0.f;
    for (int g = 0; g < BB; ++g) {
        float v = z1[g * HH + c];
        s += v; s2 = fmaf(v, v, s2);
    }
    float mu = s * (1.f / BB);
    float var = fmaxf(s2 * (1.f / BB) - mu * mu, 0.f);
    float a = cgm[c] * rsqrtf(var + BN_EPS);
    float sh = fmaf(-mu, a, cbt[c]);
    for (int g = 0; g < BB; ++g) zn[c * 65 + g] = fmaf(z1[g * HH + c], a, sh);
    __syncthreads();
    if (c < BB) {
        float l0 = cb2[0], l1 = cb2[1];
        for (int k = 0; k < HH; ++k) {
            float v = zn[k * 65 + c];
            l0 = fmaf(v, cw2[k * 2 + 0], l0);
            l1 = fmaf(v, cw2[k * 2 + 1], l1);
        }
        float m = fmaxf(l0, l1);
        float e0 = __expf(l0 - m), e1 = __expf(l1 - m);
        float inv = 1.f / (e0 + e1);
        outp[c * 2 + 0] = e0 * inv;
        outp[c * 2 + 1] = e1 * inv;
    }
}

extern "C" void kernel_launch(void* const* d_in, const int* in_sizes, int n_in,
                              void* d_out, int out_size, void* d_ws, size_t ws_size,
                              hipStream_t stream) {
    (void)in_sizes; (void)n_in; (void)out_size; (void)ws_size;
    const float* h0     = (const float*)d_in[0];
    const float* coord0 = (const float*)d_in[1];
    const float* g0     = (const float*)d_in[2];
    const int*   eidx   = (const int*)d_in[3];
    const int*   batch  = (const int*)d_in[4];
    const float* w1_0   = (const float*)d_in[5];
    const float* b1_0   = (const float*)d_in[6];
    const float* gm_0   = (const float*)d_in[7];
    const float* bt_0   = (const float*)d_in[8];
    const float* w2_0   = (const float*)d_in[9];
    const float* b2_0   = (const float*)d_in[10];
    const float* w1_r   = (const float*)d_in[11];
    const float* b1_r   = (const float*)d_in[12];
    const float* gm_r   = (const float*)d_in[13];
    const float* bt_r   = (const float*)d_in[14];
    const float* w2_r   = (const float*)d_in[15];
    const float* b2_r   = (const float*)d_in[16];
    const float* cw1    = (const float*)d_in[17];
    const float* cb1    = (const float*)d_in[18];
    const float* cgm    = (const float*)d_in[19];
    const float* cbt    = (const float*)d_in[20];
    const float* cw2    = (const float*)d_in[21];
    const float* cb2    = (const float*)d_in[22];
    float* outp = (float*)d_out;

    const int* esrc = eidx;
    const int* edst = eidx + EE;

    char* p = (char*)d_ws;
    auto alloc = [&](size_t bytes) { void* r = (void*)p; p += (bytes + 255) & ~(size_t)255; return r; };
    float* xb       = (float*)alloc((size_t)NN * HH * 4);
    float* yb       = (float*)alloc((size_t)NN * HH * 4);
    float* hb       = (float*)alloc((size_t)NN * HH * 4);
    int*   rp       = (int*)alloc((size_t)(NN + 1) * 4);
    int*   srcs     = (int*)alloc((size_t)EE * 4);
    int*   bincnt   = (int*)alloc((size_t)NBINS * 4);
    int*   binstart = (int*)alloc((size_t)NBINS * 4);
    int*   gptr     = (int*)alloc((BB + 1) * 4);
    float* bnstat   = (float*)alloc(2 * HH * 4);   // sum | sumsq
    float* bnscale  = (float*)alloc(HH * 4);
    float* bnshift  = (float*)alloc(HH * 4);
    float* psum     = (float*)alloc((size_t)BB * PCH * HH * 4);
    float* pmax     = (float*)alloc((size_t)BB * PCH * HH * 4);
    float* zb       = (float*)alloc((size_t)BB * 264 * 4);
    float* z1b      = (float*)alloc((size_t)BB * HH * 4);
    // bin buffer overlays yb (dead until k_agg_small): 391*8192*8B = 25.6MB < 51.2MB
    uint2* binbuf   = (uint2*)yb;

    const int NB_A = (EE + ACH - 1) / ACH;          // 782
    const int NB_AGG = (NN * 64 + 255) / 256;       // 25000
    const int NB_GEMM = NN / 32;                    // 3125
    const int NB_X0 = (NN * K0 + 255) / 256;

    // CSR build: LDS counting sort (coalesced writes; ~38K global atomics total)
    hipMemsetAsync(bincnt, 0, (size_t)NBINS * 4, stream);
    k_binA<<<NB_A, 256, 0, stream>>>(esrc, edst, bincnt, binbuf);
    k_binscan<<<1, 512, 0, stream>>>(bincnt, binstart, rp);
    k_binB<<<NBINS, 256, 0, stream>>>(binbuf, bincnt, binstart, rp, srcs);
    k_gptr<<<1, 128, 0, stream>>>(batch, gptr);

    // layer 0: x0 [N,19]
    k_buildx0<<<NB_X0, 256, 0, stream>>>(h0, coord0, xb);
    k_agg_small<<<NB_AGG, 256, 0, stream>>>(xb, rp, srcs, yb);
    hipMemsetAsync(bnstat, 0, 2 * HH * 4, stream);
    k_gemm_small<K0, true><<<NB_GEMM, 256, 0, stream>>>(yb, w1_0, b1_0, hb, bnstat, bnstat + HH);
    k_bnfin<<<1, 128, 0, stream>>>(bnstat, bnstat + HH, gm_0, bt_0, bnscale, bnshift);
    k_gemm128<false, true, true><<<NB_GEMM, 256, 0, stream>>>(hb, w2_0, b2_0, bnscale, bnshift,
                                                              xb, nullptr, nullptr);

    // layers 1..2
    for (int i = 0; i < 2; ++i) {
        k_agg128<<<NB_AGG, 256, 0, stream>>>(xb, rp, srcs, yb);
        hipMemsetAsync(bnstat, 0, 2 * HH * 4, stream);
        k_gemm128<true, false, false><<<NB_GEMM, 256, 0, stream>>>(yb, w1_r + (size_t)i * HH * HH,
                b1_r + i * HH, nullptr, nullptr, hb, bnstat, bnstat + HH);
        k_bnfin<<<1, 128, 0, stream>>>(bnstat, bnstat + HH, gm_r + i * HH, bt_r + i * HH, bnscale, bnshift);
        k_gemm128<false, true, true><<<NB_GEMM, 256, 0, stream>>>(hb, w2_r + (size_t)i * HH * HH,
                b2_r + i * HH, bnscale, bnshift, xb, nullptr, nullptr);
    }

    // pooling + classifier
    k_pool_part<<<BB * PCH, 128, 0, stream>>>(xb, gptr, psum, pmax);
    k_pool_fin<<<BB, 128, 0, stream>>>(psum, pmax, gptr, g0, zb);
    k_cls1<<<BB, 128, 0, stream>>>(zb, cw1, cb1, z1b);
    k_cls2<<<1, 128, 0, stream>>>(z1b, cgm, cbt, cw2, cb2, outp);
}

// Round 7
// 831.633 us; speedup vs baseline: 1.4358x; 1.2326x over previous
//
#include <hip/hip_runtime.h>
#include <math.h>

#define NN 100000
#define EE 1600000
#define BB 64
#define FF 16
#define HH 128
#define GG 8
#define K0 19
#define BN_EPS 1e-5f
#define PCH 16
#define BSHIFT 8
#define BNODES 256
#define NBINS 391          // ceil(NN/256)
#define BCAP 8192
#define ACH 2048           // edges per phase-A block

typedef short bf16x8 __attribute__((ext_vector_type(8)));
typedef float f32x4 __attribute__((ext_vector_type(4)));

__device__ __forceinline__ float elu01f(float v) {
    return v > 0.f ? v : 0.1f * (__expf(v) - 1.f);
}

__device__ __forceinline__ short f2bf(float f) {
    unsigned u = __float_as_uint(f);
    unsigned r = u + 0x7FFFu + ((u >> 16) & 1u);
    return (short)(r >> 16);
}

// ---------------- CSR build: 2-phase LDS counting sort ----------------
__global__ __launch_bounds__(256) void k_binA(const int* __restrict__ esrc, const int* __restrict__ edst,
                                              int* __restrict__ bincnt, uint2* __restrict__ binbuf) {
    __shared__ int hist[NBINS];
    __shared__ int gbase[NBINS];
    __shared__ int cur[NBINS];
    __shared__ int sc[512];
    __shared__ uint2 ebuf[ACH];
    __shared__ uint2 sorted[ACH];
    int tid = threadIdx.x;
    int e0 = blockIdx.x * ACH;
    int n = min(ACH, EE - e0);
    for (int i = tid; i < NBINS; i += 256) hist[i] = 0;
    __syncthreads();
    for (int i = tid; i < n; i += 256) {
        int s = esrc[e0 + i];
        int d = edst[e0 + i];
        ebuf[i] = make_uint2((unsigned)s, (unsigned)d);
        atomicAdd(&hist[d >> BSHIFT], 1);
    }
    __syncthreads();
    sc[tid] = (tid < NBINS) ? hist[tid] : 0;
    sc[tid + 256] = (tid + 256 < NBINS) ? hist[tid + 256] : 0;
    __syncthreads();
    for (int off = 1; off < 512; off <<= 1) {
        int a0 = sc[tid], a1 = sc[tid + 256];
        int b0 = (tid >= off) ? sc[tid - off] : 0;
        int b1 = (tid + 256 >= off) ? sc[tid + 256 - off] : 0;
        __syncthreads();
        sc[tid] = a0 + b0;
        sc[tid + 256] = a1 + b1;
        __syncthreads();
    }
    for (int b = tid; b < NBINS; b += 256) {
        int c = hist[b];
        gbase[b] = (c > 0) ? atomicAdd(&bincnt[b], c) : 0;
        cur[b] = (b > 0) ? sc[b - 1] : 0;
    }
    __syncthreads();
    for (int i = tid; i < n; i += 256) {
        uint2 e = ebuf[i];
        int b = (int)(e.y >> BSHIFT);
        int pos = atomicAdd(&cur[b], 1);
        sorted[pos] = e;
    }
    __syncthreads();
    for (int i = tid; i < n; i += 256) {
        uint2 e = sorted[i];
        int b = (int)(e.y >> BSHIFT);
        int ls = (b > 0) ? sc[b - 1] : 0;
        int gpos = gbase[b] + (i - ls);
        binbuf[(size_t)b * BCAP + gpos] = e;
    }
}

__global__ void k_binscan(const int* __restrict__ bincnt, int* __restrict__ binstart, int* __restrict__ rp) {
    __shared__ int sc[512];
    int t = threadIdx.x;
    sc[t] = (t < NBINS) ? bincnt[t] : 0;
    __syncthreads();
    for (int off = 1; off < 512; off <<= 1) {
        int v = (t >= off) ? sc[t - off] : 0;
        __syncthreads();
        sc[t] += v;
        __syncthreads();
    }
    if (t < NBINS) binstart[t] = (t > 0) ? sc[t - 1] : 0;
    if (t == 0) rp[NN] = EE;
}

__global__ __launch_bounds__(256) void k_binB(const uint2* __restrict__ binbuf, const int* __restrict__ bincnt,
                                              const int* __restrict__ binstart,
                                              int* __restrict__ rp, int* __restrict__ srcs) {
    __shared__ int hist[BNODES];
    __shared__ int scx[BNODES];
    __shared__ int scur[BNODES];
    __shared__ int sbuf[BCAP];
    int b = blockIdx.x;
    int n = bincnt[b];
    int tid = threadIdx.x;
    hist[tid] = 0;
    __syncthreads();
    const uint2* eb = binbuf + (size_t)b * BCAP;
    for (int i = tid; i < n; i += 256)
        atomicAdd(&hist[eb[i].y & (BNODES - 1)], 1);
    __syncthreads();
    scx[tid] = hist[tid];
    __syncthreads();
    for (int off = 1; off < 256; off <<= 1) {
        int v = (tid >= off) ? scx[tid - off] : 0;
        __syncthreads();
        scx[tid] += v;
        __syncthreads();
    }
    int base = binstart[b];
    int excl = (tid > 0) ? scx[tid - 1] : 0;
    int node = (b << BSHIFT) + tid;
    if (node < NN) rp[node] = base + excl;
    scur[tid] = excl;
    __syncthreads();
    for (int i = tid; i < n; i += 256) {
        uint2 e = eb[i];
        int pos = atomicAdd(&scur[e.y & (BNODES - 1)], 1);
        sbuf[pos] = (int)e.x;
    }
    __syncthreads();
    for (int i = tid; i < n; i += 256) srcs[base + i] = sbuf[i];
}

__global__ void k_gptr(const int* __restrict__ batch, int* __restrict__ gptr) {
    int t = threadIdx.x;
    if (t > BB) return;
    int lo = 0, hi = NN;
    while (lo < hi) { int mid = (lo + hi) >> 1; if (batch[mid] < t) lo = mid + 1; else hi = mid; }
    gptr[t] = lo;
}

// ---------------- weight prep: fp32 [k][col] -> bf16 transposed [col][k] ----------------
__global__ __launch_bounds__(256) void k_wprep(const float* __restrict__ w2_0, const float* __restrict__ w1_r,
                                               const float* __restrict__ w2_r, short* __restrict__ wt) {
    int t = blockIdx.x * 256 + threadIdx.x;
    if (t >= 5 * HH * HH) return;
    int m = t >> 14;
    int rem = t & 16383;
    int col = rem >> 7;
    int k = rem & 127;
    const float* src = (m == 0) ? w2_0 : (m <= 2 ? w1_r + (size_t)(m - 1) * HH * HH
                                                 : w2_r + (size_t)(m - 3) * HH * HH);
    wt[t] = f2bf(src[k * HH + col]);
}

// ---------------- feature build + aggregation ----------------
__global__ __launch_bounds__(256) void k_buildx0(const float* __restrict__ h0, const float* __restrict__ coord,
                                                 float* __restrict__ x0) {
    int i = blockIdx.x * 256 + threadIdx.x;
    if (i >= NN * K0) return;
    int node = i / K0, k = i - node * K0;
    x0[i] = (k < FF) ? h0[node * FF + k] : coord[node * 3 + (k - FF)];
}

__global__ __launch_bounds__(256) void k_agg_small(const float* __restrict__ x, const int* __restrict__ rp,
                                                   const int* __restrict__ srcs, float* __restrict__ y) {
    int w = (blockIdx.x * 256 + threadIdx.x) >> 6;
    int lane = threadIdx.x & 63;
    if (w >= NN) return;
    int beg = rp[w], end = rp[w + 1];
    bool act = lane < K0;
    size_t li = act ? (size_t)lane : 0;
    float acc0 = 0.f, acc1 = 0.f;
    if (act) acc0 = x[(size_t)w * K0 + li];
    int p = beg;
    for (; p + 8 <= end; p += 8) {
        int s0 = srcs[p + 0], s1 = srcs[p + 1], s2 = srcs[p + 2], s3 = srcs[p + 3];
        int s4 = srcs[p + 4], s5 = srcs[p + 5], s6 = srcs[p + 6], s7 = srcs[p + 7];
        float v0 = x[(size_t)s0 * K0 + li];
        float v1 = x[(size_t)s1 * K0 + li];
        float v2 = x[(size_t)s2 * K0 + li];
        float v3 = x[(size_t)s3 * K0 + li];
        float v4 = x[(size_t)s4 * K0 + li];
        float v5 = x[(size_t)s5 * K0 + li];
        float v6 = x[(size_t)s6 * K0 + li];
        float v7 = x[(size_t)s7 * K0 + li];
        acc0 += (v0 + v1) + (v2 + v3);
        acc1 += (v4 + v5) + (v6 + v7);
    }
    for (; p < end; ++p) {
        int sn = srcs[p];
        acc0 += x[(size_t)sn * K0 + li];
    }
    if (act) y[(size_t)w * K0 + lane] = acc0 + acc1;
}

__global__ __launch_bounds__(256) void k_agg128(const float* __restrict__ x, const int* __restrict__ rp,
                                                const int* __restrict__ srcs, float* __restrict__ y) {
    int w = (blockIdx.x * 256 + threadIdx.x) >> 6;
    int lane = threadIdx.x & 63;
    if (w >= NN) return;
    const float2* x2 = (const float2*)x;
    float2* y2 = (float2*)y;
    int beg = rp[w], end = rp[w + 1];
    float2 a0 = x2[(size_t)w * 64 + lane];
    float2 a1 = {0.f, 0.f};
    int p = beg;
    for (; p + 8 <= end; p += 8) {
        int s0 = srcs[p + 0], s1 = srcs[p + 1], s2 = srcs[p + 2], s3 = srcs[p + 3];
        int s4 = srcs[p + 4], s5 = srcs[p + 5], s6 = srcs[p + 6], s7 = srcs[p + 7];
        float2 v0 = x2[(size_t)s0 * 64 + lane];
        float2 v1 = x2[(size_t)s1 * 64 + lane];
        float2 v2 = x2[(size_t)s2 * 64 + lane];
        float2 v3 = x2[(size_t)s3 * 64 + lane];
        float2 v4 = x2[(size_t)s4 * 64 + lane];
        float2 v5 = x2[(size_t)s5 * 64 + lane];
        float2 v6 = x2[(size_t)s6 * 64 + lane];
        float2 v7 = x2[(size_t)s7 * 64 + lane];
        a0.x += (v0.x + v1.x) + (v2.x + v3.x);
        a0.y += (v0.y + v1.y) + (v2.y + v3.y);
        a1.x += (v4.x + v5.x) + (v6.x + v7.x);
        a1.y += (v4.y + v5.y) + (v6.y + v7.y);
    }
    for (; p < end; ++p) {
        int sn = srcs[p];
        float2 v = x2[(size_t)sn * 64 + lane];
        a0.x += v.x; a0.y += v.y;
    }
    a0.x += a1.x; a0.y += a1.y;
    y2[(size_t)w * 64 + lane] = a0;
}

// ---------------- GEMM K=19 (layer-0 first MLP, fp32) ----------------
template<int K, bool STATS>
__global__ __launch_bounds__(256) void k_gemm_small(const float* __restrict__ in, const float* __restrict__ W,
        const float* __restrict__ bias, float* __restrict__ out, float* __restrict__ ssum, float* __restrict__ ssq) {
    constexpr int SK = ((K + 3) / 4) * 4 + 4;
    __shared__ __align__(16) float yt[32 * SK];
    __shared__ float red[256];
    int tid = threadIdx.x;
    int row0 = blockIdx.x * 32;
    for (int t = tid; t < 32 * SK; t += 256) {
        int r = t / SK, k = t - r * SK;
        float v = 0.f;
        if (k < K) v = in[(size_t)(row0 + r) * K + k];
        yt[t] = v;
    }
    __syncthreads();
    int col = tid & 127;
    int rg = tid >> 7;
    float acc[16];
    #pragma unroll
    for (int r = 0; r < 16; r++) acc[r] = 0.f;
    const float* ybase = &yt[rg * 16 * SK];
    int kk = 0;
    for (; kk + 4 <= K; kk += 4) {
        float w0 = W[(kk + 0) * HH + col];
        float w1 = W[(kk + 1) * HH + col];
        float w2 = W[(kk + 2) * HH + col];
        float w3 = W[(kk + 3) * HH + col];
        #pragma unroll
        for (int r = 0; r < 16; r++) {
            const float4 v = *(const float4*)&ybase[r * SK + kk];
            acc[r] = fmaf(v.x, w0, acc[r]);
            acc[r] = fmaf(v.y, w1, acc[r]);
            acc[r] = fmaf(v.z, w2, acc[r]);
            acc[r] = fmaf(v.w, w3, acc[r]);
        }
    }
    if constexpr (K % 4 != 0) {
        float w[4];
        #pragma unroll
        for (int j = 0; j < 4; j++) w[j] = (kk + j < K) ? W[(kk + j) * HH + col] : 0.f;
        #pragma unroll
        for (int r = 0; r < 16; r++) {
            const float4 v = *(const float4*)&ybase[r * SK + kk];
            acc[r] = fmaf(v.x, w[0], acc[r]);
            acc[r] = fmaf(v.y, w[1], acc[r]);
            acc[r] = fmaf(v.z, w[2], acc[r]);
            acc[r] = fmaf(v.w, w[3], acc[r]);
        }
    }
    float bcol = bias[col];
    float s = 0.f, s2 = 0.f;
    #pragma unroll
    for (int r = 0; r < 16; r++) {
        float hv = acc[r] + bcol;
        out[(size_t)(row0 + rg * 16 + r) * HH + col] = hv;
        if (STATS) { s += hv; s2 = fmaf(hv, hv, s2); }
    }
    if (STATS) {
        red[tid] = s; __syncthreads();
        if (tid < 128) atomicAdd(&ssum[col], s + red[tid + 128]);
        __syncthreads();
        red[tid] = s2; __syncthreads();
        if (tid < 128) atomicAdd(&ssq[col], s2 + red[tid + 128]);
    }
}

// ---------------- K=128 GEMM via bf16 MFMA: 64 rows x 128 cols per block ----------------
// wave owns 64 rows x 32 cols: 4 row-tiles x 2 col-tiles of 16x16, K in 4 steps of 32.
// A staged fp32->bf16 in LDS (pad stride 136 => 2-way conflicts only).
// B read from pre-transposed bf16 WT[col][k] in global (L1-resident, 32KB).
template<bool STATS, bool BNIN, bool ELUOUT>
__global__ __launch_bounds__(256) void k_gemm_mfma(const float* __restrict__ in, const short* __restrict__ WT,
        const float* __restrict__ bias, const float* __restrict__ bnscale, const float* __restrict__ bnshift,
        float* __restrict__ out, float* __restrict__ ssum, float* __restrict__ ssq) {
    __shared__ __align__(16) short Al[64 * 136];
    __shared__ float lsum[HH], lsq[HH];
    int tid = threadIdx.x;
    int row0 = blockIdx.x * 64;
    if (STATS && tid < HH) { lsum[tid] = 0.f; lsq[tid] = 0.f; }
    // stage A: thread -> row = tid>>2, k0 = (tid&3)*32
    {
        int r = tid >> 2;
        int k0 = (tid & 3) * 32;
        int grow = row0 + r;
        short* dst = &Al[r * 136 + k0];
        if (grow < NN) {
            const float4* s4 = (const float4*)(in + (size_t)grow * HH + k0);
            #pragma unroll
            for (int j = 0; j < 8; j++) {
                float4 v = s4[j];
                if (BNIN) {
                    const float4 sc = *(const float4*)(bnscale + k0 + j * 4);
                    const float4 sh = *(const float4*)(bnshift + k0 + j * 4);
                    v.x = fmaxf(fmaf(v.x, sc.x, sh.x), 0.f);
                    v.y = fmaxf(fmaf(v.y, sc.y, sh.y), 0.f);
                    v.z = fmaxf(fmaf(v.z, sc.z, sh.z), 0.f);
                    v.w = fmaxf(fmaf(v.w, sc.w, sh.w), 0.f);
                }
                short4 b;
                b.x = f2bf(v.x); b.y = f2bf(v.y); b.z = f2bf(v.z); b.w = f2bf(v.w);
                *(short4*)(dst + j * 4) = b;
            }
        } else {
            short4 z = {0, 0, 0, 0};
            #pragma unroll
            for (int j = 0; j < 8; j++) *(short4*)(dst + j * 4) = z;
        }
    }
    __syncthreads();
    int wave = tid >> 6;
    int lane = tid & 63;
    int ln = lane & 15, quad = lane >> 4;
    int wcol0 = wave * 32;
    f32x4 acc[4][2];
    #pragma unroll
    for (int rt = 0; rt < 4; rt++)
        #pragma unroll
        for (int ct = 0; ct < 2; ct++) acc[rt][ct] = (f32x4){0.f, 0.f, 0.f, 0.f};
    #pragma unroll
    for (int ks = 0; ks < 4; ks++) {
        bf16x8 a[4], b[2];
        #pragma unroll
        for (int ct = 0; ct < 2; ct++)
            b[ct] = *(const bf16x8*)(WT + (size_t)(wcol0 + ct * 16 + ln) * HH + ks * 32 + quad * 8);
        #pragma unroll
        for (int rt = 0; rt < 4; rt++)
            a[rt] = *(const bf16x8*)(&Al[(rt * 16 + ln) * 136 + ks * 32 + quad * 8]);
        #pragma unroll
        for (int rt = 0; rt < 4; rt++)
            #pragma unroll
            for (int ct = 0; ct < 2; ct++)
                acc[rt][ct] = __builtin_amdgcn_mfma_f32_16x16x32_bf16(a[rt], b[ct], acc[rt][ct], 0, 0, 0);
    }
    float b0 = bias[wcol0 + ln];
    float b1 = bias[wcol0 + 16 + ln];
    float s[2] = {0.f, 0.f}, s2[2] = {0.f, 0.f};
    #pragma unroll
    for (int rt = 0; rt < 4; rt++) {
        #pragma unroll
        for (int r = 0; r < 4; r++) {
            int grow = row0 + rt * 16 + quad * 4 + r;
            if (grow < NN) {
                float hv0 = acc[rt][0][r] + b0;
                float hv1 = acc[rt][1][r] + b1;
                if (ELUOUT) { hv0 = elu01f(hv0); hv1 = elu01f(hv1); }
                out[(size_t)grow * HH + wcol0 + ln] = hv0;
                out[(size_t)grow * HH + wcol0 + 16 + ln] = hv1;
                if (STATS) {
                    s[0] += hv0; s2[0] = fmaf(hv0, hv0, s2[0]);
                    s[1] += hv1; s2[1] = fmaf(hv1, hv1, s2[1]);
                }
            }
        }
    }
    if (STATS) {
        atomicAdd(&lsum[wcol0 + ln], s[0]);
        atomicAdd(&lsum[wcol0 + 16 + ln], s[1]);
        atomicAdd(&lsq[wcol0 + ln], s2[0]);
        atomicAdd(&lsq[wcol0 + 16 + ln], s2[1]);
        __syncthreads();
        if (tid < HH) {
            atomicAdd(&ssum[tid], lsum[tid]);
            atomicAdd(&ssq[tid], lsq[tid]);
        }
    }
}

__global__ void k_bnfin(const float* ssum, const float* ssq, const float* __restrict__ gm,
                        const float* __restrict__ bt, float* scale, float* shift) {
    int c = threadIdx.x;
    float mu = ssum[c] * (1.f / NN);
    float var = fmaxf(ssq[c] * (1.f / NN) - mu * mu, 0.f);
    float a = gm[c] * rsqrtf(var + BN_EPS);
    scale[c] = a;
    shift[c] = fmaf(-mu, a, bt[c]);
}

// ---------------- pooling ----------------
__global__ __launch_bounds__(128) void k_pool_part(const float* __restrict__ x, const int* __restrict__ gptr,
                                                   float* __restrict__ psum, float* __restrict__ pmax) {
    int g = blockIdx.x >> 4;
    int ch = blockIdx.x & 15;
    int s = gptr[g], e = gptr[g + 1];
    int len = e - s;
    int per = (len + PCH - 1) / PCH;
    int lo = s + ch * per;
    int hi = min(lo + per, e);
    int c = threadIdx.x;
    float sm = 0.f, mx = -INFINITY;
    for (int i = lo; i < hi; ++i) {
        float v = x[(size_t)i * HH + c];
        sm += v; mx = fmaxf(mx, v);
    }
    psum[(size_t)blockIdx.x * HH + c] = sm;
    pmax[(size_t)blockIdx.x * HH + c] = mx;
}

__global__ __launch_bounds__(128) void k_pool_fin(const float* __restrict__ psum, const float* __restrict__ pmax,
                                                  const int* __restrict__ gptr, const float* __restrict__ g0,
                                                  float* __restrict__ z) {
    int g = blockIdx.x, c = threadIdx.x;
    float sm = 0.f, mx = -INFINITY;
    for (int ch = 0; ch < PCH; ++ch) {
        sm += psum[(size_t)(g * PCH + ch) * HH + c];
        mx = fmaxf(mx, pmax[(size_t)(g * PCH + ch) * HH + c]);
    }
    int cntn = gptr[g + 1] - gptr[g];
    float denom = (float)max(cntn, 1);
    z[g * 264 + c] = sm / denom;
    z[g * 264 + 128 + c] = mx;
    if (c < GG) z[g * 264 + 256 + c] = g0[g * GG + c];
}

// ---------------- classifier ----------------
__global__ __launch_bounds__(128) void k_cls1(const float* __restrict__ z, const float* __restrict__ cw1,
                                              const float* __restrict__ cb1, float* __restrict__ z1) {
    __shared__ float zr[264];
    int g = blockIdx.x, c = threadIdx.x;
    for (int t = c; t < 264; t += 128) zr[t] = z[g * 264 + t];
    __syncthreads();
    float acc = cb1[c];
    for (int k = 0; k < 264; ++k) acc = fmaf(zr[k], cw1[k * HH + c], acc);
    z1[g * HH + c] = elu01f(acc);
}

__global__ __launch_bounds__(128) void k_cls2(const float* __restrict__ z1, const float* __restrict__ cgm,
                                              const float* __restrict__ cbt, const float* __restrict__ cw2,
                                              const float* __restrict__ cb2, float* __restrict__ outp) {
    __shared__ float zn[HH * 65];
    int c = threadIdx.x;
    float s = 0.f, s2 = 0.f;
    for (int g = 0; g < BB; ++g) {
        float v = z1[g * HH + c];
        s += v; s2 = fmaf(v, v, s2);
    }
    float mu = s * (1.f / BB);
    float var = fmaxf(s2 * (1.f / BB) - mu * mu, 0.f);
    float a = cgm[c] * rsqrtf(var + BN_EPS);
    float sh = fmaf(-mu, a, cbt[c]);
    for (int g = 0; g < BB; ++g) zn[c * 65 + g] = fmaf(z1[g * HH + c], a, sh);
    __syncthreads();
    if (c < BB) {
        float l0 = cb2[0], l1 = cb2[1];
        for (int k = 0; k < HH; ++k) {
            float v = zn[k * 65 + c];
            l0 = fmaf(v, cw2[k * 2 + 0], l0);
            l1 = fmaf(v, cw2[k * 2 + 1], l1);
        }
        float m = fmaxf(l0, l1);
        float e0 = __expf(l0 - m), e1 = __expf(l1 - m);
        float inv = 1.f / (e0 + e1);
        outp[c * 2 + 0] = e0 * inv;
        outp[c * 2 + 1] = e1 * inv;
    }
}

extern "C" void kernel_launch(void* const* d_in, const int* in_sizes, int n_in,
                              void* d_out, int out_size, void* d_ws, size_t ws_size,
                              hipStream_t stream) {
    (void)in_sizes; (void)n_in; (void)out_size; (void)ws_size;
    const float* h0     = (const float*)d_in[0];
    const float* coord0 = (const float*)d_in[1];
    const float* g0     = (const float*)d_in[2];
    const int*   eidx   = (const int*)d_in[3];
    const int*   batch  = (const int*)d_in[4];
    const float* w1_0   = (const float*)d_in[5];
    const float* b1_0   = (const float*)d_in[6];
    const float* gm_0   = (const float*)d_in[7];
    const float* bt_0   = (const float*)d_in[8];
    const float* w2_0   = (const float*)d_in[9];
    const float* b2_0   = (const float*)d_in[10];
    const float* w1_r   = (const float*)d_in[11];
    const float* b1_r   = (const float*)d_in[12];
    const float* gm_r   = (const float*)d_in[13];
    const float* bt_r   = (const float*)d_in[14];
    const float* w2_r   = (const float*)d_in[15];
    const float* b2_r   = (const float*)d_in[16];
    const float* cw1    = (const float*)d_in[17];
    const float* cb1    = (const float*)d_in[18];
    const float* cgm    = (const float*)d_in[19];
    const float* cbt    = (const float*)d_in[20];
    const float* cw2    = (const float*)d_in[21];
    const float* cb2    = (const float*)d_in[22];
    float* outp = (float*)d_out;

    const int* esrc = eidx;
    const int* edst = eidx + EE;

    char* p = (char*)d_ws;
    auto alloc = [&](size_t bytes) { void* r = (void*)p; p += (bytes + 255) & ~(size_t)255; return r; };
    float* xb       = (float*)alloc((size_t)NN * HH * 4);
    float* yb       = (float*)alloc((size_t)NN * HH * 4);
    float* hb       = (float*)alloc((size_t)NN * HH * 4);
    int*   rp       = (int*)alloc((size_t)(NN + 1) * 4);
    int*   srcs     = (int*)alloc((size_t)EE * 4);
    int*   bincnt   = (int*)alloc((size_t)NBINS * 4);
    int*   binstart = (int*)alloc((size_t)NBINS * 4);
    int*   gptr     = (int*)alloc((BB + 1) * 4);
    short* wt       = (short*)alloc((size_t)5 * HH * HH * 2);
    float* bnstat   = (float*)alloc(2 * HH * 4);
    float* bnscale  = (float*)alloc(HH * 4);
    float* bnshift  = (float*)alloc(HH * 4);
    float* psum     = (float*)alloc((size_t)BB * PCH * HH * 4);
    float* pmax     = (float*)alloc((size_t)BB * PCH * HH * 4);
    float* zb       = (float*)alloc((size_t)BB * 264 * 4);
    float* z1b      = (float*)alloc((size_t)BB * HH * 4);
    uint2* binbuf   = (uint2*)yb;   // overlays yb (dead until k_agg_small)

    const int NB_A = (EE + ACH - 1) / ACH;          // 782
    const int NB_AGG = (NN * 64 + 255) / 256;       // 25000
    const int NB_G32 = NN / 32;                     // 3125
    const int NB_G64 = (NN + 63) / 64;              // 1563
    const int NB_X0 = (NN * K0 + 255) / 256;
    const int NB_WP = (5 * HH * HH + 255) / 256;    // 320

    // CSR build (LDS counting sort) + weight prep
    hipMemsetAsync(bincnt, 0, (size_t)NBINS * 4, stream);
    k_binA<<<NB_A, 256, 0, stream>>>(esrc, edst, bincnt, binbuf);
    k_binscan<<<1, 512, 0, stream>>>(bincnt, binstart, rp);
    k_binB<<<NBINS, 256, 0, stream>>>(binbuf, bincnt, binstart, rp, srcs);
    k_gptr<<<1, 128, 0, stream>>>(batch, gptr);
    k_wprep<<<NB_WP, 256, 0, stream>>>(w2_0, w1_r, w2_r, wt);

    // layer 0
    k_buildx0<<<NB_X0, 256, 0, stream>>>(h0, coord0, xb);
    k_agg_small<<<NB_AGG, 256, 0, stream>>>(xb, rp, srcs, yb);
    hipMemsetAsync(bnstat, 0, 2 * HH * 4, stream);
    k_gemm_small<K0, true><<<NB_G32, 256, 0, stream>>>(yb, w1_0, b1_0, hb, bnstat, bnstat + HH);
    k_bnfin<<<1, 128, 0, stream>>>(bnstat, bnstat + HH, gm_0, bt_0, bnscale, bnshift);
    k_gemm_mfma<false, true, true><<<NB_G64, 256, 0, stream>>>(hb, wt, b2_0, bnscale, bnshift,
                                                               xb, nullptr, nullptr);

    // layers 1..2
    for (int i = 0; i < 2; ++i) {
        k_agg128<<<NB_AGG, 256, 0, stream>>>(xb, rp, srcs, yb);
        hipMemsetAsync(bnstat, 0, 2 * HH * 4, stream);
        k_gemm_mfma<true, false, false><<<NB_G64, 256, 0, stream>>>(yb, wt + (size_t)(1 + i) * HH * HH,
                b1_r + i * HH, nullptr, nullptr, hb, bnstat, bnstat + HH);
        k_bnfin<<<1, 128, 0, stream>>>(bnstat, bnstat + HH, gm_r + i * HH, bt_r + i * HH, bnscale, bnshift);
        k_gemm_mfma<false, true, true><<<NB_G64, 256, 0, stream>>>(hb, wt + (size_t)(3 + i) * HH * HH,
                b2_r + i * HH, bnscale, bnshift, xb, nullptr, nullptr);
    }

    // pooling + classifier
    k_pool_part<<<BB * PCH, 128, 0, stream>>>(xb, gptr, psum, pmax);
    k_pool_fin<<<BB, 128, 0, stream>>>(psum, pmax, gptr, g0, zb);
    k_cls1<<<BB, 128, 0, stream>>>(zb, cw1, cb1, z1b);
    k_cls2<<<1, 128, 0, stream>>>(z1b, cgm, cbt, cw2, cb2, outp);
}

// Round 8
// 734.739 us; speedup vs baseline: 1.6252x; 1.1319x over previous
//
#include <hip/hip_runtime.h>
#include <math.h>

#define NN 100000
#define EE 1600000
#define BB 64
#define FF 16
#define HH 128
#define GG 8
#define K0 19
#define BN_EPS 1e-5f
#define PCH 16
#define BSHIFT 8
#define BNODES 256
#define NBINS 391          // ceil(NN/256)
#define BCAP 8192
#define ACH 2048           // edges per phase-A block

typedef short bf16x8 __attribute__((ext_vector_type(8)));
typedef float f32x4 __attribute__((ext_vector_type(4)));

__device__ __forceinline__ float elu01f(float v) {
    return v > 0.f ? v : 0.1f * (__expf(v) - 1.f);
}

__device__ __forceinline__ unsigned f2bfu(float f) {
    unsigned u = __float_as_uint(f);
    unsigned r = u + 0x7FFFu + ((u >> 16) & 1u);
    return r >> 16;
}
__device__ __forceinline__ short f2bf(float f) { return (short)f2bfu(f); }

// ---------------- CSR build: 2-phase LDS counting sort ----------------
__global__ __launch_bounds__(256) void k_binA(const int* __restrict__ esrc, const int* __restrict__ edst,
                                              int* __restrict__ bincnt, uint2* __restrict__ binbuf) {
    __shared__ int hist[NBINS];
    __shared__ int gbase[NBINS];
    __shared__ int cur[NBINS];
    __shared__ int sc[512];
    __shared__ uint2 ebuf[ACH];
    __shared__ uint2 sorted[ACH];
    int tid = threadIdx.x;
    int e0 = blockIdx.x * ACH;
    int n = min(ACH, EE - e0);
    for (int i = tid; i < NBINS; i += 256) hist[i] = 0;
    __syncthreads();
    for (int i = tid; i < n; i += 256) {
        int s = esrc[e0 + i];
        int d = edst[e0 + i];
        ebuf[i] = make_uint2((unsigned)s, (unsigned)d);
        atomicAdd(&hist[d >> BSHIFT], 1);
    }
    __syncthreads();
    sc[tid] = (tid < NBINS) ? hist[tid] : 0;
    sc[tid + 256] = (tid + 256 < NBINS) ? hist[tid + 256] : 0;
    __syncthreads();
    for (int off = 1; off < 512; off <<= 1) {
        int a0 = sc[tid], a1 = sc[tid + 256];
        int b0 = (tid >= off) ? sc[tid - off] : 0;
        int b1 = (tid + 256 >= off) ? sc[tid + 256 - off] : 0;
        __syncthreads();
        sc[tid] = a0 + b0;
        sc[tid + 256] = a1 + b1;
        __syncthreads();
    }
    for (int b = tid; b < NBINS; b += 256) {
        int c = hist[b];
        gbase[b] = (c > 0) ? atomicAdd(&bincnt[b], c) : 0;
        cur[b] = (b > 0) ? sc[b - 1] : 0;
    }
    __syncthreads();
    for (int i = tid; i < n; i += 256) {
        uint2 e = ebuf[i];
        int b = (int)(e.y >> BSHIFT);
        int pos = atomicAdd(&cur[b], 1);
        sorted[pos] = e;
    }
    __syncthreads();
    for (int i = tid; i < n; i += 256) {
        uint2 e = sorted[i];
        int b = (int)(e.y >> BSHIFT);
        int ls = (b > 0) ? sc[b - 1] : 0;
        int gpos = gbase[b] + (i - ls);
        binbuf[(size_t)b * BCAP + gpos] = e;
    }
}

__global__ void k_binscan(const int* __restrict__ bincnt, int* __restrict__ binstart, int* __restrict__ rp) {
    __shared__ int sc[512];
    int t = threadIdx.x;
    sc[t] = (t < NBINS) ? bincnt[t] : 0;
    __syncthreads();
    for (int off = 1; off < 512; off <<= 1) {
        int v = (t >= off) ? sc[t - off] : 0;
        __syncthreads();
        sc[t] += v;
        __syncthreads();
    }
    if (t < NBINS) binstart[t] = (t > 0) ? sc[t - 1] : 0;
    if (t == 0) rp[NN] = EE;
}

__global__ __launch_bounds__(256) void k_binB(const uint2* __restrict__ binbuf, const int* __restrict__ bincnt,
                                              const int* __restrict__ binstart,
                                              int* __restrict__ rp, int* __restrict__ srcs) {
    __shared__ int hist[BNODES];
    __shared__ int scx[BNODES];
    __shared__ int scur[BNODES];
    __shared__ int sbuf[BCAP];
    int b = blockIdx.x;
    int n = bincnt[b];
    int tid = threadIdx.x;
    hist[tid] = 0;
    __syncthreads();
    const uint2* eb = binbuf + (size_t)b * BCAP;
    for (int i = tid; i < n; i += 256)
        atomicAdd(&hist[eb[i].y & (BNODES - 1)], 1);
    __syncthreads();
    scx[tid] = hist[tid];
    __syncthreads();
    for (int off = 1; off < 256; off <<= 1) {
        int v = (tid >= off) ? scx[tid - off] : 0;
        __syncthreads();
        scx[tid] += v;
        __syncthreads();
    }
    int base = binstart[b];
    int excl = (tid > 0) ? scx[tid - 1] : 0;
    int node = (b << BSHIFT) + tid;
    if (node < NN) rp[node] = base + excl;
    scur[tid] = excl;
    __syncthreads();
    for (int i = tid; i < n; i += 256) {
        uint2 e = eb[i];
        int pos = atomicAdd(&scur[e.y & (BNODES - 1)], 1);
        sbuf[pos] = (int)e.x;
    }
    __syncthreads();
    for (int i = tid; i < n; i += 256) srcs[base + i] = sbuf[i];
}

__global__ void k_gptr(const int* __restrict__ batch, int* __restrict__ gptr) {
    int t = threadIdx.x;
    if (t > BB) return;
    int lo = 0, hi = NN;
    while (lo < hi) { int mid = (lo + hi) >> 1; if (batch[mid] < t) lo = mid + 1; else hi = mid; }
    gptr[t] = lo;
}

// ---------------- weight prep: fp32 [k][col] -> bf16 transposed [col][k] ----------------
__global__ __launch_bounds__(256) void k_wprep(const float* __restrict__ w2_0, const float* __restrict__ w1_r,
                                               const float* __restrict__ w2_r, short* __restrict__ wt) {
    int t = blockIdx.x * 256 + threadIdx.x;
    if (t >= 5 * HH * HH) return;
    int m = t >> 14;
    int rem = t & 16383;
    int col = rem >> 7;
    int k = rem & 127;
    const float* src = (m == 0) ? w2_0 : (m <= 2 ? w1_r + (size_t)(m - 1) * HH * HH
                                                 : w2_r + (size_t)(m - 3) * HH * HH);
    wt[t] = f2bf(src[k * HH + col]);
}

// ---------------- feature build + aggregation ----------------
__global__ __launch_bounds__(256) void k_buildx0(const float* __restrict__ h0, const float* __restrict__ coord,
                                                 float* __restrict__ x0) {
    int i = blockIdx.x * 256 + threadIdx.x;
    if (i >= NN * K0) return;
    int node = i / K0, k = i - node * K0;
    x0[i] = (k < FF) ? h0[node * FF + k] : coord[node * 3 + (k - FF)];
}

__global__ __launch_bounds__(256) void k_agg_small(const float* __restrict__ x, const int* __restrict__ rp,
                                                   const int* __restrict__ srcs, float* __restrict__ y) {
    int w = (blockIdx.x * 256 + threadIdx.x) >> 6;
    int lane = threadIdx.x & 63;
    if (w >= NN) return;
    int beg = rp[w], end = rp[w + 1];
    bool act = lane < K0;
    size_t li = act ? (size_t)lane : 0;
    float acc0 = 0.f, acc1 = 0.f;
    if (act) acc0 = x[(size_t)w * K0 + li];
    int p = beg;
    for (; p + 8 <= end; p += 8) {
        int s0 = srcs[p + 0], s1 = srcs[p + 1], s2 = srcs[p + 2], s3 = srcs[p + 3];
        int s4 = srcs[p + 4], s5 = srcs[p + 5], s6 = srcs[p + 6], s7 = srcs[p + 7];
        float v0 = x[(size_t)s0 * K0 + li];
        float v1 = x[(size_t)s1 * K0 + li];
        float v2 = x[(size_t)s2 * K0 + li];
        float v3 = x[(size_t)s3 * K0 + li];
        float v4 = x[(size_t)s4 * K0 + li];
        float v5 = x[(size_t)s5 * K0 + li];
        float v6 = x[(size_t)s6 * K0 + li];
        float v7 = x[(size_t)s7 * K0 + li];
        acc0 += (v0 + v1) + (v2 + v3);
        acc1 += (v4 + v5) + (v6 + v7);
    }
    for (; p < end; ++p) {
        int sn = srcs[p];
        acc0 += x[(size_t)sn * K0 + li];
    }
    if (act) y[(size_t)w * K0 + lane] = acc0 + acc1;
}

// bf16 aggregation: x rows are 128 bf16 = 64 uints; lane owns uint 'lane' (2 channels)
__global__ __launch_bounds__(256) void k_agg128_bf(const unsigned* __restrict__ x, const int* __restrict__ rp,
                                                   const int* __restrict__ srcs, unsigned* __restrict__ y) {
    int w = (blockIdx.x * 256 + threadIdx.x) >> 6;
    int lane = threadIdx.x & 63;
    if (w >= NN) return;
    int beg = rp[w], end = rp[w + 1];
    unsigned us = x[(size_t)w * 64 + lane];
    float ax = __uint_as_float(us << 16);
    float ay = __uint_as_float(us & 0xffff0000u);
    float bx = 0.f, by = 0.f;
    int p = beg;
    for (; p + 8 <= end; p += 8) {
        int s0 = srcs[p + 0], s1 = srcs[p + 1], s2 = srcs[p + 2], s3 = srcs[p + 3];
        int s4 = srcs[p + 4], s5 = srcs[p + 5], s6 = srcs[p + 6], s7 = srcs[p + 7];
        unsigned u0 = x[(size_t)s0 * 64 + lane];
        unsigned u1 = x[(size_t)s1 * 64 + lane];
        unsigned u2 = x[(size_t)s2 * 64 + lane];
        unsigned u3 = x[(size_t)s3 * 64 + lane];
        unsigned u4 = x[(size_t)s4 * 64 + lane];
        unsigned u5 = x[(size_t)s5 * 64 + lane];
        unsigned u6 = x[(size_t)s6 * 64 + lane];
        unsigned u7 = x[(size_t)s7 * 64 + lane];
        ax += (__uint_as_float(u0 << 16) + __uint_as_float(u1 << 16))
            + (__uint_as_float(u2 << 16) + __uint_as_float(u3 << 16));
        ay += (__uint_as_float(u0 & 0xffff0000u) + __uint_as_float(u1 & 0xffff0000u))
            + (__uint_as_float(u2 & 0xffff0000u) + __uint_as_float(u3 & 0xffff0000u));
        bx += (__uint_as_float(u4 << 16) + __uint_as_float(u5 << 16))
            + (__uint_as_float(u6 << 16) + __uint_as_float(u7 << 16));
        by += (__uint_as_float(u4 & 0xffff0000u) + __uint_as_float(u5 & 0xffff0000u))
            + (__uint_as_float(u6 & 0xffff0000u) + __uint_as_float(u7 & 0xffff0000u));
    }
    for (; p < end; ++p) {
        unsigned u = x[(size_t)srcs[p] * 64 + lane];
        ax += __uint_as_float(u << 16);
        ay += __uint_as_float(u & 0xffff0000u);
    }
    ax += bx; ay += by;
    y[(size_t)w * 64 + lane] = f2bfu(ax) | (f2bfu(ay) << 16);
}

// ---------------- GEMM K=19 (layer-0 first MLP, fp32) ----------------
template<int K, bool STATS>
__global__ __launch_bounds__(256) void k_gemm_small(const float* __restrict__ in, const float* __restrict__ W,
        const float* __restrict__ bias, float* __restrict__ out, float* __restrict__ ssum, float* __restrict__ ssq) {
    constexpr int SK = ((K + 3) / 4) * 4 + 4;
    __shared__ __align__(16) float yt[32 * SK];
    __shared__ float red[256];
    int tid = threadIdx.x;
    int row0 = blockIdx.x * 32;
    for (int t = tid; t < 32 * SK; t += 256) {
        int r = t / SK, k = t - r * SK;
        float v = 0.f;
        if (k < K) v = in[(size_t)(row0 + r) * K + k];
        yt[t] = v;
    }
    __syncthreads();
    int col = tid & 127;
    int rg = tid >> 7;
    float acc[16];
    #pragma unroll
    for (int r = 0; r < 16; r++) acc[r] = 0.f;
    const float* ybase = &yt[rg * 16 * SK];
    int kk = 0;
    for (; kk + 4 <= K; kk += 4) {
        float w0 = W[(kk + 0) * HH + col];
        float w1 = W[(kk + 1) * HH + col];
        float w2 = W[(kk + 2) * HH + col];
        float w3 = W[(kk + 3) * HH + col];
        #pragma unroll
        for (int r = 0; r < 16; r++) {
            const float4 v = *(const float4*)&ybase[r * SK + kk];
            acc[r] = fmaf(v.x, w0, acc[r]);
            acc[r] = fmaf(v.y, w1, acc[r]);
            acc[r] = fmaf(v.z, w2, acc[r]);
            acc[r] = fmaf(v.w, w3, acc[r]);
        }
    }
    if constexpr (K % 4 != 0) {
        float w[4];
        #pragma unroll
        for (int j = 0; j < 4; j++) w[j] = (kk + j < K) ? W[(kk + j) * HH + col] : 0.f;
        #pragma unroll
        for (int r = 0; r < 16; r++) {
            const float4 v = *(const float4*)&ybase[r * SK + kk];
            acc[r] = fmaf(v.x, w[0], acc[r]);
            acc[r] = fmaf(v.y, w[1], acc[r]);
            acc[r] = fmaf(v.z, w[2], acc[r]);
            acc[r] = fmaf(v.w, w[3], acc[r]);
        }
    }
    float bcol = bias[col];
    float s = 0.f, s2 = 0.f;
    #pragma unroll
    for (int r = 0; r < 16; r++) {
        float hv = acc[r] + bcol;
        out[(size_t)(row0 + rg * 16 + r) * HH + col] = hv;
        if (STATS) { s += hv; s2 = fmaf(hv, hv, s2); }
    }
    if (STATS) {
        red[tid] = s; __syncthreads();
        if (tid < 128) atomicAdd(&ssum[col], s + red[tid + 128]);
        __syncthreads();
        red[tid] = s2; __syncthreads();
        if (tid < 128) atomicAdd(&ssq[col], s2 + red[tid + 128]);
    }
}

// ---------------- K=128 GEMM via bf16 MFMA: 64 rows x 128 cols per block ----------------
// ABF16: A input already bf16 (direct LDS copy). OUTBF16: write bf16 activations.
template<bool STATS, bool BNIN, bool ELUOUT, bool ABF16, bool OUTBF16>
__global__ __launch_bounds__(256) void k_gemm_mfma(const void* __restrict__ in, const short* __restrict__ WT,
        const float* __restrict__ bias, const float* __restrict__ bnscale, const float* __restrict__ bnshift,
        void* __restrict__ out, float* __restrict__ ssum, float* __restrict__ ssq) {
    __shared__ __align__(16) short Al[64 * 136];
    __shared__ float lsum[HH], lsq[HH];
    int tid = threadIdx.x;
    int row0 = blockIdx.x * 64;
    if (STATS && tid < HH) { lsum[tid] = 0.f; lsq[tid] = 0.f; }
    // stage A: thread -> row = tid>>2, k0 = (tid&3)*32
    {
        int r = tid >> 2;
        int k0 = (tid & 3) * 32;
        int grow = row0 + r;
        short* dst = &Al[r * 136 + k0];
        if (grow < NN) {
            if constexpr (ABF16) {
                const int4* s4 = (const int4*)((const short*)in + (size_t)grow * HH + k0);
                int4* d4 = (int4*)dst;
                d4[0] = s4[0]; d4[1] = s4[1]; d4[2] = s4[2]; d4[3] = s4[3];
            } else {
                const float4* s4 = (const float4*)((const float*)in + (size_t)grow * HH + k0);
                #pragma unroll
                for (int j = 0; j < 8; j++) {
                    float4 v = s4[j];
                    if (BNIN) {
                        const float4 sc = *(const float4*)(bnscale + k0 + j * 4);
                        const float4 sh = *(const float4*)(bnshift + k0 + j * 4);
                        v.x = fmaxf(fmaf(v.x, sc.x, sh.x), 0.f);
                        v.y = fmaxf(fmaf(v.y, sc.y, sh.y), 0.f);
                        v.z = fmaxf(fmaf(v.z, sc.z, sh.z), 0.f);
                        v.w = fmaxf(fmaf(v.w, sc.w, sh.w), 0.f);
                    }
                    short4 b;
                    b.x = f2bf(v.x); b.y = f2bf(v.y); b.z = f2bf(v.z); b.w = f2bf(v.w);
                    *(short4*)(dst + j * 4) = b;
                }
            }
        } else {
            int4 z = {0, 0, 0, 0};
            int4* d4 = (int4*)dst;
            d4[0] = z; d4[1] = z; d4[2] = z; d4[3] = z;
        }
    }
    __syncthreads();
    int wave = tid >> 6;
    int lane = tid & 63;
    int ln = lane & 15, quad = lane >> 4;
    int wcol0 = wave * 32;
    f32x4 acc[4][2];
    #pragma unroll
    for (int rt = 0; rt < 4; rt++)
        #pragma unroll
        for (int ct = 0; ct < 2; ct++) acc[rt][ct] = (f32x4){0.f, 0.f, 0.f, 0.f};
    #pragma unroll
    for (int ks = 0; ks < 4; ks++) {
        bf16x8 a[4], b[2];
        #pragma unroll
        for (int ct = 0; ct < 2; ct++)
            b[ct] = *(const bf16x8*)(WT + (size_t)(wcol0 + ct * 16 + ln) * HH + ks * 32 + quad * 8);
        #pragma unroll
        for (int rt = 0; rt < 4; rt++)
            a[rt] = *(const bf16x8*)(&Al[(rt * 16 + ln) * 136 + ks * 32 + quad * 8]);
        #pragma unroll
        for (int rt = 0; rt < 4; rt++)
            #pragma unroll
            for (int ct = 0; ct < 2; ct++)
                acc[rt][ct] = __builtin_amdgcn_mfma_f32_16x16x32_bf16(a[rt], b[ct], acc[rt][ct], 0, 0, 0);
    }
    float b0 = bias[wcol0 + ln];
    float b1 = bias[wcol0 + 16 + ln];
    float s[2] = {0.f, 0.f}, s2[2] = {0.f, 0.f};
    #pragma unroll
    for (int rt = 0; rt < 4; rt++) {
        #pragma unroll
        for (int r = 0; r < 4; r++) {
            int grow = row0 + rt * 16 + quad * 4 + r;
            if (grow < NN) {
                float hv0 = acc[rt][0][r] + b0;
                float hv1 = acc[rt][1][r] + b1;
                if (ELUOUT) { hv0 = elu01f(hv0); hv1 = elu01f(hv1); }
                if constexpr (OUTBF16) {
                    unsigned short* ob = (unsigned short*)out;
                    ob[(size_t)grow * HH + wcol0 + ln] = (unsigned short)f2bfu(hv0);
                    ob[(size_t)grow * HH + wcol0 + 16 + ln] = (unsigned short)f2bfu(hv1);
                } else {
                    float* of = (float*)out;
                    of[(size_t)grow * HH + wcol0 + ln] = hv0;
                    of[(size_t)grow * HH + wcol0 + 16 + ln] = hv1;
                }
                if (STATS) {
                    s[0] += hv0; s2[0] = fmaf(hv0, hv0, s2[0]);
                    s[1] += hv1; s2[1] = fmaf(hv1, hv1, s2[1]);
                }
            }
        }
    }
    if (STATS) {
        atomicAdd(&lsum[wcol0 + ln], s[0]);
        atomicAdd(&lsum[wcol0 + 16 + ln], s[1]);
        atomicAdd(&lsq[wcol0 + ln], s2[0]);
        atomicAdd(&lsq[wcol0 + 16 + ln], s2[1]);
        __syncthreads();
        if (tid < HH) {
            atomicAdd(&ssum[tid], lsum[tid]);
            atomicAdd(&ssq[tid], lsq[tid]);
        }
    }
}

__global__ void k_bnfin(const float* ssum, const float* ssq, const float* __restrict__ gm,
                        const float* __restrict__ bt, float* scale, float* shift) {
    int c = threadIdx.x;
    float mu = ssum[c] * (1.f / NN);
    float var = fmaxf(ssq[c] * (1.f / NN) - mu * mu, 0.f);
    float a = gm[c] * rsqrtf(var + BN_EPS);
    scale[c] = a;
    shift[c] = fmaf(-mu, a, bt[c]);
}

// ---------------- pooling ----------------
__global__ __launch_bounds__(128) void k_pool_part(const float* __restrict__ x, const int* __restrict__ gptr,
                                                   float* __restrict__ psum, float* __restrict__ pmax) {
    int g = blockIdx.x >> 4;
    int ch = blockIdx.x & 15;
    int s = gptr[g], e = gptr[g + 1];
    int len = e - s;
    int per = (len + PCH - 1) / PCH;
    int lo = s + ch * per;
    int hi = min(lo + per, e);
    int c = threadIdx.x;
    float sm = 0.f, mx = -INFINITY;
    for (int i = lo; i < hi; ++i) {
        float v = x[(size_t)i * HH + c];
        sm += v; mx = fmaxf(mx, v);
    }
    psum[(size_t)blockIdx.x * HH + c] = sm;
    pmax[(size_t)blockIdx.x * HH + c] = mx;
}

__global__ __launch_bounds__(128) void k_pool_fin(const float* __restrict__ psum, const float* __restrict__ pmax,
                                                  const int* __restrict__ gptr, const float* __restrict__ g0,
                                                  float* __restrict__ z) {
    int g = blockIdx.x, c = threadIdx.x;
    float sm = 0.f, mx = -INFINITY;
    for (int ch = 0; ch < PCH; ++ch) {
        sm += psum[(size_t)(g * PCH + ch) * HH + c];
        mx = fmaxf(mx, pmax[(size_t)(g * PCH + ch) * HH + c]);
    }
    int cntn = gptr[g + 1] - gptr[g];
    float denom = (float)max(cntn, 1);
    z[g * 264 + c] = sm / denom;
    z[g * 264 + 128 + c] = mx;
    if (c < GG) z[g * 264 + 256 + c] = g0[g * GG + c];
}

// ---------------- classifier ----------------
__global__ __launch_bounds__(128) void k_cls1(const float* __restrict__ z, const float* __restrict__ cw1,
                                              const float* __restrict__ cb1, float* __restrict__ z1) {
    __shared__ float zr[264];
    int g = blockIdx.x, c = threadIdx.x;
    for (int t = c; t < 264; t += 128) zr[t] = z[g * 264 + t];
    __syncthreads();
    float acc = cb1[c];
    for (int k = 0; k < 264; ++k) acc = fmaf(zr[k], cw1[k * HH + c], acc);
    z1[g * HH + c] = elu01f(acc);
}

__global__ __launch_bounds__(128) void k_cls2(const float* __restrict__ z1, const float* __restrict__ cgm,
                                              const float* __restrict__ cbt, const float* __restrict__ cw2,
                                              const float* __restrict__ cb2, float* __restrict__ outp) {
    __shared__ float zn[HH * 65];
    int c = threadIdx.x;
    float s = 0.f, s2 = 0.f;
    for (int g = 0; g < BB; ++g) {
        float v = z1[g * HH + c];
        s += v; s2 = fmaf(v, v, s2);
    }
    float mu = s * (1.f / BB);
    float var = fmaxf(s2 * (1.f / BB) - mu * mu, 0.f);
    float a = cgm[c] * rsqrtf(var + BN_EPS);
    float sh = fmaf(-mu, a, cbt[c]);
    for (int g = 0; g < BB; ++g) zn[c * 65 + g] = fmaf(z1[g * HH + c], a, sh);
    __syncthreads();
    if (c < BB) {
        float l0 = cb2[0], l1 = cb2[1];
        for (int k = 0; k < HH; ++k) {
            float v = zn[k * 65 + c];
            l0 = fmaf(v, cw2[k * 2 + 0], l0);
            l1 = fmaf(v, cw2[k * 2 + 1], l1);
        }
        float m = fmaxf(l0, l1);
        float e0 = __expf(l0 - m), e1 = __expf(l1 - m);
        float inv = 1.f / (e0 + e1);
        outp[c * 2 + 0] = e0 * inv;
        outp[c * 2 + 1] = e1 * inv;
    }
}

extern "C" void kernel_launch(void* const* d_in, const int* in_sizes, int n_in,
                              void* d_out, int out_size, void* d_ws, size_t ws_size,
                              hipStream_t stream) {
    (void)in_sizes; (void)n_in; (void)out_size; (void)ws_size;
    const float* h0     = (const float*)d_in[0];
    const float* coord0 = (const float*)d_in[1];
    const float* g0     = (const float*)d_in[2];
    const int*   eidx   = (const int*)d_in[3];
    const int*   batch  = (const int*)d_in[4];
    const float* w1_0   = (const float*)d_in[5];
    const float* b1_0   = (const float*)d_in[6];
    const float* gm_0   = (const float*)d_in[7];
    const float* bt_0   = (const float*)d_in[8];
    const float* w2_0   = (const float*)d_in[9];
    const float* b2_0   = (const float*)d_in[10];
    const float* w1_r   = (const float*)d_in[11];
    const float* b1_r   = (const float*)d_in[12];
    const float* gm_r   = (const float*)d_in[13];
    const float* bt_r   = (const float*)d_in[14];
    const float* w2_r   = (const float*)d_in[15];
    const float* b2_r   = (const float*)d_in[16];
    const float* cw1    = (const float*)d_in[17];
    const float* cb1    = (const float*)d_in[18];
    const float* cgm    = (const float*)d_in[19];
    const float* cbt    = (const float*)d_in[20];
    const float* cw2    = (const float*)d_in[21];
    const float* cb2    = (const float*)d_in[22];
    float* outp = (float*)d_out;

    const int* esrc = eidx;
    const int* edst = eidx + EE;

    char* p = (char*)d_ws;
    auto alloc = [&](size_t bytes) { void* r = (void*)p; p += (bytes + 255) & ~(size_t)255; return r; };
    float*    xb       = (float*)alloc((size_t)NN * HH * 4);   // layer0 input (19d) + final fp32 output
    float*    yb19     = (float*)alloc((size_t)NN * K0 * 4);
    float*    hb       = (float*)alloc((size_t)NN * HH * 4);   // fp32 h; binbuf overlays
    unsigned* xbf      = (unsigned*)alloc((size_t)NN * 64 * 4);
    unsigned* ybf      = (unsigned*)alloc((size_t)NN * 64 * 4);
    int*      rp       = (int*)alloc((size_t)(NN + 1) * 4);
    int*      srcs     = (int*)alloc((size_t)EE * 4);
    int*      bincnt   = (int*)alloc((size_t)NBINS * 4);
    int*      binstart = (int*)alloc((size_t)NBINS * 4);
    int*      gptr     = (int*)alloc((BB + 1) * 4);
    short*    wt       = (short*)alloc((size_t)5 * HH * HH * 2);
    float*    bnstat   = (float*)alloc(2 * HH * 4);
    float*    bnscale  = (float*)alloc(HH * 4);
    float*    bnshift  = (float*)alloc(HH * 4);
    float*    psum     = (float*)alloc((size_t)BB * PCH * HH * 4);
    float*    pmax     = (float*)alloc((size_t)BB * PCH * HH * 4);
    float*    zb       = (float*)alloc((size_t)BB * 264 * 4);
    float*    z1b      = (float*)alloc((size_t)BB * HH * 4);
    uint2*    binbuf   = (uint2*)hb;   // overlays hb (hb first written after CSR build)

    const int NB_A = (EE + ACH - 1) / ACH;          // 782
    const int NB_AGG = (NN * 64 + 255) / 256;       // 25000
    const int NB_G32 = NN / 32;                     // 3125
    const int NB_G64 = (NN + 63) / 64;              // 1563
    const int NB_X0 = (NN * K0 + 255) / 256;
    const int NB_WP = (5 * HH * HH + 255) / 256;    // 320

    // CSR build (LDS counting sort) + weight prep
    hipMemsetAsync(bincnt, 0, (size_t)NBINS * 4, stream);
    k_binA<<<NB_A, 256, 0, stream>>>(esrc, edst, bincnt, binbuf);
    k_binscan<<<1, 512, 0, stream>>>(bincnt, binstart, rp);
    k_binB<<<NBINS, 256, 0, stream>>>(binbuf, bincnt, binstart, rp, srcs);
    k_gptr<<<1, 128, 0, stream>>>(batch, gptr);
    k_wprep<<<NB_WP, 256, 0, stream>>>(w2_0, w1_r, w2_r, wt);

    // layer 0 (fp32 path up to second MLP)
    k_buildx0<<<NB_X0, 256, 0, stream>>>(h0, coord0, xb);
    k_agg_small<<<NB_AGG, 256, 0, stream>>>(xb, rp, srcs, yb19);
    hipMemsetAsync(bnstat, 0, 2 * HH * 4, stream);
    k_gemm_small<K0, true><<<NB_G32, 256, 0, stream>>>(yb19, w1_0, b1_0, hb, bnstat, bnstat + HH);
    k_bnfin<<<1, 128, 0, stream>>>(bnstat, bnstat + HH, gm_0, bt_0, bnscale, bnshift);
    k_gemm_mfma<false, true, true, false, true><<<NB_G64, 256, 0, stream>>>(hb, wt, b2_0, bnscale, bnshift,
                                                                            xbf, nullptr, nullptr);

    // layers 1..2 (bf16 activations)
    for (int i = 0; i < 2; ++i) {
        k_agg128_bf<<<NB_AGG, 256, 0, stream>>>(xbf, rp, srcs, ybf);
        hipMemsetAsync(bnstat, 0, 2 * HH * 4, stream);
        k_gemm_mfma<true, false, false, true, false><<<NB_G64, 256, 0, stream>>>(ybf,
                wt + (size_t)(1 + i) * HH * HH, b1_r + i * HH, nullptr, nullptr, hb, bnstat, bnstat + HH);
        k_bnfin<<<1, 128, 0, stream>>>(bnstat, bnstat + HH, gm_r + i * HH, bt_r + i * HH, bnscale, bnshift);
        if (i == 0) {
            k_gemm_mfma<false, true, true, false, true><<<NB_G64, 256, 0, stream>>>(hb,
                    wt + (size_t)(3 + i) * HH * HH, b2_r + i * HH, bnscale, bnshift, xbf, nullptr, nullptr);
        } else {
            k_gemm_mfma<false, true, true, false, false><<<NB_G64, 256, 0, stream>>>(hb,
                    wt + (size_t)(3 + i) * HH * HH, b2_r + i * HH, bnscale, bnshift, xb, nullptr, nullptr);
        }
    }

    // pooling + classifier (fp32)
    k_pool_part<<<BB * PCH, 128, 0, stream>>>(xb, gptr, psum, pmax);
    k_pool_fin<<<BB, 128, 0, stream>>>(psum, pmax, gptr, g0, zb);
    k_cls1<<<BB, 128, 0, stream>>>(zb, cw1, cb1, z1b);
    k_cls2<<<1, 128, 0, stream>>>(z1b, cgm, cbt, cw2, cb2, outp);
}

// Round 9
// 641.168 us; speedup vs baseline: 1.8623x; 1.1459x over previous
//
#include <hip/hip_runtime.h>
#include <math.h>

#define NN 100000
#define EE 1600000
#define BB 64
#define FF 16
#define HH 128
#define GG 8
#define K0 19
#define BN_EPS 1e-5f
#define PCH 16
#define BSHIFT 8
#define BNODES 256
#define NBINS 391          // ceil(NN/256)
#define BCAP 8192
#define ACH 2048           // edges per phase-A block

typedef short bf16x8 __attribute__((ext_vector_type(8)));
typedef float f32x4 __attribute__((ext_vector_type(4)));

__device__ __forceinline__ float elu01f(float v) {
    return v > 0.f ? v : 0.1f * (__expf(v) - 1.f);
}

__device__ __forceinline__ unsigned f2bfu(float f) {
    unsigned u = __float_as_uint(f);
    unsigned r = u + 0x7FFFu + ((u >> 16) & 1u);
    return r >> 16;
}
__device__ __forceinline__ short f2bf(float f) { return (short)f2bfu(f); }

// ---------------- CSR build: 2-phase LDS counting sort ----------------
__global__ __launch_bounds__(256) void k_binA(const int* __restrict__ esrc, const int* __restrict__ edst,
                                              int* __restrict__ bincnt, uint2* __restrict__ binbuf) {
    __shared__ int hist[NBINS];
    __shared__ int gbase[NBINS];
    __shared__ int cur[NBINS];
    __shared__ int sc[512];
    __shared__ uint2 ebuf[ACH];
    __shared__ uint2 sorted[ACH];
    int tid = threadIdx.x;
    int e0 = blockIdx.x * ACH;
    int n = min(ACH, EE - e0);
    for (int i = tid; i < NBINS; i += 256) hist[i] = 0;
    __syncthreads();
    for (int i = tid; i < n; i += 256) {
        int s = esrc[e0 + i];
        int d = edst[e0 + i];
        ebuf[i] = make_uint2((unsigned)s, (unsigned)d);
        atomicAdd(&hist[d >> BSHIFT], 1);
    }
    __syncthreads();
    sc[tid] = (tid < NBINS) ? hist[tid] : 0;
    sc[tid + 256] = (tid + 256 < NBINS) ? hist[tid + 256] : 0;
    __syncthreads();
    for (int off = 1; off < 512; off <<= 1) {
        int a0 = sc[tid], a1 = sc[tid + 256];
        int b0 = (tid >= off) ? sc[tid - off] : 0;
        int b1 = (tid + 256 >= off) ? sc[tid + 256 - off] : 0;
        __syncthreads();
        sc[tid] = a0 + b0;
        sc[tid + 256] = a1 + b1;
        __syncthreads();
    }
    for (int b = tid; b < NBINS; b += 256) {
        int c = hist[b];
        gbase[b] = (c > 0) ? atomicAdd(&bincnt[b], c) : 0;
        cur[b] = (b > 0) ? sc[b - 1] : 0;
    }
    __syncthreads();
    for (int i = tid; i < n; i += 256) {
        uint2 e = ebuf[i];
        int b = (int)(e.y >> BSHIFT);
        int pos = atomicAdd(&cur[b], 1);
        sorted[pos] = e;
    }
    __syncthreads();
    for (int i = tid; i < n; i += 256) {
        uint2 e = sorted[i];
        int b = (int)(e.y >> BSHIFT);
        int ls = (b > 0) ? sc[b - 1] : 0;
        int gpos = gbase[b] + (i - ls);
        binbuf[(size_t)b * BCAP + gpos] = e;
    }
}

__global__ void k_binscan(const int* __restrict__ bincnt, int* __restrict__ binstart, int* __restrict__ rp) {
    __shared__ int sc[512];
    int t = threadIdx.x;
    sc[t] = (t < NBINS) ? bincnt[t] : 0;
    __syncthreads();
    for (int off = 1; off < 512; off <<= 1) {
        int v = (t >= off) ? sc[t - off] : 0;
        __syncthreads();
        sc[t] += v;
        __syncthreads();
    }
    if (t < NBINS) binstart[t] = (t > 0) ? sc[t - 1] : 0;
    if (t == 0) rp[NN] = EE;
}

__global__ __launch_bounds__(256) void k_binB(const uint2* __restrict__ binbuf, const int* __restrict__ bincnt,
                                              const int* __restrict__ binstart,
                                              int* __restrict__ rp, int* __restrict__ srcs) {
    __shared__ int hist[BNODES];
    __shared__ int scx[BNODES];
    __shared__ int scur[BNODES];
    __shared__ int sbuf[BCAP];
    int b = blockIdx.x;
    int n = bincnt[b];
    int tid = threadIdx.x;
    hist[tid] = 0;
    __syncthreads();
    const uint2* eb = binbuf + (size_t)b * BCAP;
    for (int i = tid; i < n; i += 256)
        atomicAdd(&hist[eb[i].y & (BNODES - 1)], 1);
    __syncthreads();
    scx[tid] = hist[tid];
    __syncthreads();
    for (int off = 1; off < 256; off <<= 1) {
        int v = (tid >= off) ? scx[tid - off] : 0;
        __syncthreads();
        scx[tid] += v;
        __syncthreads();
    }
    int base = binstart[b];
    int excl = (tid > 0) ? scx[tid - 1] : 0;
    int node = (b << BSHIFT) + tid;
    if (node < NN) rp[node] = base + excl;
    scur[tid] = excl;
    __syncthreads();
    for (int i = tid; i < n; i += 256) {
        uint2 e = eb[i];
        int pos = atomicAdd(&scur[e.y & (BNODES - 1)], 1);
        sbuf[pos] = (int)e.x;
    }
    __syncthreads();
    for (int i = tid; i < n; i += 256) srcs[base + i] = sbuf[i];
}

__global__ void k_gptr(const int* __restrict__ batch, int* __restrict__ gptr) {
    int t = threadIdx.x;
    if (t > BB) return;
    int lo = 0, hi = NN;
    while (lo < hi) { int mid = (lo + hi) >> 1; if (batch[mid] < t) lo = mid + 1; else hi = mid; }
    gptr[t] = lo;
}

// ---------------- weight prep: fp32 [k][col] -> bf16 transposed [col][k] ----------------
__global__ __launch_bounds__(256) void k_wprep(const float* __restrict__ w2_0, const float* __restrict__ w1_r,
                                               const float* __restrict__ w2_r, short* __restrict__ wt) {
    int t = blockIdx.x * 256 + threadIdx.x;
    if (t >= 5 * HH * HH) return;
    int m = t >> 14;
    int rem = t & 16383;
    int col = rem >> 7;
    int k = rem & 127;
    const float* src = (m == 0) ? w2_0 : (m <= 2 ? w1_r + (size_t)(m - 1) * HH * HH
                                                 : w2_r + (size_t)(m - 3) * HH * HH);
    wt[t] = f2bf(src[k * HH + col]);
}

// ---------------- feature build + aggregation ----------------
__global__ __launch_bounds__(256) void k_buildx0(const float* __restrict__ h0, const float* __restrict__ coord,
                                                 float* __restrict__ x0) {
    int i = blockIdx.x * 256 + threadIdx.x;
    if (i >= NN * K0) return;
    int node = i / K0, k = i - node * K0;
    x0[i] = (k < FF) ? h0[node * FF + k] : coord[node * 3 + (k - FF)];
}

__global__ __launch_bounds__(256) void k_agg_small(const float* __restrict__ x, const int* __restrict__ rp,
                                                   const int* __restrict__ srcs, float* __restrict__ y) {
    int w = (blockIdx.x * 256 + threadIdx.x) >> 6;
    int lane = threadIdx.x & 63;
    if (w >= NN) return;
    int beg = rp[w], end = rp[w + 1];
    bool act = lane < K0;
    size_t li = act ? (size_t)lane : 0;
    float acc0 = 0.f, acc1 = 0.f;
    if (act) acc0 = x[(size_t)w * K0 + li];
    int p = beg;
    for (; p + 8 <= end; p += 8) {
        int s0 = srcs[p + 0], s1 = srcs[p + 1], s2 = srcs[p + 2], s3 = srcs[p + 3];
        int s4 = srcs[p + 4], s5 = srcs[p + 5], s6 = srcs[p + 6], s7 = srcs[p + 7];
        float v0 = x[(size_t)s0 * K0 + li];
        float v1 = x[(size_t)s1 * K0 + li];
        float v2 = x[(size_t)s2 * K0 + li];
        float v3 = x[(size_t)s3 * K0 + li];
        float v4 = x[(size_t)s4 * K0 + li];
        float v5 = x[(size_t)s5 * K0 + li];
        float v6 = x[(size_t)s6 * K0 + li];
        float v7 = x[(size_t)s7 * K0 + li];
        acc0 += (v0 + v1) + (v2 + v3);
        acc1 += (v4 + v5) + (v6 + v7);
    }
    for (; p < end; ++p) {
        int sn = srcs[p];
        acc0 += x[(size_t)sn * K0 + li];
    }
    if (act) y[(size_t)w * K0 + lane] = acc0 + acc1;
}

// bf16 aggregation: x rows are 128 bf16 = 64 uints; lane owns uint 'lane' (2 channels)
__global__ __launch_bounds__(256) void k_agg128_bf(const unsigned* __restrict__ x, const int* __restrict__ rp,
                                                   const int* __restrict__ srcs, unsigned* __restrict__ y) {
    int w = (blockIdx.x * 256 + threadIdx.x) >> 6;
    int lane = threadIdx.x & 63;
    if (w >= NN) return;
    int beg = rp[w], end = rp[w + 1];
    unsigned us = x[(size_t)w * 64 + lane];
    float ax = __uint_as_float(us << 16);
    float ay = __uint_as_float(us & 0xffff0000u);
    float bx = 0.f, by = 0.f;
    int p = beg;
    for (; p + 8 <= end; p += 8) {
        int s0 = srcs[p + 0], s1 = srcs[p + 1], s2 = srcs[p + 2], s3 = srcs[p + 3];
        int s4 = srcs[p + 4], s5 = srcs[p + 5], s6 = srcs[p + 6], s7 = srcs[p + 7];
        unsigned u0 = x[(size_t)s0 * 64 + lane];
        unsigned u1 = x[(size_t)s1 * 64 + lane];
        unsigned u2 = x[(size_t)s2 * 64 + lane];
        unsigned u3 = x[(size_t)s3 * 64 + lane];
        unsigned u4 = x[(size_t)s4 * 64 + lane];
        unsigned u5 = x[(size_t)s5 * 64 + lane];
        unsigned u6 = x[(size_t)s6 * 64 + lane];
        unsigned u7 = x[(size_t)s7 * 64 + lane];
        ax += (__uint_as_float(u0 << 16) + __uint_as_float(u1 << 16))
            + (__uint_as_float(u2 << 16) + __uint_as_float(u3 << 16));
        ay += (__uint_as_float(u0 & 0xffff0000u) + __uint_as_float(u1 & 0xffff0000u))
            + (__uint_as_float(u2 & 0xffff0000u) + __uint_as_float(u3 & 0xffff0000u));
        bx += (__uint_as_float(u4 << 16) + __uint_as_float(u5 << 16))
            + (__uint_as_float(u6 << 16) + __uint_as_float(u7 << 16));
        by += (__uint_as_float(u4 & 0xffff0000u) + __uint_as_float(u5 & 0xffff0000u))
            + (__uint_as_float(u6 & 0xffff0000u) + __uint_as_float(u7 & 0xffff0000u));
    }
    for (; p < end; ++p) {
        unsigned u = x[(size_t)srcs[p] * 64 + lane];
        ax += __uint_as_float(u << 16);
        ay += __uint_as_float(u & 0xffff0000u);
    }
    ax += bx; ay += by;
    y[(size_t)w * 64 + lane] = f2bfu(ax) | (f2bfu(ay) << 16);
}

// ---------------- GEMM K=19 (layer-0 first MLP, fp32) ----------------
// STATS path: per-block partial row (256 floats: colsum | colsq), no global atomics.
template<int K, bool STATS>
__global__ __launch_bounds__(256) void k_gemm_small(const float* __restrict__ in, const float* __restrict__ W,
        const float* __restrict__ bias, float* __restrict__ out, float* __restrict__ part) {
    constexpr int SK = ((K + 3) / 4) * 4 + 4;
    __shared__ __align__(16) float yt[32 * SK];
    __shared__ float red[256];
    int tid = threadIdx.x;
    int row0 = blockIdx.x * 32;
    for (int t = tid; t < 32 * SK; t += 256) {
        int r = t / SK, k = t - r * SK;
        float v = 0.f;
        if (k < K) v = in[(size_t)(row0 + r) * K + k];
        yt[t] = v;
    }
    __syncthreads();
    int col = tid & 127;
    int rg = tid >> 7;
    float acc[16];
    #pragma unroll
    for (int r = 0; r < 16; r++) acc[r] = 0.f;
    const float* ybase = &yt[rg * 16 * SK];
    int kk = 0;
    for (; kk + 4 <= K; kk += 4) {
        float w0 = W[(kk + 0) * HH + col];
        float w1 = W[(kk + 1) * HH + col];
        float w2 = W[(kk + 2) * HH + col];
        float w3 = W[(kk + 3) * HH + col];
        #pragma unroll
        for (int r = 0; r < 16; r++) {
            const float4 v = *(const float4*)&ybase[r * SK + kk];
            acc[r] = fmaf(v.x, w0, acc[r]);
            acc[r] = fmaf(v.y, w1, acc[r]);
            acc[r] = fmaf(v.z, w2, acc[r]);
            acc[r] = fmaf(v.w, w3, acc[r]);
        }
    }
    if constexpr (K % 4 != 0) {
        float w[4];
        #pragma unroll
        for (int j = 0; j < 4; j++) w[j] = (kk + j < K) ? W[(kk + j) * HH + col] : 0.f;
        #pragma unroll
        for (int r = 0; r < 16; r++) {
            const float4 v = *(const float4*)&ybase[r * SK + kk];
            acc[r] = fmaf(v.x, w[0], acc[r]);
            acc[r] = fmaf(v.y, w[1], acc[r]);
            acc[r] = fmaf(v.z, w[2], acc[r]);
            acc[r] = fmaf(v.w, w[3], acc[r]);
        }
    }
    float bcol = bias[col];
    float s = 0.f, s2 = 0.f;
    #pragma unroll
    for (int r = 0; r < 16; r++) {
        float hv = acc[r] + bcol;
        out[(size_t)(row0 + rg * 16 + r) * HH + col] = hv;
        if (STATS) { s += hv; s2 = fmaf(hv, hv, s2); }
    }
    if (STATS) {
        red[tid] = s; __syncthreads();
        if (tid < 128) part[(size_t)blockIdx.x * 256 + tid] = s + red[tid + 128];
        __syncthreads();
        red[tid] = s2; __syncthreads();
        if (tid < 128) part[(size_t)blockIdx.x * 256 + 128 + tid] = s2 + red[tid + 128];
    }
}

// ---------------- K=128 GEMM via bf16 MFMA: 64 rows x 128 cols per block ----------------
template<bool STATS, bool BNIN, bool ELUOUT, bool ABF16, bool OUTBF16>
__global__ __launch_bounds__(256) void k_gemm_mfma(const void* __restrict__ in, const short* __restrict__ WT,
        const float* __restrict__ bias, const float* __restrict__ bnscale, const float* __restrict__ bnshift,
        void* __restrict__ out, float* __restrict__ part) {
    __shared__ __align__(16) short Al[64 * 136];
    __shared__ float lsum[HH], lsq[HH];
    int tid = threadIdx.x;
    int row0 = blockIdx.x * 64;
    if (STATS && tid < HH) { lsum[tid] = 0.f; lsq[tid] = 0.f; }
    {
        int r = tid >> 2;
        int k0 = (tid & 3) * 32;
        int grow = row0 + r;
        short* dst = &Al[r * 136 + k0];
        if (grow < NN) {
            if constexpr (ABF16) {
                const int4* s4 = (const int4*)((const short*)in + (size_t)grow * HH + k0);
                int4* d4 = (int4*)dst;
                d4[0] = s4[0]; d4[1] = s4[1]; d4[2] = s4[2]; d4[3] = s4[3];
            } else {
                const float4* s4 = (const float4*)((const float*)in + (size_t)grow * HH + k0);
                #pragma unroll
                for (int j = 0; j < 8; j++) {
                    float4 v = s4[j];
                    if (BNIN) {
                        const float4 sc = *(const float4*)(bnscale + k0 + j * 4);
                        const float4 sh = *(const float4*)(bnshift + k0 + j * 4);
                        v.x = fmaxf(fmaf(v.x, sc.x, sh.x), 0.f);
                        v.y = fmaxf(fmaf(v.y, sc.y, sh.y), 0.f);
                        v.z = fmaxf(fmaf(v.z, sc.z, sh.z), 0.f);
                        v.w = fmaxf(fmaf(v.w, sc.w, sh.w), 0.f);
                    }
                    short4 b;
                    b.x = f2bf(v.x); b.y = f2bf(v.y); b.z = f2bf(v.z); b.w = f2bf(v.w);
                    *(short4*)(dst + j * 4) = b;
                }
            }
        } else {
            int4 z = {0, 0, 0, 0};
            int4* d4 = (int4*)dst;
            d4[0] = z; d4[1] = z; d4[2] = z; d4[3] = z;
        }
    }
    __syncthreads();
    int wave = tid >> 6;
    int lane = tid & 63;
    int ln = lane & 15, quad = lane >> 4;
    int wcol0 = wave * 32;
    f32x4 acc[4][2];
    #pragma unroll
    for (int rt = 0; rt < 4; rt++)
        #pragma unroll
        for (int ct = 0; ct < 2; ct++) acc[rt][ct] = (f32x4){0.f, 0.f, 0.f, 0.f};
    #pragma unroll
    for (int ks = 0; ks < 4; ks++) {
        bf16x8 a[4], b[2];
        #pragma unroll
        for (int ct = 0; ct < 2; ct++)
            b[ct] = *(const bf16x8*)(WT + (size_t)(wcol0 + ct * 16 + ln) * HH + ks * 32 + quad * 8);
        #pragma unroll
        for (int rt = 0; rt < 4; rt++)
            a[rt] = *(const bf16x8*)(&Al[(rt * 16 + ln) * 136 + ks * 32 + quad * 8]);
        #pragma unroll
        for (int rt = 0; rt < 4; rt++)
            #pragma unroll
            for (int ct = 0; ct < 2; ct++)
                acc[rt][ct] = __builtin_amdgcn_mfma_f32_16x16x32_bf16(a[rt], b[ct], acc[rt][ct], 0, 0, 0);
    }
    float b0 = bias[wcol0 + ln];
    float b1 = bias[wcol0 + 16 + ln];
    float s[2] = {0.f, 0.f}, s2[2] = {0.f, 0.f};
    #pragma unroll
    for (int rt = 0; rt < 4; rt++) {
        #pragma unroll
        for (int r = 0; r < 4; r++) {
            int grow = row0 + rt * 16 + quad * 4 + r;
            if (grow < NN) {
                float hv0 = acc[rt][0][r] + b0;
                float hv1 = acc[rt][1][r] + b1;
                if (ELUOUT) { hv0 = elu01f(hv0); hv1 = elu01f(hv1); }
                if constexpr (OUTBF16) {
                    unsigned short* ob = (unsigned short*)out;
                    ob[(size_t)grow * HH + wcol0 + ln] = (unsigned short)f2bfu(hv0);
                    ob[(size_t)grow * HH + wcol0 + 16 + ln] = (unsigned short)f2bfu(hv1);
                } else {
                    float* of = (float*)out;
                    of[(size_t)grow * HH + wcol0 + ln] = hv0;
                    of[(size_t)grow * HH + wcol0 + 16 + ln] = hv1;
                }
                if (STATS) {
                    s[0] += hv0; s2[0] = fmaf(hv0, hv0, s2[0]);
                    s[1] += hv1; s2[1] = fmaf(hv1, hv1, s2[1]);
                }
            }
        }
    }
    if (STATS) {
        atomicAdd(&lsum[wcol0 + ln], s[0]);
        atomicAdd(&lsum[wcol0 + 16 + ln], s[1]);
        atomicAdd(&lsq[wcol0 + ln], s2[0]);
        atomicAdd(&lsq[wcol0 + 16 + ln], s2[1]);
        __syncthreads();
        if (tid < HH) {
            part[(size_t)blockIdx.x * 256 + tid] = lsum[tid];
            part[(size_t)blockIdx.x * 256 + 128 + tid] = lsq[tid];
        }
    }
}

// stage-1 stat reduce: 64 blocks fold nrows partial rows -> part2[64][256]
__global__ __launch_bounds__(256) void k_statred(const float* __restrict__ part, float* __restrict__ part2,
                                                 int nrows) {
    int tid = threadIdx.x;
    float acc = 0.f;
    for (int r = blockIdx.x; r < nrows; r += 64)
        acc += part[(size_t)r * 256 + tid];
    part2[(size_t)blockIdx.x * 256 + tid] = acc;
}

__global__ void k_bnfin(const float* __restrict__ part2, const float* __restrict__ gm,
                        const float* __restrict__ bt, float* scale, float* shift) {
    int c = threadIdx.x;
    float s = 0.f, s2 = 0.f;
    #pragma unroll 4
    for (int j = 0; j < 64; ++j) {
        s += part2[(size_t)j * 256 + c];
        s2 += part2[(size_t)j * 256 + 128 + c];
    }
    float mu = s * (1.f / NN);
    float var = fmaxf(s2 * (1.f / NN) - mu * mu, 0.f);
    float a = gm[c] * rsqrtf(var + BN_EPS);
    scale[c] = a;
    shift[c] = fmaf(-mu, a, bt[c]);
}

// ---------------- pooling ----------------
__global__ __launch_bounds__(128) void k_pool_part(const float* __restrict__ x, const int* __restrict__ gptr,
                                                   float* __restrict__ psum, float* __restrict__ pmax) {
    int g = blockIdx.x >> 4;
    int ch = blockIdx.x & 15;
    int s = gptr[g], e = gptr[g + 1];
    int len = e - s;
    int per = (len + PCH - 1) / PCH;
    int lo = s + ch * per;
    int hi = min(lo + per, e);
    int c = threadIdx.x;
    float sm = 0.f, mx = -INFINITY;
    for (int i = lo; i < hi; ++i) {
        float v = x[(size_t)i * HH + c];
        sm += v; mx = fmaxf(mx, v);
    }
    psum[(size_t)blockIdx.x * HH + c] = sm;
    pmax[(size_t)blockIdx.x * HH + c] = mx;
}

__global__ __launch_bounds__(128) void k_pool_fin(const float* __restrict__ psum, const float* __restrict__ pmax,
                                                  const int* __restrict__ gptr, const float* __restrict__ g0,
                                                  float* __restrict__ z) {
    int g = blockIdx.x, c = threadIdx.x;
    float sm = 0.f, mx = -INFINITY;
    for (int ch = 0; ch < PCH; ++ch) {
        sm += psum[(size_t)(g * PCH + ch) * HH + c];
        mx = fmaxf(mx, pmax[(size_t)(g * PCH + ch) * HH + c]);
    }
    int cntn = gptr[g + 1] - gptr[g];
    float denom = (float)max(cntn, 1);
    z[g * 264 + c] = sm / denom;
    z[g * 264 + 128 + c] = mx;
    if (c < GG) z[g * 264 + 256 + c] = g0[g * GG + c];
}

// ---------------- classifier ----------------
__global__ __launch_bounds__(128) void k_cls1(const float* __restrict__ z, const float* __restrict__ cw1,
                                              const float* __restrict__ cb1, float* __restrict__ z1) {
    __shared__ float zr[264];
    int g = blockIdx.x, c = threadIdx.x;
    for (int t = c; t < 264; t += 128) zr[t] = z[g * 264 + t];
    __syncthreads();
    float acc = cb1[c];
    for (int k = 0; k < 264; ++k) acc = fmaf(zr[k], cw1[k * HH + c], acc);
    z1[g * HH + c] = elu01f(acc);
}

__global__ __launch_bounds__(128) void k_cls2(const float* __restrict__ z1, const float* __restrict__ cgm,
                                              const float* __restrict__ cbt, const float* __restrict__ cw2,
                                              const float* __restrict__ cb2, float* __restrict__ outp) {
    __shared__ float zn[HH * 65];
    int c = threadIdx.x;
    float s = 0.f, s2 = 0.f;
    for (int g = 0; g < BB; ++g) {
        float v = z1[g * HH + c];
        s += v; s2 = fmaf(v, v, s2);
    }
    float mu = s * (1.f / BB);
    float var = fmaxf(s2 * (1.f / BB) - mu * mu, 0.f);
    float a = cgm[c] * rsqrtf(var + BN_EPS);
    float sh = fmaf(-mu, a, cbt[c]);
    for (int g = 0; g < BB; ++g) zn[c * 65 + g] = fmaf(z1[g * HH + c], a, sh);
    __syncthreads();
    if (c < BB) {
        float l0 = cb2[0], l1 = cb2[1];
        for (int k = 0; k < HH; ++k) {
            float v = zn[k * 65 + c];
            l0 = fmaf(v, cw2[k * 2 + 0], l0);
            l1 = fmaf(v, cw2[k * 2 + 1], l1);
        }
        float m = fmaxf(l0, l1);
        float e0 = __expf(l0 - m), e1 = __expf(l1 - m);
        float inv = 1.f / (e0 + e1);
        outp[c * 2 + 0] = e0 * inv;
        outp[c * 2 + 1] = e1 * inv;
    }
}

extern "C" void kernel_launch(void* const* d_in, const int* in_sizes, int n_in,
                              void* d_out, int out_size, void* d_ws, size_t ws_size,
                              hipStream_t stream) {
    (void)in_sizes; (void)n_in; (void)out_size; (void)ws_size;
    const float* h0     = (const float*)d_in[0];
    const float* coord0 = (const float*)d_in[1];
    const float* g0     = (const float*)d_in[2];
    const int*   eidx   = (const int*)d_in[3];
    const int*   batch  = (const int*)d_in[4];
    const float* w1_0   = (const float*)d_in[5];
    const float* b1_0   = (const float*)d_in[6];
    const float* gm_0   = (const float*)d_in[7];
    const float* bt_0   = (const float*)d_in[8];
    const float* w2_0   = (const float*)d_in[9];
    const float* b2_0   = (const float*)d_in[10];
    const float* w1_r   = (const float*)d_in[11];
    const float* b1_r   = (const float*)d_in[12];
    const float* gm_r   = (const float*)d_in[13];
    const float* bt_r   = (const float*)d_in[14];
    const float* w2_r   = (const float*)d_in[15];
    const float* b2_r   = (const float*)d_in[16];
    const float* cw1    = (const float*)d_in[17];
    const float* cb1    = (const float*)d_in[18];
    const float* cgm    = (const float*)d_in[19];
    const float* cbt    = (const float*)d_in[20];
    const float* cw2    = (const float*)d_in[21];
    const float* cb2    = (const float*)d_in[22];
    float* outp = (float*)d_out;

    const int* esrc = eidx;
    const int* edst = eidx + EE;

    char* p = (char*)d_ws;
    auto alloc = [&](size_t bytes) { void* r = (void*)p; p += (bytes + 255) & ~(size_t)255; return r; };
    float*    xb       = (float*)alloc((size_t)NN * HH * 4);   // layer0 input (19d) + final fp32 output
    float*    yb19     = (float*)alloc((size_t)NN * K0 * 4);
    float*    hb       = (float*)alloc((size_t)NN * HH * 4);   // fp32 h; binbuf overlays
    unsigned* xbf      = (unsigned*)alloc((size_t)NN * 64 * 4);
    unsigned* ybf      = (unsigned*)alloc((size_t)NN * 64 * 4);
    int*      rp       = (int*)alloc((size_t)(NN + 1) * 4);
    int*      srcs     = (int*)alloc((size_t)EE * 4);
    int*      bincnt   = (int*)alloc((size_t)NBINS * 4);
    int*      binstart = (int*)alloc((size_t)NBINS * 4);
    int*      gptr     = (int*)alloc((BB + 1) * 4);
    short*    wt       = (short*)alloc((size_t)5 * HH * HH * 2);
    float*    part     = (float*)alloc((size_t)3125 * 256 * 4);
    float*    part2    = (float*)alloc((size_t)64 * 256 * 4);
    float*    bnscale  = (float*)alloc(HH * 4);
    float*    bnshift  = (float*)alloc(HH * 4);
    float*    psum     = (float*)alloc((size_t)BB * PCH * HH * 4);
    float*    pmax     = (float*)alloc((size_t)BB * PCH * HH * 4);
    float*    zb       = (float*)alloc((size_t)BB * 264 * 4);
    float*    z1b      = (float*)alloc((size_t)BB * HH * 4);
    uint2*    binbuf   = (uint2*)hb;   // overlays hb (hb first written after CSR build)

    const int NB_A = (EE + ACH - 1) / ACH;          // 782
    const int NB_AGG = (NN * 64 + 255) / 256;       // 25000
    const int NB_G32 = NN / 32;                     // 3125
    const int NB_G64 = (NN + 63) / 64;              // 1563
    const int NB_X0 = (NN * K0 + 255) / 256;
    const int NB_WP = (5 * HH * HH + 255) / 256;    // 320

    // CSR build (LDS counting sort) + weight prep
    hipMemsetAsync(bincnt, 0, (size_t)NBINS * 4, stream);
    k_binA<<<NB_A, 256, 0, stream>>>(esrc, edst, bincnt, binbuf);
    k_binscan<<<1, 512, 0, stream>>>(bincnt, binstart, rp);
    k_binB<<<NBINS, 256, 0, stream>>>(binbuf, bincnt, binstart, rp, srcs);
    k_gptr<<<1, 128, 0, stream>>>(batch, gptr);
    k_wprep<<<NB_WP, 256, 0, stream>>>(w2_0, w1_r, w2_r, wt);

    // layer 0 (fp32 path up to second MLP)
    k_buildx0<<<NB_X0, 256, 0, stream>>>(h0, coord0, xb);
    k_agg_small<<<NB_AGG, 256, 0, stream>>>(xb, rp, srcs, yb19);
    k_gemm_small<K0, true><<<NB_G32, 256, 0, stream>>>(yb19, w1_0, b1_0, hb, part);
    k_statred<<<64, 256, 0, stream>>>(part, part2, NB_G32);
    k_bnfin<<<1, 128, 0, stream>>>(part2, gm_0, bt_0, bnscale, bnshift);
    k_gemm_mfma<false, true, true, false, true><<<NB_G64, 256, 0, stream>>>(hb, wt, b2_0, bnscale, bnshift,
                                                                            xbf, nullptr);

    // layers 1..2 (bf16 activations)
    for (int i = 0; i < 2; ++i) {
        k_agg128_bf<<<NB_AGG, 256, 0, stream>>>(xbf, rp, srcs, ybf);
        k_gemm_mfma<true, false, false, true, false><<<NB_G64, 256, 0, stream>>>(ybf,
                wt + (size_t)(1 + i) * HH * HH, b1_r + i * HH, nullptr, nullptr, hb, part);
        k_statred<<<64, 256, 0, stream>>>(part, part2, NB_G64);
        k_bnfin<<<1, 128, 0, stream>>>(part2, gm_r + i * HH, bt_r + i * HH, bnscale, bnshift);
        if (i == 0) {
            k_gemm_mfma<false, true, true, false, true><<<NB_G64, 256, 0, stream>>>(hb,
                    wt + (size_t)(3 + i) * HH * HH, b2_r + i * HH, bnscale, bnshift, xbf, nullptr);
        } else {
            k_gemm_mfma<false, true, true, false, false><<<NB_G64, 256, 0, stream>>>(hb,
                    wt + (size_t)(3 + i) * HH * HH, b2_r + i * HH, bnscale, bnshift, xb, nullptr);
        }
    }

    // pooling + classifier (fp32)
    k_pool_part<<<BB * PCH, 128, 0, stream>>>(xb, gptr, psum, pmax);
    k_pool_fin<<<BB, 128, 0, stream>>>(psum, pmax, gptr, g0, zb);
    k_cls1<<<BB, 128, 0, stream>>>(zb, cw1, cb1, z1b);
    k_cls2<<<1, 128, 0, stream>>>(z1b, cgm, cbt, cw2, cb2, outp);
}

// Round 10
// 636.082 us; speedup vs baseline: 1.8772x; 1.0080x over previous
//
#include <hip/hip_runtime.h>
#include <math.h>

#define NN 100000
#define EE 1600000
#define BB 64
#define FF 16
#define HH 128
#define GG 8
#define K0 19
#define BN_EPS 1e-5f
#define PCH 16
#define BSHIFT 8
#define BNODES 256
#define NBINS 391          // ceil(NN/256)
#define BCAP 8192
#define ACH 2048           // edges per phase-A block

typedef short bf16x8 __attribute__((ext_vector_type(8)));
typedef float f32x4 __attribute__((ext_vector_type(4)));

__device__ __forceinline__ float elu01f(float v) {
    return v > 0.f ? v : 0.1f * (__expf(v) - 1.f);
}

__device__ __forceinline__ unsigned f2bfu(float f) {
    unsigned u = __float_as_uint(f);
    unsigned r = u + 0x7FFFu + ((u >> 16) & 1u);
    return r >> 16;
}
__device__ __forceinline__ short f2bf(float f) { return (short)f2bfu(f); }
__device__ __forceinline__ float bfu2f(unsigned short b) {
    return __uint_as_float(((unsigned)b) << 16);
}

// ---------------- CSR build: 2-phase LDS counting sort ----------------
__global__ __launch_bounds__(256) void k_binA(const int* __restrict__ esrc, const int* __restrict__ edst,
                                              int* __restrict__ bincnt, uint2* __restrict__ binbuf) {
    __shared__ int hist[NBINS];
    __shared__ int gbase[NBINS];
    __shared__ int cur[NBINS];
    __shared__ int sc[512];
    __shared__ uint2 ebuf[ACH];
    __shared__ uint2 sorted[ACH];
    int tid = threadIdx.x;
    int e0 = blockIdx.x * ACH;
    int n = min(ACH, EE - e0);
    for (int i = tid; i < NBINS; i += 256) hist[i] = 0;
    __syncthreads();
    for (int i = tid; i < n; i += 256) {
        int s = esrc[e0 + i];
        int d = edst[e0 + i];
        ebuf[i] = make_uint2((unsigned)s, (unsigned)d);
        atomicAdd(&hist[d >> BSHIFT], 1);
    }
    __syncthreads();
    sc[tid] = (tid < NBINS) ? hist[tid] : 0;
    sc[tid + 256] = (tid + 256 < NBINS) ? hist[tid + 256] : 0;
    __syncthreads();
    for (int off = 1; off < 512; off <<= 1) {
        int a0 = sc[tid], a1 = sc[tid + 256];
        int b0 = (tid >= off) ? sc[tid - off] : 0;
        int b1 = (tid + 256 >= off) ? sc[tid + 256 - off] : 0;
        __syncthreads();
        sc[tid] = a0 + b0;
        sc[tid + 256] = a1 + b1;
        __syncthreads();
    }
    for (int b = tid; b < NBINS; b += 256) {
        int c = hist[b];
        gbase[b] = (c > 0) ? atomicAdd(&bincnt[b], c) : 0;
        cur[b] = (b > 0) ? sc[b - 1] : 0;
    }
    __syncthreads();
    for (int i = tid; i < n; i += 256) {
        uint2 e = ebuf[i];
        int b = (int)(e.y >> BSHIFT);
        int pos = atomicAdd(&cur[b], 1);
        sorted[pos] = e;
    }
    __syncthreads();
    for (int i = tid; i < n; i += 256) {
        uint2 e = sorted[i];
        int b = (int)(e.y >> BSHIFT);
        int ls = (b > 0) ? sc[b - 1] : 0;
        int gpos = gbase[b] + (i - ls);
        binbuf[(size_t)b * BCAP + gpos] = e;
    }
}

__global__ void k_binscan(const int* __restrict__ bincnt, int* __restrict__ binstart, int* __restrict__ rp) {
    __shared__ int sc[512];
    int t = threadIdx.x;
    sc[t] = (t < NBINS) ? bincnt[t] : 0;
    __syncthreads();
    for (int off = 1; off < 512; off <<= 1) {
        int v = (t >= off) ? sc[t - off] : 0;
        __syncthreads();
        sc[t] += v;
        __syncthreads();
    }
    if (t < NBINS) binstart[t] = (t > 0) ? sc[t - 1] : 0;
    if (t == 0) rp[NN] = EE;
}

__global__ __launch_bounds__(256) void k_binB(const uint2* __restrict__ binbuf, const int* __restrict__ bincnt,
                                              const int* __restrict__ binstart,
                                              int* __restrict__ rp, int* __restrict__ srcs) {
    __shared__ int hist[BNODES];
    __shared__ int scx[BNODES];
    __shared__ int scur[BNODES];
    __shared__ int sbuf[BCAP];
    int b = blockIdx.x;
    int n = bincnt[b];
    int tid = threadIdx.x;
    hist[tid] = 0;
    __syncthreads();
    const uint2* eb = binbuf + (size_t)b * BCAP;
    for (int i = tid; i < n; i += 256)
        atomicAdd(&hist[eb[i].y & (BNODES - 1)], 1);
    __syncthreads();
    scx[tid] = hist[tid];
    __syncthreads();
    for (int off = 1; off < 256; off <<= 1) {
        int v = (tid >= off) ? scx[tid - off] : 0;
        __syncthreads();
        scx[tid] += v;
        __syncthreads();
    }
    int base = binstart[b];
    int excl = (tid > 0) ? scx[tid - 1] : 0;
    int node = (b << BSHIFT) + tid;
    if (node < NN) rp[node] = base + excl;
    scur[tid] = excl;
    __syncthreads();
    for (int i = tid; i < n; i += 256) {
        uint2 e = eb[i];
        int pos = atomicAdd(&scur[e.y & (BNODES - 1)], 1);
        sbuf[pos] = (int)e.x;
    }
    __syncthreads();
    for (int i = tid; i < n; i += 256) srcs[base + i] = sbuf[i];
}

__global__ void k_gptr(const int* __restrict__ batch, int* __restrict__ gptr) {
    int t = threadIdx.x;
    if (t > BB) return;
    int lo = 0, hi = NN;
    while (lo < hi) { int mid = (lo + hi) >> 1; if (batch[mid] < t) lo = mid + 1; else hi = mid; }
    gptr[t] = lo;
}

// ---------------- weight prep: fp32 [k][col] -> bf16 transposed [col][k] ----------------
__global__ __launch_bounds__(256) void k_wprep(const float* __restrict__ w2_0, const float* __restrict__ w1_r,
                                               const float* __restrict__ w2_r, short* __restrict__ wt) {
    int t = blockIdx.x * 256 + threadIdx.x;
    if (t >= 5 * HH * HH) return;
    int m = t >> 14;
    int rem = t & 16383;
    int col = rem >> 7;
    int k = rem & 127;
    const float* src = (m == 0) ? w2_0 : (m <= 2 ? w1_r + (size_t)(m - 1) * HH * HH
                                                 : w2_r + (size_t)(m - 3) * HH * HH);
    wt[t] = f2bf(src[k * HH + col]);
}

// ---------------- feature build + aggregation ----------------
__global__ __launch_bounds__(256) void k_buildx0(const float* __restrict__ h0, const float* __restrict__ coord,
                                                 float* __restrict__ x0) {
    int i = blockIdx.x * 256 + threadIdx.x;
    if (i >= NN * K0) return;
    int node = i / K0, k = i - node * K0;
    x0[i] = (k < FF) ? h0[node * FF + k] : coord[node * 3 + (k - FF)];
}

__global__ __launch_bounds__(256) void k_agg_small(const float* __restrict__ x, const int* __restrict__ rp,
                                                   const int* __restrict__ srcs, float* __restrict__ y) {
    int w = (blockIdx.x * 256 + threadIdx.x) >> 6;
    int lane = threadIdx.x & 63;
    if (w >= NN) return;
    int beg = rp[w], end = rp[w + 1];
    bool act = lane < K0;
    size_t li = act ? (size_t)lane : 0;
    float acc0 = 0.f, acc1 = 0.f;
    if (act) acc0 = x[(size_t)w * K0 + li];
    int p = beg;
    for (; p + 8 <= end; p += 8) {
        int s0 = srcs[p + 0], s1 = srcs[p + 1], s2 = srcs[p + 2], s3 = srcs[p + 3];
        int s4 = srcs[p + 4], s5 = srcs[p + 5], s6 = srcs[p + 6], s7 = srcs[p + 7];
        float v0 = x[(size_t)s0 * K0 + li];
        float v1 = x[(size_t)s1 * K0 + li];
        float v2 = x[(size_t)s2 * K0 + li];
        float v3 = x[(size_t)s3 * K0 + li];
        float v4 = x[(size_t)s4 * K0 + li];
        float v5 = x[(size_t)s5 * K0 + li];
        float v6 = x[(size_t)s6 * K0 + li];
        float v7 = x[(size_t)s7 * K0 + li];
        acc0 += (v0 + v1) + (v2 + v3);
        acc1 += (v4 + v5) + (v6 + v7);
    }
    for (; p < end; ++p) {
        int sn = srcs[p];
        acc0 += x[(size_t)sn * K0 + li];
    }
    if (act) y[(size_t)w * K0 + lane] = acc0 + acc1;
}

// bf16 aggregation: x rows are 128 bf16 = 64 uints; lane owns uint 'lane' (2 channels)
// 16-deep unroll: 16 independent gathers in flight per wave (mean degree = 16)
__global__ __launch_bounds__(256) void k_agg128_bf(const unsigned* __restrict__ x, const int* __restrict__ rp,
                                                   const int* __restrict__ srcs, unsigned* __restrict__ y) {
    int w = (blockIdx.x * 256 + threadIdx.x) >> 6;
    int lane = threadIdx.x & 63;
    if (w >= NN) return;
    int beg = rp[w], end = rp[w + 1];
    unsigned us = x[(size_t)w * 64 + lane];
    float ax = __uint_as_float(us << 16);
    float ay = __uint_as_float(us & 0xffff0000u);
    float bx = 0.f, by = 0.f;
    float cx = 0.f, cy = 0.f;
    float dx = 0.f, dy = 0.f;
    int p = beg;
    for (; p + 16 <= end; p += 16) {
        int s0 = srcs[p + 0], s1 = srcs[p + 1], s2 = srcs[p + 2], s3 = srcs[p + 3];
        int s4 = srcs[p + 4], s5 = srcs[p + 5], s6 = srcs[p + 6], s7 = srcs[p + 7];
        int s8 = srcs[p + 8], s9 = srcs[p + 9], sa = srcs[p + 10], sb = srcs[p + 11];
        int sc_ = srcs[p + 12], sd = srcs[p + 13], se = srcs[p + 14], sf = srcs[p + 15];
        unsigned u0 = x[(size_t)s0 * 64 + lane];
        unsigned u1 = x[(size_t)s1 * 64 + lane];
        unsigned u2 = x[(size_t)s2 * 64 + lane];
        unsigned u3 = x[(size_t)s3 * 64 + lane];
        unsigned u4 = x[(size_t)s4 * 64 + lane];
        unsigned u5 = x[(size_t)s5 * 64 + lane];
        unsigned u6 = x[(size_t)s6 * 64 + lane];
        unsigned u7 = x[(size_t)s7 * 64 + lane];
        unsigned u8 = x[(size_t)s8 * 64 + lane];
        unsigned u9 = x[(size_t)s9 * 64 + lane];
        unsigned ua = x[(size_t)sa * 64 + lane];
        unsigned ub = x[(size_t)sb * 64 + lane];
        unsigned uc = x[(size_t)sc_ * 64 + lane];
        unsigned ud = x[(size_t)sd * 64 + lane];
        unsigned ue = x[(size_t)se * 64 + lane];
        unsigned uf = x[(size_t)sf * 64 + lane];
        ax += (__uint_as_float(u0 << 16) + __uint_as_float(u1 << 16))
            + (__uint_as_float(u2 << 16) + __uint_as_float(u3 << 16));
        ay += (__uint_as_float(u0 & 0xffff0000u) + __uint_as_float(u1 & 0xffff0000u))
            + (__uint_as_float(u2 & 0xffff0000u) + __uint_as_float(u3 & 0xffff0000u));
        bx += (__uint_as_float(u4 << 16) + __uint_as_float(u5 << 16))
            + (__uint_as_float(u6 << 16) + __uint_as_float(u7 << 16));
        by += (__uint_as_float(u4 & 0xffff0000u) + __uint_as_float(u5 & 0xffff0000u))
            + (__uint_as_float(u6 & 0xffff0000u) + __uint_as_float(u7 & 0xffff0000u));
        cx += (__uint_as_float(u8 << 16) + __uint_as_float(u9 << 16))
            + (__uint_as_float(ua << 16) + __uint_as_float(ub << 16));
        cy += (__uint_as_float(u8 & 0xffff0000u) + __uint_as_float(u9 & 0xffff0000u))
            + (__uint_as_float(ua & 0xffff0000u) + __uint_as_float(ub & 0xffff0000u));
        dx += (__uint_as_float(uc << 16) + __uint_as_float(ud << 16))
            + (__uint_as_float(ue << 16) + __uint_as_float(uf << 16));
        dy += (__uint_as_float(uc & 0xffff0000u) + __uint_as_float(ud & 0xffff0000u))
            + (__uint_as_float(ue & 0xffff0000u) + __uint_as_float(uf & 0xffff0000u));
    }
    for (; p + 8 <= end; p += 8) {
        int s0 = srcs[p + 0], s1 = srcs[p + 1], s2 = srcs[p + 2], s3 = srcs[p + 3];
        int s4 = srcs[p + 4], s5 = srcs[p + 5], s6 = srcs[p + 6], s7 = srcs[p + 7];
        unsigned u0 = x[(size_t)s0 * 64 + lane];
        unsigned u1 = x[(size_t)s1 * 64 + lane];
        unsigned u2 = x[(size_t)s2 * 64 + lane];
        unsigned u3 = x[(size_t)s3 * 64 + lane];
        unsigned u4 = x[(size_t)s4 * 64 + lane];
        unsigned u5 = x[(size_t)s5 * 64 + lane];
        unsigned u6 = x[(size_t)s6 * 64 + lane];
        unsigned u7 = x[(size_t)s7 * 64 + lane];
        ax += (__uint_as_float(u0 << 16) + __uint_as_float(u1 << 16))
            + (__uint_as_float(u2 << 16) + __uint_as_float(u3 << 16));
        ay += (__uint_as_float(u0 & 0xffff0000u) + __uint_as_float(u1 & 0xffff0000u))
            + (__uint_as_float(u2 & 0xffff0000u) + __uint_as_float(u3 & 0xffff0000u));
        bx += (__uint_as_float(u4 << 16) + __uint_as_float(u5 << 16))
            + (__uint_as_float(u6 << 16) + __uint_as_float(u7 << 16));
        by += (__uint_as_float(u4 & 0xffff0000u) + __uint_as_float(u5 & 0xffff0000u))
            + (__uint_as_float(u6 & 0xffff0000u) + __uint_as_float(u7 & 0xffff0000u));
    }
    for (; p < end; ++p) {
        unsigned u = x[(size_t)srcs[p] * 64 + lane];
        ax += __uint_as_float(u << 16);
        ay += __uint_as_float(u & 0xffff0000u);
    }
    ax += bx + cx + dx;
    ay += by + cy + dy;
    y[(size_t)w * 64 + lane] = f2bfu(ax) | (f2bfu(ay) << 16);
}

// ---------------- GEMM K=19 (layer-0 first MLP, fp32) ----------------
template<int K, bool STATS>
__global__ __launch_bounds__(256) void k_gemm_small(const float* __restrict__ in, const float* __restrict__ W,
        const float* __restrict__ bias, float* __restrict__ out, float* __restrict__ part) {
    constexpr int SK = ((K + 3) / 4) * 4 + 4;
    __shared__ __align__(16) float yt[32 * SK];
    __shared__ float red[256];
    int tid = threadIdx.x;
    int row0 = blockIdx.x * 32;
    for (int t = tid; t < 32 * SK; t += 256) {
        int r = t / SK, k = t - r * SK;
        float v = 0.f;
        if (k < K) v = in[(size_t)(row0 + r) * K + k];
        yt[t] = v;
    }
    __syncthreads();
    int col = tid & 127;
    int rg = tid >> 7;
    float acc[16];
    #pragma unroll
    for (int r = 0; r < 16; r++) acc[r] = 0.f;
    const float* ybase = &yt[rg * 16 * SK];
    int kk = 0;
    for (; kk + 4 <= K; kk += 4) {
        float w0 = W[(kk + 0) * HH + col];
        float w1 = W[(kk + 1) * HH + col];
        float w2 = W[(kk + 2) * HH + col];
        float w3 = W[(kk + 3) * HH + col];
        #pragma unroll
        for (int r = 0; r < 16; r++) {
            const float4 v = *(const float4*)&ybase[r * SK + kk];
            acc[r] = fmaf(v.x, w0, acc[r]);
            acc[r] = fmaf(v.y, w1, acc[r]);
            acc[r] = fmaf(v.z, w2, acc[r]);
            acc[r] = fmaf(v.w, w3, acc[r]);
        }
    }
    if constexpr (K % 4 != 0) {
        float w[4];
        #pragma unroll
        for (int j = 0; j < 4; j++) w[j] = (kk + j < K) ? W[(kk + j) * HH + col] : 0.f;
        #pragma unroll
        for (int r = 0; r < 16; r++) {
            const float4 v = *(const float4*)&ybase[r * SK + kk];
            acc[r] = fmaf(v.x, w[0], acc[r]);
            acc[r] = fmaf(v.y, w[1], acc[r]);
            acc[r] = fmaf(v.z, w[2], acc[r]);
            acc[r] = fmaf(v.w, w[3], acc[r]);
        }
    }
    float bcol = bias[col];
    float s = 0.f, s2 = 0.f;
    #pragma unroll
    for (int r = 0; r < 16; r++) {
        float hv = acc[r] + bcol;
        out[(size_t)(row0 + rg * 16 + r) * HH + col] = hv;
        if (STATS) { s += hv; s2 = fmaf(hv, hv, s2); }
    }
    if (STATS) {
        red[tid] = s; __syncthreads();
        if (tid < 128) part[(size_t)blockIdx.x * 256 + tid] = s + red[tid + 128];
        __syncthreads();
        red[tid] = s2; __syncthreads();
        if (tid < 128) part[(size_t)blockIdx.x * 256 + 128 + tid] = s2 + red[tid + 128];
    }
}

// ---------------- K=128 GEMM via bf16 MFMA: 64 rows x 128 cols per block ----------------
template<bool STATS, bool BNIN, bool ELUOUT, bool ABF16, bool OUTBF16>
__global__ __launch_bounds__(256) void k_gemm_mfma(const void* __restrict__ in, const short* __restrict__ WT,
        const float* __restrict__ bias, const float* __restrict__ bnscale, const float* __restrict__ bnshift,
        void* __restrict__ out, float* __restrict__ part) {
    __shared__ __align__(16) short Al[64 * 136];
    __shared__ float lsum[HH], lsq[HH];
    int tid = threadIdx.x;
    int row0 = blockIdx.x * 64;
    if (STATS && tid < HH) { lsum[tid] = 0.f; lsq[tid] = 0.f; }
    {
        int r = tid >> 2;
        int k0 = (tid & 3) * 32;
        int grow = row0 + r;
        short* dst = &Al[r * 136 + k0];
        if (grow < NN) {
            if constexpr (ABF16) {
                const int4* s4 = (const int4*)((const short*)in + (size_t)grow * HH + k0);
                int4* d4 = (int4*)dst;
                d4[0] = s4[0]; d4[1] = s4[1]; d4[2] = s4[2]; d4[3] = s4[3];
            } else {
                const float4* s4 = (const float4*)((const float*)in + (size_t)grow * HH + k0);
                #pragma unroll
                for (int j = 0; j < 8; j++) {
                    float4 v = s4[j];
                    if (BNIN) {
                        const float4 sc = *(const float4*)(bnscale + k0 + j * 4);
                        const float4 sh = *(const float4*)(bnshift + k0 + j * 4);
                        v.x = fmaxf(fmaf(v.x, sc.x, sh.x), 0.f);
                        v.y = fmaxf(fmaf(v.y, sc.y, sh.y), 0.f);
                        v.z = fmaxf(fmaf(v.z, sc.z, sh.z), 0.f);
                        v.w = fmaxf(fmaf(v.w, sc.w, sh.w), 0.f);
                    }
                    short4 b;
                    b.x = f2bf(v.x); b.y = f2bf(v.y); b.z = f2bf(v.z); b.w = f2bf(v.w);
                    *(short4*)(dst + j * 4) = b;
                }
            }
        } else {
            int4 z = {0, 0, 0, 0};
            int4* d4 = (int4*)dst;
            d4[0] = z; d4[1] = z; d4[2] = z; d4[3] = z;
        }
    }
    __syncthreads();
    int wave = tid >> 6;
    int lane = tid & 63;
    int ln = lane & 15, quad = lane >> 4;
    int wcol0 = wave * 32;
    f32x4 acc[4][2];
    #pragma unroll
    for (int rt = 0; rt < 4; rt++)
        #pragma unroll
        for (int ct = 0; ct < 2; ct++) acc[rt][ct] = (f32x4){0.f, 0.f, 0.f, 0.f};
    #pragma unroll
    for (int ks = 0; ks < 4; ks++) {
        bf16x8 a[4], b[2];
        #pragma unroll
        for (int ct = 0; ct < 2; ct++)
            b[ct] = *(const bf16x8*)(WT + (size_t)(wcol0 + ct * 16 + ln) * HH + ks * 32 + quad * 8);
        #pragma unroll
        for (int rt = 0; rt < 4; rt++)
            a[rt] = *(const bf16x8*)(&Al[(rt * 16 + ln) * 136 + ks * 32 + quad * 8]);
        #pragma unroll
        for (int rt = 0; rt < 4; rt++)
            #pragma unroll
            for (int ct = 0; ct < 2; ct++)
                acc[rt][ct] = __builtin_amdgcn_mfma_f32_16x16x32_bf16(a[rt], b[ct], acc[rt][ct], 0, 0, 0);
    }
    float b0 = bias[wcol0 + ln];
    float b1 = bias[wcol0 + 16 + ln];
    float s[2] = {0.f, 0.f}, s2[2] = {0.f, 0.f};
    #pragma unroll
    for (int rt = 0; rt < 4; rt++) {
        #pragma unroll
        for (int r = 0; r < 4; r++) {
            int grow = row0 + rt * 16 + quad * 4 + r;
            if (grow < NN) {
                float hv0 = acc[rt][0][r] + b0;
                float hv1 = acc[rt][1][r] + b1;
                if (ELUOUT) { hv0 = elu01f(hv0); hv1 = elu01f(hv1); }
                if constexpr (OUTBF16) {
                    unsigned short* ob = (unsigned short*)out;
                    ob[(size_t)grow * HH + wcol0 + ln] = (unsigned short)f2bfu(hv0);
                    ob[(size_t)grow * HH + wcol0 + 16 + ln] = (unsigned short)f2bfu(hv1);
                } else {
                    float* of = (float*)out;
                    of[(size_t)grow * HH + wcol0 + ln] = hv0;
                    of[(size_t)grow * HH + wcol0 + 16 + ln] = hv1;
                }
                if (STATS) {
                    s[0] += hv0; s2[0] = fmaf(hv0, hv0, s2[0]);
                    s[1] += hv1; s2[1] = fmaf(hv1, hv1, s2[1]);
                }
            }
        }
    }
    if (STATS) {
        atomicAdd(&lsum[wcol0 + ln], s[0]);
        atomicAdd(&lsum[wcol0 + 16 + ln], s[1]);
        atomicAdd(&lsq[wcol0 + ln], s2[0]);
        atomicAdd(&lsq[wcol0 + 16 + ln], s2[1]);
        __syncthreads();
        if (tid < HH) {
            part[(size_t)blockIdx.x * 256 + tid] = lsum[tid];
            part[(size_t)blockIdx.x * 256 + 128 + tid] = lsq[tid];
        }
    }
}

// stage-1 stat reduce: 64 blocks fold nrows partial rows -> part2[64][256]
__global__ __launch_bounds__(256) void k_statred(const float* __restrict__ part, float* __restrict__ part2,
                                                 int nrows) {
    int tid = threadIdx.x;
    float acc = 0.f;
    for (int r = blockIdx.x; r < nrows; r += 64)
        acc += part[(size_t)r * 256 + tid];
    part2[(size_t)blockIdx.x * 256 + tid] = acc;
}

__global__ void k_bnfin(const float* __restrict__ part2, const float* __restrict__ gm,
                        const float* __restrict__ bt, float* scale, float* shift) {
    int c = threadIdx.x;
    float s = 0.f, s2 = 0.f;
    #pragma unroll 4
    for (int j = 0; j < 64; ++j) {
        s += part2[(size_t)j * 256 + c];
        s2 += part2[(size_t)j * 256 + 128 + c];
    }
    float mu = s * (1.f / NN);
    float var = fmaxf(s2 * (1.f / NN) - mu * mu, 0.f);
    float a = gm[c] * rsqrtf(var + BN_EPS);
    scale[c] = a;
    shift[c] = fmaf(-mu, a, bt[c]);
}

// ---------------- pooling (bf16 input) ----------------
__global__ __launch_bounds__(128) void k_pool_part(const unsigned short* __restrict__ x,
                                                   const int* __restrict__ gptr,
                                                   float* __restrict__ psum, float* __restrict__ pmax) {
    int g = blockIdx.x >> 4;
    int ch = blockIdx.x & 15;
    int s = gptr[g], e = gptr[g + 1];
    int len = e - s;
    int per = (len + PCH - 1) / PCH;
    int lo = s + ch * per;
    int hi = min(lo + per, e);
    int c = threadIdx.x;
    float sm = 0.f, mx = -INFINITY;
    for (int i = lo; i < hi; ++i) {
        float v = bfu2f(x[(size_t)i * HH + c]);
        sm += v; mx = fmaxf(mx, v);
    }
    psum[(size_t)blockIdx.x * HH + c] = sm;
    pmax[(size_t)blockIdx.x * HH + c] = mx;
}

__global__ __launch_bounds__(128) void k_pool_fin(const float* __restrict__ psum, const float* __restrict__ pmax,
                                                  const int* __restrict__ gptr, const float* __restrict__ g0,
                                                  float* __restrict__ z) {
    int g = blockIdx.x, c = threadIdx.x;
    float sm = 0.f, mx = -INFINITY;
    for (int ch = 0; ch < PCH; ++ch) {
        sm += psum[(size_t)(g * PCH + ch) * HH + c];
        mx = fmaxf(mx, pmax[(size_t)(g * PCH + ch) * HH + c]);
    }
    int cntn = gptr[g + 1] - gptr[g];
    float denom = (float)max(cntn, 1);
    z[g * 264 + c] = sm / denom;
    z[g * 264 + 128 + c] = mx;
    if (c < GG) z[g * 264 + 256 + c] = g0[g * GG + c];
}

// ---------------- classifier ----------------
__global__ __launch_bounds__(128) void k_cls1(const float* __restrict__ z, const float* __restrict__ cw1,
                                              const float* __restrict__ cb1, float* __restrict__ z1) {
    __shared__ float zr[264];
    int g = blockIdx.x, c = threadIdx.x;
    for (int t = c; t < 264; t += 128) zr[t] = z[g * 264 + t];
    __syncthreads();
    float acc = cb1[c];
    for (int k = 0; k < 264; ++k) acc = fmaf(zr[k], cw1[k * HH + c], acc);
    z1[g * HH + c] = elu01f(acc);
}

__global__ __launch_bounds__(128) void k_cls2(const float* __restrict__ z1, const float* __restrict__ cgm,
                                              const float* __restrict__ cbt, const float* __restrict__ cw2,
                                              const float* __restrict__ cb2, float* __restrict__ outp) {
    __shared__ float zn[HH * 65];
    int c = threadIdx.x;
    float s = 0.f, s2 = 0.f;
    for (int g = 0; g < BB; ++g) {
        float v = z1[g * HH + c];
        s += v; s2 = fmaf(v, v, s2);
    }
    float mu = s * (1.f / BB);
    float var = fmaxf(s2 * (1.f / BB) - mu * mu, 0.f);
    float a = cgm[c] * rsqrtf(var + BN_EPS);
    float sh = fmaf(-mu, a, cbt[c]);
    for (int g = 0; g < BB; ++g) zn[c * 65 + g] = fmaf(z1[g * HH + c], a, sh);
    __syncthreads();
    if (c < BB) {
        float l0 = cb2[0], l1 = cb2[1];
        for (int k = 0; k < HH; ++k) {
            float v = zn[k * 65 + c];
            l0 = fmaf(v, cw2[k * 2 + 0], l0);
            l1 = fmaf(v, cw2[k * 2 + 1], l1);
        }
        float m = fmaxf(l0, l1);
        float e0 = __expf(l0 - m), e1 = __expf(l1 - m);
        float inv = 1.f / (e0 + e1);
        outp[c * 2 + 0] = e0 * inv;
        outp[c * 2 + 1] = e1 * inv;
    }
}

extern "C" void kernel_launch(void* const* d_in, const int* in_sizes, int n_in,
                              void* d_out, int out_size, void* d_ws, size_t ws_size,
                              hipStream_t stream) {
    (void)in_sizes; (void)n_in; (void)out_size; (void)ws_size;
    const float* h0     = (const float*)d_in[0];
    const float* coord0 = (const float*)d_in[1];
    const float* g0     = (const float*)d_in[2];
    const int*   eidx   = (const int*)d_in[3];
    const int*   batch  = (const int*)d_in[4];
    const float* w1_0   = (const float*)d_in[5];
    const float* b1_0   = (const float*)d_in[6];
    const float* gm_0   = (const float*)d_in[7];
    const float* bt_0   = (const float*)d_in[8];
    const float* w2_0   = (const float*)d_in[9];
    const float* b2_0   = (const float*)d_in[10];
    const float* w1_r   = (const float*)d_in[11];
    const float* b1_r   = (const float*)d_in[12];
    const float* gm_r   = (const float*)d_in[13];
    const float* bt_r   = (const float*)d_in[14];
    const float* w2_r   = (const float*)d_in[15];
    const float* b2_r   = (const float*)d_in[16];
    const float* cw1    = (const float*)d_in[17];
    const float* cb1    = (const float*)d_in[18];
    const float* cgm    = (const float*)d_in[19];
    const float* cbt    = (const float*)d_in[20];
    const float* cw2    = (const float*)d_in[21];
    const float* cb2    = (const float*)d_in[22];
    float* outp = (float*)d_out;

    const int* esrc = eidx;
    const int* edst = eidx + EE;

    char* p = (char*)d_ws;
    auto alloc = [&](size_t bytes) { void* r = (void*)p; p += (bytes + 255) & ~(size_t)255; return r; };
    float*    xb       = (float*)alloc((size_t)NN * HH * 4);   // layer0 19-dim input
    float*    yb19     = (float*)alloc((size_t)NN * K0 * 4);
    float*    hb       = (float*)alloc((size_t)NN * HH * 4);   // fp32 h; binbuf overlays
    unsigned* xbf      = (unsigned*)alloc((size_t)NN * 64 * 4);
    unsigned* ybf      = (unsigned*)alloc((size_t)NN * 64 * 4);
    int*      rp       = (int*)alloc((size_t)(NN + 1) * 4);
    int*      srcs     = (int*)alloc((size_t)EE * 4);
    int*      bincnt   = (int*)alloc((size_t)NBINS * 4);
    int*      binstart = (int*)alloc((size_t)NBINS * 4);
    int*      gptr     = (int*)alloc((BB + 1) * 4);
    short*    wt       = (short*)alloc((size_t)5 * HH * HH * 2);
    float*    part     = (float*)alloc((size_t)3125 * 256 * 4);
    float*    part2    = (float*)alloc((size_t)64 * 256 * 4);
    float*    bnscale  = (float*)alloc(HH * 4);
    float*    bnshift  = (float*)alloc(HH * 4);
    float*    psum     = (float*)alloc((size_t)BB * PCH * HH * 4);
    float*    pmax     = (float*)alloc((size_t)BB * PCH * HH * 4);
    float*    zb       = (float*)alloc((size_t)BB * 264 * 4);
    float*    z1b      = (float*)alloc((size_t)BB * HH * 4);
    uint2*    binbuf   = (uint2*)hb;   // overlays hb (hb first written after CSR build)

    const int NB_A = (EE + ACH - 1) / ACH;          // 782
    const int NB_AGG = (NN * 64 + 255) / 256;       // 25000
    const int NB_G32 = NN / 32;                     // 3125
    const int NB_G64 = (NN + 63) / 64;              // 1563
    const int NB_X0 = (NN * K0 + 255) / 256;
    const int NB_WP = (5 * HH * HH + 255) / 256;    // 320

    // CSR build (LDS counting sort) + weight prep
    hipMemsetAsync(bincnt, 0, (size_t)NBINS * 4, stream);
    k_binA<<<NB_A, 256, 0, stream>>>(esrc, edst, bincnt, binbuf);
    k_binscan<<<1, 512, 0, stream>>>(bincnt, binstart, rp);
    k_binB<<<NBINS, 256, 0, stream>>>(binbuf, bincnt, binstart, rp, srcs);
    k_gptr<<<1, 128, 0, stream>>>(batch, gptr);
    k_wprep<<<NB_WP, 256, 0, stream>>>(w2_0, w1_r, w2_r, wt);

    // layer 0 (fp32 path up to second MLP)
    k_buildx0<<<NB_X0, 256, 0, stream>>>(h0, coord0, xb);
    k_agg_small<<<NB_AGG, 256, 0, stream>>>(xb, rp, srcs, yb19);
    k_gemm_small<K0, true><<<NB_G32, 256, 0, stream>>>(yb19, w1_0, b1_0, hb, part);
    k_statred<<<64, 256, 0, stream>>>(part, part2, NB_G32);
    k_bnfin<<<1, 128, 0, stream>>>(part2, gm_0, bt_0, bnscale, bnshift);
    k_gemm_mfma<false, true, true, false, true><<<NB_G64, 256, 0, stream>>>(hb, wt, b2_0, bnscale, bnshift,
                                                                            xbf, nullptr);

    // layers 1..2 (bf16 activations)
    for (int i = 0; i < 2; ++i) {
        k_agg128_bf<<<NB_AGG, 256, 0, stream>>>(xbf, rp, srcs, ybf);
        k_gemm_mfma<true, false, false, true, false><<<NB_G64, 256, 0, stream>>>(ybf,
                wt + (size_t)(1 + i) * HH * HH, b1_r + i * HH, nullptr, nullptr, hb, part);
        k_statred<<<64, 256, 0, stream>>>(part, part2, NB_G64);
        k_bnfin<<<1, 128, 0, stream>>>(part2, gm_r + i * HH, bt_r + i * HH, bnscale, bnshift);
        // both layers write bf16; final layer pooled from bf16
        k_gemm_mfma<false, true, true, false, true><<<NB_G64, 256, 0, stream>>>(hb,
                wt + (size_t)(3 + i) * HH * HH, b2_r + i * HH, bnscale, bnshift, xbf, nullptr);
    }

    // pooling + classifier (pooling reads bf16, accumulates fp32)
    k_pool_part<<<BB * PCH, 128, 0, stream>>>((const unsigned short*)xbf, gptr, psum, pmax);
    k_pool_fin<<<BB, 128, 0, stream>>>(psum, pmax, gptr, g0, zb);
    k_cls1<<<BB, 128, 0, stream>>>(zb, cw1, cb1, z1b);
    k_cls2<<<1, 128, 0, stream>>>(z1b, cgm, cbt, cw2, cb2, outp);
}

// Round 11
// 618.079 us; speedup vs baseline: 1.9319x; 1.0291x over previous
//
#include <hip/hip_runtime.h>
#include <math.h>

#define NN 100000
#define EE 1600000
#define BB 64
#define FF 16
#define HH 128
#define GG 8
#define K0 19
#define BN_EPS 1e-5f
#define PCH 16
#define BSHIFT 8
#define BNODES 256
#define NBINS 391          // ceil(NN/256)
#define BCAP 8192
#define ACH 2048           // edges per phase-A block

typedef short bf16x8 __attribute__((ext_vector_type(8)));
typedef float f32x4 __attribute__((ext_vector_type(4)));

__device__ __forceinline__ float elu01f(float v) {
    return v > 0.f ? v : 0.1f * (__expf(v) - 1.f);
}

__device__ __forceinline__ unsigned f2bfu(float f) {
    unsigned u = __float_as_uint(f);
    unsigned r = u + 0x7FFFu + ((u >> 16) & 1u);
    return r >> 16;
}
__device__ __forceinline__ short f2bf(float f) { return (short)f2bfu(f); }
__device__ __forceinline__ float bfu2f(unsigned short b) {
    return __uint_as_float(((unsigned)b) << 16);
}

// ---------------- CSR build: 2-phase LDS counting sort ----------------
__global__ __launch_bounds__(256) void k_binA(const int* __restrict__ esrc, const int* __restrict__ edst,
                                              int* __restrict__ bincnt, uint2* __restrict__ binbuf) {
    __shared__ int hist[NBINS];
    __shared__ int gbase[NBINS];
    __shared__ int cur[NBINS];
    __shared__ int sc[512];
    __shared__ uint2 ebuf[ACH];
    __shared__ uint2 sorted[ACH];
    int tid = threadIdx.x;
    int e0 = blockIdx.x * ACH;
    int n = min(ACH, EE - e0);
    for (int i = tid; i < NBINS; i += 256) hist[i] = 0;
    __syncthreads();
    for (int i = tid; i < n; i += 256) {
        int s = esrc[e0 + i];
        int d = edst[e0 + i];
        ebuf[i] = make_uint2((unsigned)s, (unsigned)d);
        atomicAdd(&hist[d >> BSHIFT], 1);
    }
    __syncthreads();
    sc[tid] = (tid < NBINS) ? hist[tid] : 0;
    sc[tid + 256] = (tid + 256 < NBINS) ? hist[tid + 256] : 0;
    __syncthreads();
    for (int off = 1; off < 512; off <<= 1) {
        int a0 = sc[tid], a1 = sc[tid + 256];
        int b0 = (tid >= off) ? sc[tid - off] : 0;
        int b1 = (tid + 256 >= off) ? sc[tid + 256 - off] : 0;
        __syncthreads();
        sc[tid] = a0 + b0;
        sc[tid + 256] = a1 + b1;
        __syncthreads();
    }
    for (int b = tid; b < NBINS; b += 256) {
        int c = hist[b];
        gbase[b] = (c > 0) ? atomicAdd(&bincnt[b], c) : 0;
        cur[b] = (b > 0) ? sc[b - 1] : 0;
    }
    __syncthreads();
    for (int i = tid; i < n; i += 256) {
        uint2 e = ebuf[i];
        int b = (int)(e.y >> BSHIFT);
        int pos = atomicAdd(&cur[b], 1);
        sorted[pos] = e;
    }
    __syncthreads();
    for (int i = tid; i < n; i += 256) {
        uint2 e = sorted[i];
        int b = (int)(e.y >> BSHIFT);
        int ls = (b > 0) ? sc[b - 1] : 0;
        int gpos = gbase[b] + (i - ls);
        binbuf[(size_t)b * BCAP + gpos] = e;
    }
}

__global__ void k_binscan(const int* __restrict__ bincnt, int* __restrict__ binstart, int* __restrict__ rp) {
    __shared__ int sc[512];
    int t = threadIdx.x;
    sc[t] = (t < NBINS) ? bincnt[t] : 0;
    __syncthreads();
    for (int off = 1; off < 512; off <<= 1) {
        int v = (t >= off) ? sc[t - off] : 0;
        __syncthreads();
        sc[t] += v;
        __syncthreads();
    }
    if (t < NBINS) binstart[t] = (t > 0) ? sc[t - 1] : 0;
    if (t == 0) rp[NN] = EE;
}

__global__ __launch_bounds__(256) void k_binB(const uint2* __restrict__ binbuf, const int* __restrict__ bincnt,
                                              const int* __restrict__ binstart,
                                              int* __restrict__ rp, int* __restrict__ srcs) {
    __shared__ int hist[BNODES];
    __shared__ int scx[BNODES];
    __shared__ int scur[BNODES];
    __shared__ int sbuf[BCAP];
    int b = blockIdx.x;
    int n = bincnt[b];
    int tid = threadIdx.x;
    hist[tid] = 0;
    __syncthreads();
    const uint2* eb = binbuf + (size_t)b * BCAP;
    for (int i = tid; i < n; i += 256)
        atomicAdd(&hist[eb[i].y & (BNODES - 1)], 1);
    __syncthreads();
    scx[tid] = hist[tid];
    __syncthreads();
    for (int off = 1; off < 256; off <<= 1) {
        int v = (tid >= off) ? scx[tid - off] : 0;
        __syncthreads();
        scx[tid] += v;
        __syncthreads();
    }
    int base = binstart[b];
    int excl = (tid > 0) ? scx[tid - 1] : 0;
    int node = (b << BSHIFT) + tid;
    if (node < NN) rp[node] = base + excl;
    scur[tid] = excl;
    __syncthreads();
    for (int i = tid; i < n; i += 256) {
        uint2 e = eb[i];
        int pos = atomicAdd(&scur[e.y & (BNODES - 1)], 1);
        sbuf[pos] = (int)e.x;
    }
    __syncthreads();
    for (int i = tid; i < n; i += 256) srcs[base + i] = sbuf[i];
}

__global__ void k_gptr(const int* __restrict__ batch, int* __restrict__ gptr) {
    int t = threadIdx.x;
    if (t > BB) return;
    int lo = 0, hi = NN;
    while (lo < hi) { int mid = (lo + hi) >> 1; if (batch[mid] < t) lo = mid + 1; else hi = mid; }
    gptr[t] = lo;
}

// ---------------- weight prep: fp32 [k][col] -> bf16 transposed [col][k] ----------------
__global__ __launch_bounds__(256) void k_wprep(const float* __restrict__ w2_0, const float* __restrict__ w1_r,
                                               const float* __restrict__ w2_r, short* __restrict__ wt) {
    int t = blockIdx.x * 256 + threadIdx.x;
    if (t >= 5 * HH * HH) return;
    int m = t >> 14;
    int rem = t & 16383;
    int col = rem >> 7;
    int k = rem & 127;
    const float* src = (m == 0) ? w2_0 : (m <= 2 ? w1_r + (size_t)(m - 1) * HH * HH
                                                 : w2_r + (size_t)(m - 3) * HH * HH);
    wt[t] = f2bf(src[k * HH + col]);
}

// ---------------- feature build + aggregation ----------------
__global__ __launch_bounds__(256) void k_buildx0(const float* __restrict__ h0, const float* __restrict__ coord,
                                                 float* __restrict__ x0) {
    int i = blockIdx.x * 256 + threadIdx.x;
    if (i >= NN * K0) return;
    int node = i / K0, k = i - node * K0;
    x0[i] = (k < FF) ? h0[node * FF + k] : coord[node * 3 + (k - FF)];
}

__global__ __launch_bounds__(256) void k_agg_small(const float* __restrict__ x, const int* __restrict__ rp,
                                                   const int* __restrict__ srcs, float* __restrict__ y) {
    int w = (blockIdx.x * 256 + threadIdx.x) >> 6;
    int lane = threadIdx.x & 63;
    if (w >= NN) return;
    int beg = rp[w], end = rp[w + 1];
    bool act = lane < K0;
    size_t li = act ? (size_t)lane : 0;
    float acc0 = 0.f, acc1 = 0.f;
    if (act) acc0 = x[(size_t)w * K0 + li];
    int p = beg;
    for (; p + 8 <= end; p += 8) {
        int s0 = srcs[p + 0], s1 = srcs[p + 1], s2 = srcs[p + 2], s3 = srcs[p + 3];
        int s4 = srcs[p + 4], s5 = srcs[p + 5], s6 = srcs[p + 6], s7 = srcs[p + 7];
        float v0 = x[(size_t)s0 * K0 + li];
        float v1 = x[(size_t)s1 * K0 + li];
        float v2 = x[(size_t)s2 * K0 + li];
        float v3 = x[(size_t)s3 * K0 + li];
        float v4 = x[(size_t)s4 * K0 + li];
        float v5 = x[(size_t)s5 * K0 + li];
        float v6 = x[(size_t)s6 * K0 + li];
        float v7 = x[(size_t)s7 * K0 + li];
        acc0 += (v0 + v1) + (v2 + v3);
        acc1 += (v4 + v5) + (v6 + v7);
    }
    for (; p < end; ++p) {
        int sn = srcs[p];
        acc0 += x[(size_t)sn * K0 + li];
    }
    if (act) y[(size_t)w * K0 + lane] = acc0 + acc1;
}

// bf16 aggregation: x rows are 128 bf16 = 64 uints; lane owns uint 'lane' (2 channels)
__global__ __launch_bounds__(256) void k_agg128_bf(const unsigned* __restrict__ x, const int* __restrict__ rp,
                                                   const int* __restrict__ srcs, unsigned* __restrict__ y) {
    int w = (blockIdx.x * 256 + threadIdx.x) >> 6;
    int lane = threadIdx.x & 63;
    if (w >= NN) return;
    int beg = rp[w], end = rp[w + 1];
    unsigned us = x[(size_t)w * 64 + lane];
    float ax = __uint_as_float(us << 16);
    float ay = __uint_as_float(us & 0xffff0000u);
    float bx = 0.f, by = 0.f;
    float cx = 0.f, cy = 0.f;
    float dx = 0.f, dy = 0.f;
    int p = beg;
    for (; p + 16 <= end; p += 16) {
        int s0 = srcs[p + 0], s1 = srcs[p + 1], s2 = srcs[p + 2], s3 = srcs[p + 3];
        int s4 = srcs[p + 4], s5 = srcs[p + 5], s6 = srcs[p + 6], s7 = srcs[p + 7];
        int s8 = srcs[p + 8], s9 = srcs[p + 9], sa = srcs[p + 10], sb = srcs[p + 11];
        int sc_ = srcs[p + 12], sd = srcs[p + 13], se = srcs[p + 14], sf = srcs[p + 15];
        unsigned u0 = x[(size_t)s0 * 64 + lane];
        unsigned u1 = x[(size_t)s1 * 64 + lane];
        unsigned u2 = x[(size_t)s2 * 64 + lane];
        unsigned u3 = x[(size_t)s3 * 64 + lane];
        unsigned u4 = x[(size_t)s4 * 64 + lane];
        unsigned u5 = x[(size_t)s5 * 64 + lane];
        unsigned u6 = x[(size_t)s6 * 64 + lane];
        unsigned u7 = x[(size_t)s7 * 64 + lane];
        unsigned u8 = x[(size_t)s8 * 64 + lane];
        unsigned u9 = x[(size_t)s9 * 64 + lane];
        unsigned ua = x[(size_t)sa * 64 + lane];
        unsigned ub = x[(size_t)sb * 64 + lane];
        unsigned uc = x[(size_t)sc_ * 64 + lane];
        unsigned ud = x[(size_t)sd * 64 + lane];
        unsigned ue = x[(size_t)se * 64 + lane];
        unsigned uf = x[(size_t)sf * 64 + lane];
        ax += (__uint_as_float(u0 << 16) + __uint_as_float(u1 << 16))
            + (__uint_as_float(u2 << 16) + __uint_as_float(u3 << 16));
        ay += (__uint_as_float(u0 & 0xffff0000u) + __uint_as_float(u1 & 0xffff0000u))
            + (__uint_as_float(u2 & 0xffff0000u) + __uint_as_float(u3 & 0xffff0000u));
        bx += (__uint_as_float(u4 << 16) + __uint_as_float(u5 << 16))
            + (__uint_as_float(u6 << 16) + __uint_as_float(u7 << 16));
        by += (__uint_as_float(u4 & 0xffff0000u) + __uint_as_float(u5 & 0xffff0000u))
            + (__uint_as_float(u6 & 0xffff0000u) + __uint_as_float(u7 & 0xffff0000u));
        cx += (__uint_as_float(u8 << 16) + __uint_as_float(u9 << 16))
            + (__uint_as_float(ua << 16) + __uint_as_float(ub << 16));
        cy += (__uint_as_float(u8 & 0xffff0000u) + __uint_as_float(u9 & 0xffff0000u))
            + (__uint_as_float(ua & 0xffff0000u) + __uint_as_float(ub & 0xffff0000u));
        dx += (__uint_as_float(uc << 16) + __uint_as_float(ud << 16))
            + (__uint_as_float(ue << 16) + __uint_as_float(uf << 16));
        dy += (__uint_as_float(uc & 0xffff0000u) + __uint_as_float(ud & 0xffff0000u))
            + (__uint_as_float(ue & 0xffff0000u) + __uint_as_float(uf & 0xffff0000u));
    }
    for (; p + 8 <= end; p += 8) {
        int s0 = srcs[p + 0], s1 = srcs[p + 1], s2 = srcs[p + 2], s3 = srcs[p + 3];
        int s4 = srcs[p + 4], s5 = srcs[p + 5], s6 = srcs[p + 6], s7 = srcs[p + 7];
        unsigned u0 = x[(size_t)s0 * 64 + lane];
        unsigned u1 = x[(size_t)s1 * 64 + lane];
        unsigned u2 = x[(size_t)s2 * 64 + lane];
        unsigned u3 = x[(size_t)s3 * 64 + lane];
        unsigned u4 = x[(size_t)s4 * 64 + lane];
        unsigned u5 = x[(size_t)s5 * 64 + lane];
        unsigned u6 = x[(size_t)s6 * 64 + lane];
        unsigned u7 = x[(size_t)s7 * 64 + lane];
        ax += (__uint_as_float(u0 << 16) + __uint_as_float(u1 << 16))
            + (__uint_as_float(u2 << 16) + __uint_as_float(u3 << 16));
        ay += (__uint_as_float(u0 & 0xffff0000u) + __uint_as_float(u1 & 0xffff0000u))
            + (__uint_as_float(u2 & 0xffff0000u) + __uint_as_float(u3 & 0xffff0000u));
        bx += (__uint_as_float(u4 << 16) + __uint_as_float(u5 << 16))
            + (__uint_as_float(u6 << 16) + __uint_as_float(u7 << 16));
        by += (__uint_as_float(u4 & 0xffff0000u) + __uint_as_float(u5 & 0xffff0000u))
            + (__uint_as_float(u6 & 0xffff0000u) + __uint_as_float(u7 & 0xffff0000u));
    }
    for (; p < end; ++p) {
        unsigned u = x[(size_t)srcs[p] * 64 + lane];
        ax += __uint_as_float(u << 16);
        ay += __uint_as_float(u & 0xffff0000u);
    }
    ax += bx + cx + dx;
    ay += by + cy + dy;
    y[(size_t)w * 64 + lane] = f2bfu(ax) | (f2bfu(ay) << 16);
}

// ---------------- GEMM K=19 (layer-0 first MLP, fp32 compute, bf16 out) ----------------
template<int K, bool STATS>
__global__ __launch_bounds__(256) void k_gemm_small(const float* __restrict__ in, const float* __restrict__ W,
        const float* __restrict__ bias, unsigned short* __restrict__ out, float* __restrict__ part) {
    constexpr int SK = ((K + 3) / 4) * 4 + 4;
    __shared__ __align__(16) float yt[32 * SK];
    __shared__ float red[256];
    int tid = threadIdx.x;
    int row0 = blockIdx.x * 32;
    for (int t = tid; t < 32 * SK; t += 256) {
        int r = t / SK, k = t - r * SK;
        float v = 0.f;
        if (k < K) v = in[(size_t)(row0 + r) * K + k];
        yt[t] = v;
    }
    __syncthreads();
    int col = tid & 127;
    int rg = tid >> 7;
    float acc[16];
    #pragma unroll
    for (int r = 0; r < 16; r++) acc[r] = 0.f;
    const float* ybase = &yt[rg * 16 * SK];
    int kk = 0;
    for (; kk + 4 <= K; kk += 4) {
        float w0 = W[(kk + 0) * HH + col];
        float w1 = W[(kk + 1) * HH + col];
        float w2 = W[(kk + 2) * HH + col];
        float w3 = W[(kk + 3) * HH + col];
        #pragma unroll
        for (int r = 0; r < 16; r++) {
            const float4 v = *(const float4*)&ybase[r * SK + kk];
            acc[r] = fmaf(v.x, w0, acc[r]);
            acc[r] = fmaf(v.y, w1, acc[r]);
            acc[r] = fmaf(v.z, w2, acc[r]);
            acc[r] = fmaf(v.w, w3, acc[r]);
        }
    }
    if constexpr (K % 4 != 0) {
        float w[4];
        #pragma unroll
        for (int j = 0; j < 4; j++) w[j] = (kk + j < K) ? W[(kk + j) * HH + col] : 0.f;
        #pragma unroll
        for (int r = 0; r < 16; r++) {
            const float4 v = *(const float4*)&ybase[r * SK + kk];
            acc[r] = fmaf(v.x, w[0], acc[r]);
            acc[r] = fmaf(v.y, w[1], acc[r]);
            acc[r] = fmaf(v.z, w[2], acc[r]);
            acc[r] = fmaf(v.w, w[3], acc[r]);
        }
    }
    float bcol = bias[col];
    float s = 0.f, s2 = 0.f;
    #pragma unroll
    for (int r = 0; r < 16; r++) {
        float hv = acc[r] + bcol;
        out[(size_t)(row0 + rg * 16 + r) * HH + col] = (unsigned short)f2bfu(hv);
        if (STATS) { s += hv; s2 = fmaf(hv, hv, s2); }
    }
    if (STATS) {
        red[tid] = s; __syncthreads();
        if (tid < 128) part[(size_t)blockIdx.x * 256 + tid] = s + red[tid + 128];
        __syncthreads();
        red[tid] = s2; __syncthreads();
        if (tid < 128) part[(size_t)blockIdx.x * 256 + 128 + tid] = s2 + red[tid + 128];
    }
}

// ---------------- K=128 GEMM via bf16 MFMA: 64 rows x 128 cols per block ----------------
// in/out both bf16. BNIN: apply relu(v*scale+shift) during LDS staging (unpack/fma/repack).
template<bool STATS, bool BNIN, bool ELUOUT>
__global__ __launch_bounds__(256) void k_gemm_mfma(const unsigned short* __restrict__ in,
        const short* __restrict__ WT, const float* __restrict__ bias,
        const float* __restrict__ bnscale, const float* __restrict__ bnshift,
        unsigned short* __restrict__ out, float* __restrict__ part) {
    __shared__ __align__(16) short Al[64 * 136];
    __shared__ float lsum[HH], lsq[HH];
    int tid = threadIdx.x;
    int row0 = blockIdx.x * 64;
    if (STATS && tid < HH) { lsum[tid] = 0.f; lsq[tid] = 0.f; }
    {
        int r = tid >> 2;
        int k0 = (tid & 3) * 32;
        int grow = row0 + r;
        short* dst = &Al[r * 136 + k0];
        if (grow < NN) {
            const uint4* s4 = (const uint4*)(in + (size_t)grow * HH + k0);
            if constexpr (!BNIN) {
                uint4* d4 = (uint4*)dst;
                d4[0] = s4[0]; d4[1] = s4[1]; d4[2] = s4[2]; d4[3] = s4[3];
            } else {
                unsigned* d = (unsigned*)dst;
                #pragma unroll
                for (int q = 0; q < 4; q++) {
                    uint4 u = s4[q];
                    float4 sc0 = *(const float4*)(bnscale + k0 + q * 8);
                    float4 sh0 = *(const float4*)(bnshift + k0 + q * 8);
                    float4 sc1 = *(const float4*)(bnscale + k0 + q * 8 + 4);
                    float4 sh1 = *(const float4*)(bnshift + k0 + q * 8 + 4);
                    float a0 = __uint_as_float(u.x << 16), a1 = __uint_as_float(u.x & 0xffff0000u);
                    float a2 = __uint_as_float(u.y << 16), a3 = __uint_as_float(u.y & 0xffff0000u);
                    float a4 = __uint_as_float(u.z << 16), a5 = __uint_as_float(u.z & 0xffff0000u);
                    float a6 = __uint_as_float(u.w << 16), a7 = __uint_as_float(u.w & 0xffff0000u);
                    a0 = fmaxf(fmaf(a0, sc0.x, sh0.x), 0.f);
                    a1 = fmaxf(fmaf(a1, sc0.y, sh0.y), 0.f);
                    a2 = fmaxf(fmaf(a2, sc0.z, sh0.z), 0.f);
                    a3 = fmaxf(fmaf(a3, sc0.w, sh0.w), 0.f);
                    a4 = fmaxf(fmaf(a4, sc1.x, sh1.x), 0.f);
                    a5 = fmaxf(fmaf(a5, sc1.y, sh1.y), 0.f);
                    a6 = fmaxf(fmaf(a6, sc1.z, sh1.z), 0.f);
                    a7 = fmaxf(fmaf(a7, sc1.w, sh1.w), 0.f);
                    d[q * 4 + 0] = f2bfu(a0) | (f2bfu(a1) << 16);
                    d[q * 4 + 1] = f2bfu(a2) | (f2bfu(a3) << 16);
                    d[q * 4 + 2] = f2bfu(a4) | (f2bfu(a5) << 16);
                    d[q * 4 + 3] = f2bfu(a6) | (f2bfu(a7) << 16);
                }
            }
        } else {
            uint4 z = {0, 0, 0, 0};
            uint4* d4 = (uint4*)dst;
            d4[0] = z; d4[1] = z; d4[2] = z; d4[3] = z;
        }
    }
    __syncthreads();
    int wave = tid >> 6;
    int lane = tid & 63;
    int ln = lane & 15, quad = lane >> 4;
    int wcol0 = wave * 32;
    f32x4 acc[4][2];
    #pragma unroll
    for (int rt = 0; rt < 4; rt++)
        #pragma unroll
        for (int ct = 0; ct < 2; ct++) acc[rt][ct] = (f32x4){0.f, 0.f, 0.f, 0.f};
    #pragma unroll
    for (int ks = 0; ks < 4; ks++) {
        bf16x8 a[4], b[2];
        #pragma unroll
        for (int ct = 0; ct < 2; ct++)
            b[ct] = *(const bf16x8*)(WT + (size_t)(wcol0 + ct * 16 + ln) * HH + ks * 32 + quad * 8);
        #pragma unroll
        for (int rt = 0; rt < 4; rt++)
            a[rt] = *(const bf16x8*)(&Al[(rt * 16 + ln) * 136 + ks * 32 + quad * 8]);
        #pragma unroll
        for (int rt = 0; rt < 4; rt++)
            #pragma unroll
            for (int ct = 0; ct < 2; ct++)
                acc[rt][ct] = __builtin_amdgcn_mfma_f32_16x16x32_bf16(a[rt], b[ct], acc[rt][ct], 0, 0, 0);
    }
    float b0 = bias[wcol0 + ln];
    float b1 = bias[wcol0 + 16 + ln];
    float s[2] = {0.f, 0.f}, s2[2] = {0.f, 0.f};
    #pragma unroll
    for (int rt = 0; rt < 4; rt++) {
        #pragma unroll
        for (int r = 0; r < 4; r++) {
            int grow = row0 + rt * 16 + quad * 4 + r;
            if (grow < NN) {
                float hv0 = acc[rt][0][r] + b0;
                float hv1 = acc[rt][1][r] + b1;
                if (ELUOUT) { hv0 = elu01f(hv0); hv1 = elu01f(hv1); }
                out[(size_t)grow * HH + wcol0 + ln] = (unsigned short)f2bfu(hv0);
                out[(size_t)grow * HH + wcol0 + 16 + ln] = (unsigned short)f2bfu(hv1);
                if (STATS) {
                    s[0] += hv0; s2[0] = fmaf(hv0, hv0, s2[0]);
                    s[1] += hv1; s2[1] = fmaf(hv1, hv1, s2[1]);
                }
            }
        }
    }
    if (STATS) {
        atomicAdd(&lsum[wcol0 + ln], s[0]);
        atomicAdd(&lsum[wcol0 + 16 + ln], s[1]);
        atomicAdd(&lsq[wcol0 + ln], s2[0]);
        atomicAdd(&lsq[wcol0 + 16 + ln], s2[1]);
        __syncthreads();
        if (tid < HH) {
            part[(size_t)blockIdx.x * 256 + tid] = lsum[tid];
            part[(size_t)blockIdx.x * 256 + 128 + tid] = lsq[tid];
        }
    }
}

// stage-1 stat reduce: 64 blocks fold nrows partial rows -> part2[64][256]
__global__ __launch_bounds__(256) void k_statred(const float* __restrict__ part, float* __restrict__ part2,
                                                 int nrows) {
    int tid = threadIdx.x;
    float acc = 0.f;
    for (int r = blockIdx.x; r < nrows; r += 64)
        acc += part[(size_t)r * 256 + tid];
    part2[(size_t)blockIdx.x * 256 + tid] = acc;
}

__global__ void k_bnfin(const float* __restrict__ part2, const float* __restrict__ gm,
                        const float* __restrict__ bt, float* scale, float* shift) {
    int c = threadIdx.x;
    float s = 0.f, s2 = 0.f;
    #pragma unroll 4
    for (int j = 0; j < 64; ++j) {
        s += part2[(size_t)j * 256 + c];
        s2 += part2[(size_t)j * 256 + 128 + c];
    }
    float mu = s * (1.f / NN);
    float var = fmaxf(s2 * (1.f / NN) - mu * mu, 0.f);
    float a = gm[c] * rsqrtf(var + BN_EPS);
    scale[c] = a;
    shift[c] = fmaf(-mu, a, bt[c]);
}

// ---------------- pooling (bf16 input) ----------------
__global__ __launch_bounds__(128) void k_pool_part(const unsigned short* __restrict__ x,
                                                   const int* __restrict__ gptr,
                                                   float* __restrict__ psum, float* __restrict__ pmax) {
    int g = blockIdx.x >> 4;
    int ch = blockIdx.x & 15;
    int s = gptr[g], e = gptr[g + 1];
    int len = e - s;
    int per = (len + PCH - 1) / PCH;
    int lo = s + ch * per;
    int hi = min(lo + per, e);
    int c = threadIdx.x;
    float sm = 0.f, mx = -INFINITY;
    for (int i = lo; i < hi; ++i) {
        float v = bfu2f(x[(size_t)i * HH + c]);
        sm += v; mx = fmaxf(mx, v);
    }
    psum[(size_t)blockIdx.x * HH + c] = sm;
    pmax[(size_t)blockIdx.x * HH + c] = mx;
}

__global__ __launch_bounds__(128) void k_pool_fin(const float* __restrict__ psum, const float* __restrict__ pmax,
                                                  const int* __restrict__ gptr, const float* __restrict__ g0,
                                                  float* __restrict__ z) {
    int g = blockIdx.x, c = threadIdx.x;
    float sm = 0.f, mx = -INFINITY;
    for (int ch = 0; ch < PCH; ++ch) {
        sm += psum[(size_t)(g * PCH + ch) * HH + c];
        mx = fmaxf(mx, pmax[(size_t)(g * PCH + ch) * HH + c]);
    }
    int cntn = gptr[g + 1] - gptr[g];
    float denom = (float)max(cntn, 1);
    z[g * 264 + c] = sm / denom;
    z[g * 264 + 128 + c] = mx;
    if (c < GG) z[g * 264 + 256 + c] = g0[g * GG + c];
}

// ---------------- classifier ----------------
__global__ __launch_bounds__(128) void k_cls1(const float* __restrict__ z, const float* __restrict__ cw1,
                                              const float* __restrict__ cb1, float* __restrict__ z1) {
    __shared__ float zr[264];
    int g = blockIdx.x, c = threadIdx.x;
    for (int t = c; t < 264; t += 128) zr[t] = z[g * 264 + t];
    __syncthreads();
    float acc = cb1[c];
    for (int k = 0; k < 264; ++k) acc = fmaf(zr[k], cw1[k * HH + c], acc);
    z1[g * HH + c] = elu01f(acc);
}

__global__ __launch_bounds__(128) void k_cls2(const float* __restrict__ z1, const float* __restrict__ cgm,
                                              const float* __restrict__ cbt, const float* __restrict__ cw2,
                                              const float* __restrict__ cb2, float* __restrict__ outp) {
    __shared__ float zn[HH * 65];
    int c = threadIdx.x;
    float s = 0.f, s2 = 0.f;
    for (int g = 0; g < BB; ++g) {
        float v = z1[g * HH + c];
        s += v; s2 = fmaf(v, v, s2);
    }
    float mu = s * (1.f / BB);
    float var = fmaxf(s2 * (1.f / BB) - mu * mu, 0.f);
    float a = cgm[c] * rsqrtf(var + BN_EPS);
    float sh = fmaf(-mu, a, cbt[c]);
    for (int g = 0; g < BB; ++g) zn[c * 65 + g] = fmaf(z1[g * HH + c], a, sh);
    __syncthreads();
    if (c < BB) {
        float l0 = cb2[0], l1 = cb2[1];
        for (int k = 0; k < HH; ++k) {
            float v = zn[k * 65 + c];
            l0 = fmaf(v, cw2[k * 2 + 0], l0);
            l1 = fmaf(v, cw2[k * 2 + 1], l1);
        }
        float m = fmaxf(l0, l1);
        float e0 = __expf(l0 - m), e1 = __expf(l1 - m);
        float inv = 1.f / (e0 + e1);
        outp[c * 2 + 0] = e0 * inv;
        outp[c * 2 + 1] = e1 * inv;
    }
}

extern "C" void kernel_launch(void* const* d_in, const int* in_sizes, int n_in,
                              void* d_out, int out_size, void* d_ws, size_t ws_size,
                              hipStream_t stream) {
    (void)in_sizes; (void)n_in; (void)out_size; (void)ws_size;
    const float* h0     = (const float*)d_in[0];
    const float* coord0 = (const float*)d_in[1];
    const float* g0     = (const float*)d_in[2];
    const int*   eidx   = (const int*)d_in[3];
    const int*   batch  = (const int*)d_in[4];
    const float* w1_0   = (const float*)d_in[5];
    const float* b1_0   = (const float*)d_in[6];
    const float* gm_0   = (const float*)d_in[7];
    const float* bt_0   = (const float*)d_in[8];
    const float* w2_0   = (const float*)d_in[9];
    const float* b2_0   = (const float*)d_in[10];
    const float* w1_r   = (const float*)d_in[11];
    const float* b1_r   = (const float*)d_in[12];
    const float* gm_r   = (const float*)d_in[13];
    const float* bt_r   = (const float*)d_in[14];
    const float* w2_r   = (const float*)d_in[15];
    const float* b2_r   = (const float*)d_in[16];
    const float* cw1    = (const float*)d_in[17];
    const float* cb1    = (const float*)d_in[18];
    const float* cgm    = (const float*)d_in[19];
    const float* cbt    = (const float*)d_in[20];
    const float* cw2    = (const float*)d_in[21];
    const float* cb2    = (const float*)d_in[22];
    float* outp = (float*)d_out;

    const int* esrc = eidx;
    const int* edst = eidx + EE;

    char* p = (char*)d_ws;
    auto alloc = [&](size_t bytes) { void* r = (void*)p; p += (bytes + 255) & ~(size_t)255; return r; };
    float*          xb       = (float*)alloc((size_t)NN * HH * 4);   // 19-dim x0; binbuf overlays
    float*          yb19     = (float*)alloc((size_t)NN * K0 * 4);
    unsigned short* hbf      = (unsigned short*)alloc((size_t)NN * HH * 2);
    unsigned*       xbf      = (unsigned*)alloc((size_t)NN * 64 * 4);
    unsigned*       ybf      = (unsigned*)alloc((size_t)NN * 64 * 4);
    int*            rp       = (int*)alloc((size_t)(NN + 1) * 4);
    int*            srcs     = (int*)alloc((size_t)EE * 4);
    int*            bincnt   = (int*)alloc((size_t)NBINS * 4);
    int*            binstart = (int*)alloc((size_t)NBINS * 4);
    int*            gptr     = (int*)alloc((BB + 1) * 4);
    short*          wt       = (short*)alloc((size_t)5 * HH * HH * 2);
    float*          part     = (float*)alloc((size_t)3125 * 256 * 4);
    float*          part2    = (float*)alloc((size_t)64 * 256 * 4);
    float*          bnscale  = (float*)alloc(HH * 4);
    float*          bnshift  = (float*)alloc(HH * 4);
    float*          psum     = (float*)alloc((size_t)BB * PCH * HH * 4);
    float*          pmax     = (float*)alloc((size_t)BB * PCH * HH * 4);
    float*          zb       = (float*)alloc((size_t)BB * 264 * 4);
    float*          z1b      = (float*)alloc((size_t)BB * HH * 4);
    // binbuf (25.65 MB) overlays xb (51.2 MB): binbuf dead after k_binB; xb written after
    uint2*          binbuf   = (uint2*)xb;

    const int NB_A = (EE + ACH - 1) / ACH;          // 782
    const int NB_AGG = (NN * 64 + 255) / 256;       // 25000
    const int NB_G32 = NN / 32;                     // 3125
    const int NB_G64 = (NN + 63) / 64;              // 1563
    const int NB_X0 = (NN * K0 + 255) / 256;
    const int NB_WP = (5 * HH * HH + 255) / 256;    // 320

    // CSR build (LDS counting sort) + weight prep
    hipMemsetAsync(bincnt, 0, (size_t)NBINS * 4, stream);
    k_binA<<<NB_A, 256, 0, stream>>>(esrc, edst, bincnt, binbuf);
    k_binscan<<<1, 512, 0, stream>>>(bincnt, binstart, rp);
    k_binB<<<NBINS, 256, 0, stream>>>(binbuf, bincnt, binstart, rp, srcs);
    k_gptr<<<1, 128, 0, stream>>>(batch, gptr);
    k_wprep<<<NB_WP, 256, 0, stream>>>(w2_0, w1_r, w2_r, wt);

    // layer 0 (fp32 up to first MLP output, then bf16)
    k_buildx0<<<NB_X0, 256, 0, stream>>>(h0, coord0, xb);
    k_agg_small<<<NB_AGG, 256, 0, stream>>>(xb, rp, srcs, yb19);
    k_gemm_small<K0, true><<<NB_G32, 256, 0, stream>>>(yb19, w1_0, b1_0, hbf, part);
    k_statred<<<64, 256, 0, stream>>>(part, part2, NB_G32);
    k_bnfin<<<1, 128, 0, stream>>>(part2, gm_0, bt_0, bnscale, bnshift);
    k_gemm_mfma<false, true, true><<<NB_G64, 256, 0, stream>>>(hbf, wt, b2_0, bnscale, bnshift,
                                                               (unsigned short*)xbf, nullptr);

    // layers 1..2 (bf16 activations + bf16 hidden)
    for (int i = 0; i < 2; ++i) {
        k_agg128_bf<<<NB_AGG, 256, 0, stream>>>(xbf, rp, srcs, ybf);
        k_gemm_mfma<true, false, false><<<NB_G64, 256, 0, stream>>>((const unsigned short*)ybf,
                wt + (size_t)(1 + i) * HH * HH, b1_r + i * HH, nullptr, nullptr, hbf, part);
        k_statred<<<64, 256, 0, stream>>>(part, part2, NB_G64);
        k_bnfin<<<1, 128, 0, stream>>>(part2, gm_r + i * HH, bt_r + i * HH, bnscale, bnshift);
        k_gemm_mfma<false, true, true><<<NB_G64, 256, 0, stream>>>(hbf,
                wt + (size_t)(3 + i) * HH * HH, b2_r + i * HH, bnscale, bnshift,
                (unsigned short*)xbf, nullptr);
    }

    // pooling + classifier (pooling reads bf16, accumulates fp32)
    k_pool_part<<<BB * PCH, 128, 0, stream>>>((const unsigned short*)xbf, gptr, psum, pmax);
    k_pool_fin<<<BB, 128, 0, stream>>>(psum, pmax, gptr, g0, zb);
    k_cls1<<<BB, 128, 0, stream>>>(zb, cw1, cb1, z1b);
    k_cls2<<<1, 128, 0, stream>>>(z1b, cgm, cbt, cw2, cb2, outp);
}

// Round 12
// 591.544 us; speedup vs baseline: 2.0186x; 1.0449x over previous
//
#include <hip/hip_runtime.h>
#include <math.h>

#define NN 100000
#define EE 1600000
#define BB 64
#define FF 16
#define HH 128
#define GG 8
#define K0 19
#define BN_EPS 1e-5f
#define PCH 16
#define BSHIFT 8
#define BNODES 256
#define NBINS 391          // ceil(NN/256)
#define BCAP 8192
#define ACH 2048           // edges per phase-A block

typedef short bf16x8 __attribute__((ext_vector_type(8)));
typedef float f32x4 __attribute__((ext_vector_type(4)));

__device__ __forceinline__ float elu01f(float v) {
    return v > 0.f ? v : 0.1f * (__expf(v) - 1.f);
}

__device__ __forceinline__ unsigned f2bfu(float f) {
    unsigned u = __float_as_uint(f);
    unsigned r = u + 0x7FFFu + ((u >> 16) & 1u);
    return r >> 16;
}
__device__ __forceinline__ short f2bf(float f) { return (short)f2bfu(f); }
__device__ __forceinline__ float bfu2f(unsigned short b) {
    return __uint_as_float(((unsigned)b) << 16);
}
__device__ __forceinline__ float bflo(unsigned u) { return __uint_as_float(u << 16); }
__device__ __forceinline__ float bfhi(unsigned u) { return __uint_as_float(u & 0xffff0000u); }

// ---------------- CSR build: 2-phase LDS counting sort ----------------
__global__ __launch_bounds__(256) void k_binA(const int* __restrict__ esrc, const int* __restrict__ edst,
                                              int* __restrict__ bincnt, uint2* __restrict__ binbuf) {
    __shared__ int hist[NBINS];
    __shared__ int gbase[NBINS];
    __shared__ int cur[NBINS];
    __shared__ int sc[512];
    __shared__ uint2 ebuf[ACH];
    __shared__ uint2 sorted[ACH];
    int tid = threadIdx.x;
    int e0 = blockIdx.x * ACH;
    int n = min(ACH, EE - e0);
    for (int i = tid; i < NBINS; i += 256) hist[i] = 0;
    __syncthreads();
    for (int i = tid; i < n; i += 256) {
        int s = esrc[e0 + i];
        int d = edst[e0 + i];
        ebuf[i] = make_uint2((unsigned)s, (unsigned)d);
        atomicAdd(&hist[d >> BSHIFT], 1);
    }
    __syncthreads();
    sc[tid] = (tid < NBINS) ? hist[tid] : 0;
    sc[tid + 256] = (tid + 256 < NBINS) ? hist[tid + 256] : 0;
    __syncthreads();
    for (int off = 1; off < 512; off <<= 1) {
        int a0 = sc[tid], a1 = sc[tid + 256];
        int b0 = (tid >= off) ? sc[tid - off] : 0;
        int b1 = (tid + 256 >= off) ? sc[tid + 256 - off] : 0;
        __syncthreads();
        sc[tid] = a0 + b0;
        sc[tid + 256] = a1 + b1;
        __syncthreads();
    }
    for (int b = tid; b < NBINS; b += 256) {
        int c = hist[b];
        gbase[b] = (c > 0) ? atomicAdd(&bincnt[b], c) : 0;
        cur[b] = (b > 0) ? sc[b - 1] : 0;
    }
    __syncthreads();
    for (int i = tid; i < n; i += 256) {
        uint2 e = ebuf[i];
        int b = (int)(e.y >> BSHIFT);
        int pos = atomicAdd(&cur[b], 1);
        sorted[pos] = e;
    }
    __syncthreads();
    for (int i = tid; i < n; i += 256) {
        uint2 e = sorted[i];
        int b = (int)(e.y >> BSHIFT);
        int ls = (b > 0) ? sc[b - 1] : 0;
        int gpos = gbase[b] + (i - ls);
        binbuf[(size_t)b * BCAP + gpos] = e;
    }
}

// binscan + gptr fused (independent work, one dispatch)
__global__ void k_binscan(const int* __restrict__ bincnt, int* __restrict__ binstart, int* __restrict__ rp,
                          const int* __restrict__ batch, int* __restrict__ gptr) {
    __shared__ int sc[512];
    int t = threadIdx.x;
    sc[t] = (t < NBINS) ? bincnt[t] : 0;
    __syncthreads();
    for (int off = 1; off < 512; off <<= 1) {
        int v = (t >= off) ? sc[t - off] : 0;
        __syncthreads();
        sc[t] += v;
        __syncthreads();
    }
    if (t < NBINS) binstart[t] = (t > 0) ? sc[t - 1] : 0;
    if (t == 0) rp[NN] = EE;
    if (t <= BB) {
        int lo = 0, hi = NN;
        while (lo < hi) { int mid = (lo + hi) >> 1; if (batch[mid] < t) lo = mid + 1; else hi = mid; }
        gptr[t] = lo;
    }
}

__global__ __launch_bounds__(256) void k_binB(const uint2* __restrict__ binbuf, const int* __restrict__ bincnt,
                                              const int* __restrict__ binstart,
                                              int* __restrict__ rp, int* __restrict__ srcs) {
    __shared__ int hist[BNODES];
    __shared__ int scx[BNODES];
    __shared__ int scur[BNODES];
    __shared__ int sbuf[BCAP];
    int b = blockIdx.x;
    int n = bincnt[b];
    int tid = threadIdx.x;
    hist[tid] = 0;
    __syncthreads();
    const uint2* eb = binbuf + (size_t)b * BCAP;
    for (int i = tid; i < n; i += 256)
        atomicAdd(&hist[eb[i].y & (BNODES - 1)], 1);
    __syncthreads();
    scx[tid] = hist[tid];
    __syncthreads();
    for (int off = 1; off < 256; off <<= 1) {
        int v = (tid >= off) ? scx[tid - off] : 0;
        __syncthreads();
        scx[tid] += v;
        __syncthreads();
    }
    int base = binstart[b];
    int excl = (tid > 0) ? scx[tid - 1] : 0;
    int node = (b << BSHIFT) + tid;
    if (node < NN) rp[node] = base + excl;
    scur[tid] = excl;
    __syncthreads();
    for (int i = tid; i < n; i += 256) {
        uint2 e = eb[i];
        int pos = atomicAdd(&scur[e.y & (BNODES - 1)], 1);
        sbuf[pos] = (int)e.x;
    }
    __syncthreads();
    for (int i = tid; i < n; i += 256) srcs[base + i] = sbuf[i];
}

// ---------------- weight prep: fp32 [k][col] -> bf16 transposed [col][k] ----------------
__global__ __launch_bounds__(256) void k_wprep(const float* __restrict__ w2_0, const float* __restrict__ w1_r,
                                               const float* __restrict__ w2_r, short* __restrict__ wt) {
    int t = blockIdx.x * 256 + threadIdx.x;
    if (t >= 5 * HH * HH) return;
    int m = t >> 14;
    int rem = t & 16383;
    int col = rem >> 7;
    int k = rem & 127;
    const float* src = (m == 0) ? w2_0 : (m <= 2 ? w1_r + (size_t)(m - 1) * HH * HH
                                                 : w2_r + (size_t)(m - 3) * HH * HH);
    wt[t] = f2bf(src[k * HH + col]);
}

// ---------------- feature build (bf16, rows padded to 32 ch = 64B) ----------------
__global__ __launch_bounds__(256) void k_buildx0(const float* __restrict__ h0, const float* __restrict__ coord,
                                                 unsigned short* __restrict__ x0) {
    int i = blockIdx.x * 256 + threadIdx.x;
    if (i >= NN * 32) return;
    int node = i >> 5, k = i & 31;
    float v = 0.f;
    if (k < FF) v = h0[node * FF + k];
    else if (k < K0) v = coord[node * 3 + (k - FF)];
    x0[i] = (unsigned short)f2bfu(v);
}

// ---------------- layer-0 aggregation: 16 edges/wave (4 lanes x 16B per row) ----------------
__global__ __launch_bounds__(256) void k_agg_small(const uint4* __restrict__ x, const int* __restrict__ rp,
                                                   const int* __restrict__ srcs, uint4* __restrict__ y) {
    int w = (blockIdx.x * 256 + threadIdx.x) >> 6;
    int lane = threadIdx.x & 63;
    if (w >= NN) return;
    int e = lane >> 2, q = lane & 3;
    int beg = rp[w], end = rp[w + 1];
    float acc[8];
    {   // self row on e==0 lanes
        if (e == 0) {
            uint4 u = x[(size_t)w * 4 + q];
            acc[0] = bflo(u.x); acc[1] = bfhi(u.x);
            acc[2] = bflo(u.y); acc[3] = bfhi(u.y);
            acc[4] = bflo(u.z); acc[5] = bfhi(u.z);
            acc[6] = bflo(u.w); acc[7] = bfhi(u.w);
        } else {
            #pragma unroll
            for (int j = 0; j < 8; j++) acc[j] = 0.f;
        }
    }
    for (int p = beg; p < end; p += 16) {
        int rem = end - p;
        bool act = e < rem;
        int sn = act ? srcs[p + e] : 0;
        uint4 u = x[(size_t)sn * 4 + q];
        float m = act ? 1.f : 0.f;
        acc[0] = fmaf(m, bflo(u.x), acc[0]); acc[1] = fmaf(m, bfhi(u.x), acc[1]);
        acc[2] = fmaf(m, bflo(u.y), acc[2]); acc[3] = fmaf(m, bfhi(u.y), acc[3]);
        acc[4] = fmaf(m, bflo(u.z), acc[4]); acc[5] = fmaf(m, bfhi(u.z), acc[5]);
        acc[6] = fmaf(m, bflo(u.w), acc[6]); acc[7] = fmaf(m, bfhi(u.w), acc[7]);
    }
    // butterfly over edge-slot dimension (lane bits 2..5)
    #pragma unroll
    for (int mask = 4; mask <= 32; mask <<= 1)
        #pragma unroll
        for (int j = 0; j < 8; j++)
            acc[j] += __shfl_xor(acc[j], mask, 64);
    if (e == 0) {
        uint4 o;
        o.x = f2bfu(acc[0]) | (f2bfu(acc[1]) << 16);
        o.y = f2bfu(acc[2]) | (f2bfu(acc[3]) << 16);
        o.z = f2bfu(acc[4]) | (f2bfu(acc[5]) << 16);
        o.w = f2bfu(acc[6]) | (f2bfu(acc[7]) << 16);
        y[(size_t)w * 4 + q] = o;
    }
}

// bf16 aggregation: x rows are 128 bf16 = 64 uints; lane owns uint 'lane' (2 channels)
__global__ __launch_bounds__(256) void k_agg128_bf(const unsigned* __restrict__ x, const int* __restrict__ rp,
                                                   const int* __restrict__ srcs, unsigned* __restrict__ y) {
    int w = (blockIdx.x * 256 + threadIdx.x) >> 6;
    int lane = threadIdx.x & 63;
    if (w >= NN) return;
    int beg = rp[w], end = rp[w + 1];
    unsigned us = x[(size_t)w * 64 + lane];
    float ax = bflo(us), ay = bfhi(us);
    float bx = 0.f, by = 0.f;
    float cx = 0.f, cy = 0.f;
    float dx = 0.f, dy = 0.f;
    int p = beg;
    for (; p + 16 <= end; p += 16) {
        int s0 = srcs[p + 0], s1 = srcs[p + 1], s2 = srcs[p + 2], s3 = srcs[p + 3];
        int s4 = srcs[p + 4], s5 = srcs[p + 5], s6 = srcs[p + 6], s7 = srcs[p + 7];
        int s8 = srcs[p + 8], s9 = srcs[p + 9], sa = srcs[p + 10], sb = srcs[p + 11];
        int sc_ = srcs[p + 12], sd = srcs[p + 13], se = srcs[p + 14], sf = srcs[p + 15];
        unsigned u0 = x[(size_t)s0 * 64 + lane];
        unsigned u1 = x[(size_t)s1 * 64 + lane];
        unsigned u2 = x[(size_t)s2 * 64 + lane];
        unsigned u3 = x[(size_t)s3 * 64 + lane];
        unsigned u4 = x[(size_t)s4 * 64 + lane];
        unsigned u5 = x[(size_t)s5 * 64 + lane];
        unsigned u6 = x[(size_t)s6 * 64 + lane];
        unsigned u7 = x[(size_t)s7 * 64 + lane];
        unsigned u8 = x[(size_t)s8 * 64 + lane];
        unsigned u9 = x[(size_t)s9 * 64 + lane];
        unsigned ua = x[(size_t)sa * 64 + lane];
        unsigned ub = x[(size_t)sb * 64 + lane];
        unsigned uc = x[(size_t)sc_ * 64 + lane];
        unsigned ud = x[(size_t)sd * 64 + lane];
        unsigned ue = x[(size_t)se * 64 + lane];
        unsigned uf = x[(size_t)sf * 64 + lane];
        ax += (bflo(u0) + bflo(u1)) + (bflo(u2) + bflo(u3));
        ay += (bfhi(u0) + bfhi(u1)) + (bfhi(u2) + bfhi(u3));
        bx += (bflo(u4) + bflo(u5)) + (bflo(u6) + bflo(u7));
        by += (bfhi(u4) + bfhi(u5)) + (bfhi(u6) + bfhi(u7));
        cx += (bflo(u8) + bflo(u9)) + (bflo(ua) + bflo(ub));
        cy += (bfhi(u8) + bfhi(u9)) + (bfhi(ua) + bfhi(ub));
        dx += (bflo(uc) + bflo(ud)) + (bflo(ue) + bflo(uf));
        dy += (bfhi(uc) + bfhi(ud)) + (bfhi(ue) + bfhi(uf));
    }
    for (; p + 8 <= end; p += 8) {
        int s0 = srcs[p + 0], s1 = srcs[p + 1], s2 = srcs[p + 2], s3 = srcs[p + 3];
        int s4 = srcs[p + 4], s5 = srcs[p + 5], s6 = srcs[p + 6], s7 = srcs[p + 7];
        unsigned u0 = x[(size_t)s0 * 64 + lane];
        unsigned u1 = x[(size_t)s1 * 64 + lane];
        unsigned u2 = x[(size_t)s2 * 64 + lane];
        unsigned u3 = x[(size_t)s3 * 64 + lane];
        unsigned u4 = x[(size_t)s4 * 64 + lane];
        unsigned u5 = x[(size_t)s5 * 64 + lane];
        unsigned u6 = x[(size_t)s6 * 64 + lane];
        unsigned u7 = x[(size_t)s7 * 64 + lane];
        ax += (bflo(u0) + bflo(u1)) + (bflo(u2) + bflo(u3));
        ay += (bfhi(u0) + bfhi(u1)) + (bfhi(u2) + bfhi(u3));
        bx += (bflo(u4) + bflo(u5)) + (bflo(u6) + bflo(u7));
        by += (bfhi(u4) + bfhi(u5)) + (bfhi(u6) + bfhi(u7));
    }
    for (; p < end; ++p) {
        unsigned u = x[(size_t)srcs[p] * 64 + lane];
        ax += bflo(u);
        ay += bfhi(u);
    }
    ax += bx + cx + dx;
    ay += by + cy + dy;
    y[(size_t)w * 64 + lane] = f2bfu(ax) | (f2bfu(ay) << 16);
}

// ---------------- GEMM K=19 (fp32 compute, bf16 in [NN][32], bf16 out) ----------------
template<int K, bool STATS>
__global__ __launch_bounds__(256) void k_gemm_small(const unsigned short* __restrict__ in,
        const float* __restrict__ W, const float* __restrict__ bias,
        unsigned short* __restrict__ out, float* __restrict__ part) {
    constexpr int SK = ((K + 3) / 4) * 4 + 4;
    __shared__ __align__(16) float yt[32 * SK];
    __shared__ float red[256];
    int tid = threadIdx.x;
    int row0 = blockIdx.x * 32;
    for (int t = tid; t < 32 * SK; t += 256) {
        int r = t / SK, k = t - r * SK;
        float v = 0.f;
        if (k < K) v = bfu2f(in[(size_t)(row0 + r) * 32 + k]);
        yt[t] = v;
    }
    __syncthreads();
    int col = tid & 127;
    int rg = tid >> 7;
    float acc[16];
    #pragma unroll
    for (int r = 0; r < 16; r++) acc[r] = 0.f;
    const float* ybase = &yt[rg * 16 * SK];
    int kk = 0;
    for (; kk + 4 <= K; kk += 4) {
        float w0 = W[(kk + 0) * HH + col];
        float w1 = W[(kk + 1) * HH + col];
        float w2 = W[(kk + 2) * HH + col];
        float w3 = W[(kk + 3) * HH + col];
        #pragma unroll
        for (int r = 0; r < 16; r++) {
            const float4 v = *(const float4*)&ybase[r * SK + kk];
            acc[r] = fmaf(v.x, w0, acc[r]);
            acc[r] = fmaf(v.y, w1, acc[r]);
            acc[r] = fmaf(v.z, w2, acc[r]);
            acc[r] = fmaf(v.w, w3, acc[r]);
        }
    }
    if constexpr (K % 4 != 0) {
        float w[4];
        #pragma unroll
        for (int j = 0; j < 4; j++) w[j] = (kk + j < K) ? W[(kk + j) * HH + col] : 0.f;
        #pragma unroll
        for (int r = 0; r < 16; r++) {
            const float4 v = *(const float4*)&ybase[r * SK + kk];
            acc[r] = fmaf(v.x, w[0], acc[r]);
            acc[r] = fmaf(v.y, w[1], acc[r]);
            acc[r] = fmaf(v.z, w[2], acc[r]);
            acc[r] = fmaf(v.w, w[3], acc[r]);
        }
    }
    float bcol = bias[col];
    float s = 0.f, s2 = 0.f;
    #pragma unroll
    for (int r = 0; r < 16; r++) {
        float hv = acc[r] + bcol;
        out[(size_t)(row0 + rg * 16 + r) * HH + col] = (unsigned short)f2bfu(hv);
        if (STATS) { s += hv; s2 = fmaf(hv, hv, s2); }
    }
    if (STATS) {
        red[tid] = s; __syncthreads();
        if (tid < 128) part[(size_t)blockIdx.x * 256 + tid] = s + red[tid + 128];
        __syncthreads();
        red[tid] = s2; __syncthreads();
        if (tid < 128) part[(size_t)blockIdx.x * 256 + 128 + tid] = s2 + red[tid + 128];
    }
}

// ---------------- K=128 GEMM via bf16 MFMA: 64 rows x 128 cols per block ----------------
template<bool STATS, bool BNIN, bool ELUOUT>
__global__ __launch_bounds__(256) void k_gemm_mfma(const unsigned short* __restrict__ in,
        const short* __restrict__ WT, const float* __restrict__ bias,
        const float* __restrict__ bnscale, const float* __restrict__ bnshift,
        unsigned short* __restrict__ out, float* __restrict__ part) {
    __shared__ __align__(16) short Al[64 * 136];
    __shared__ float lsum[HH], lsq[HH];
    int tid = threadIdx.x;
    int row0 = blockIdx.x * 64;
    if (STATS && tid < HH) { lsum[tid] = 0.f; lsq[tid] = 0.f; }
    {
        int r = tid >> 2;
        int k0 = (tid & 3) * 32;
        int grow = row0 + r;
        short* dst = &Al[r * 136 + k0];
        if (grow < NN) {
            const uint4* s4 = (const uint4*)(in + (size_t)grow * HH + k0);
            if constexpr (!BNIN) {
                uint4* d4 = (uint4*)dst;
                d4[0] = s4[0]; d4[1] = s4[1]; d4[2] = s4[2]; d4[3] = s4[3];
            } else {
                unsigned* d = (unsigned*)dst;
                #pragma unroll
                for (int q = 0; q < 4; q++) {
                    uint4 u = s4[q];
                    float4 sc0 = *(const float4*)(bnscale + k0 + q * 8);
                    float4 sh0 = *(const float4*)(bnshift + k0 + q * 8);
                    float4 sc1 = *(const float4*)(bnscale + k0 + q * 8 + 4);
                    float4 sh1 = *(const float4*)(bnshift + k0 + q * 8 + 4);
                    float a0 = bflo(u.x), a1 = bfhi(u.x);
                    float a2 = bflo(u.y), a3 = bfhi(u.y);
                    float a4 = bflo(u.z), a5 = bfhi(u.z);
                    float a6 = bflo(u.w), a7 = bfhi(u.w);
                    a0 = fmaxf(fmaf(a0, sc0.x, sh0.x), 0.f);
                    a1 = fmaxf(fmaf(a1, sc0.y, sh0.y), 0.f);
                    a2 = fmaxf(fmaf(a2, sc0.z, sh0.z), 0.f);
                    a3 = fmaxf(fmaf(a3, sc0.w, sh0.w), 0.f);
                    a4 = fmaxf(fmaf(a4, sc1.x, sh1.x), 0.f);
                    a5 = fmaxf(fmaf(a5, sc1.y, sh1.y), 0.f);
                    a6 = fmaxf(fmaf(a6, sc1.z, sh1.z), 0.f);
                    a7 = fmaxf(fmaf(a7, sc1.w, sh1.w), 0.f);
                    d[q * 4 + 0] = f2bfu(a0) | (f2bfu(a1) << 16);
                    d[q * 4 + 1] = f2bfu(a2) | (f2bfu(a3) << 16);
                    d[q * 4 + 2] = f2bfu(a4) | (f2bfu(a5) << 16);
                    d[q * 4 + 3] = f2bfu(a6) | (f2bfu(a7) << 16);
                }
            }
        } else {
            uint4 z = {0, 0, 0, 0};
            uint4* d4 = (uint4*)dst;
            d4[0] = z; d4[1] = z; d4[2] = z; d4[3] = z;
        }
    }
    __syncthreads();
    int wave = tid >> 6;
    int lane = tid & 63;
    int ln = lane & 15, quad = lane >> 4;
    int wcol0 = wave * 32;
    f32x4 acc[4][2];
    #pragma unroll
    for (int rt = 0; rt < 4; rt++)
        #pragma unroll
        for (int ct = 0; ct < 2; ct++) acc[rt][ct] = (f32x4){0.f, 0.f, 0.f, 0.f};
    #pragma unroll
    for (int ks = 0; ks < 4; ks++) {
        bf16x8 a[4], b[2];
        #pragma unroll
        for (int ct = 0; ct < 2; ct++)
            b[ct] = *(const bf16x8*)(WT + (size_t)(wcol0 + ct * 16 + ln) * HH + ks * 32 + quad * 8);
        #pragma unroll
        for (int rt = 0; rt < 4; rt++)
            a[rt] = *(const bf16x8*)(&Al[(rt * 16 + ln) * 136 + ks * 32 + quad * 8]);
        #pragma unroll
        for (int rt = 0; rt < 4; rt++)
            #pragma unroll
            for (int ct = 0; ct < 2; ct++)
                acc[rt][ct] = __builtin_amdgcn_mfma_f32_16x16x32_bf16(a[rt], b[ct], acc[rt][ct], 0, 0, 0);
    }
    float b0 = bias[wcol0 + ln];
    float b1 = bias[wcol0 + 16 + ln];
    float s[2] = {0.f, 0.f}, s2[2] = {0.f, 0.f};
    #pragma unroll
    for (int rt = 0; rt < 4; rt++) {
        #pragma unroll
        for (int r = 0; r < 4; r++) {
            int grow = row0 + rt * 16 + quad * 4 + r;
            if (grow < NN) {
                float hv0 = acc[rt][0][r] + b0;
                float hv1 = acc[rt][1][r] + b1;
                if (ELUOUT) { hv0 = elu01f(hv0); hv1 = elu01f(hv1); }
                out[(size_t)grow * HH + wcol0 + ln] = (unsigned short)f2bfu(hv0);
                out[(size_t)grow * HH + wcol0 + 16 + ln] = (unsigned short)f2bfu(hv1);
                if (STATS) {
                    s[0] += hv0; s2[0] = fmaf(hv0, hv0, s2[0]);
                    s[1] += hv1; s2[1] = fmaf(hv1, hv1, s2[1]);
                }
            }
        }
    }
    if (STATS) {
        atomicAdd(&lsum[wcol0 + ln], s[0]);
        atomicAdd(&lsum[wcol0 + 16 + ln], s[1]);
        atomicAdd(&lsq[wcol0 + ln], s2[0]);
        atomicAdd(&lsq[wcol0 + 16 + ln], s2[1]);
        __syncthreads();
        if (tid < HH) {
            part[(size_t)blockIdx.x * 256 + tid] = lsum[tid];
            part[(size_t)blockIdx.x * 256 + 128 + tid] = lsq[tid];
        }
    }
}

// stage-1 stat reduce: 64 blocks fold nrows partial rows -> part2[64][256]
__global__ __launch_bounds__(256) void k_statred(const float* __restrict__ part, float* __restrict__ part2,
                                                 int nrows) {
    int tid = threadIdx.x;
    float acc = 0.f;
    for (int r = blockIdx.x; r < nrows; r += 64)
        acc += part[(size_t)r * 256 + tid];
    part2[(size_t)blockIdx.x * 256 + tid] = acc;
}

__global__ void k_bnfin(const float* __restrict__ part2, const float* __restrict__ gm,
                        const float* __restrict__ bt, float* scale, float* shift) {
    int c = threadIdx.x;
    float s = 0.f, s2 = 0.f;
    #pragma unroll 4
    for (int j = 0; j < 64; ++j) {
        s += part2[(size_t)j * 256 + c];
        s2 += part2[(size_t)j * 256 + 128 + c];
    }
    float mu = s * (1.f / NN);
    float var = fmaxf(s2 * (1.f / NN) - mu * mu, 0.f);
    float a = gm[c] * rsqrtf(var + BN_EPS);
    scale[c] = a;
    shift[c] = fmaf(-mu, a, bt[c]);
}

// ---------------- pooling (bf16 input) ----------------
__global__ __launch_bounds__(128) void k_pool_part(const unsigned short* __restrict__ x,
                                                   const int* __restrict__ gptr,
                                                   float* __restrict__ psum, float* __restrict__ pmax) {
    int g = blockIdx.x >> 4;
    int ch = blockIdx.x & 15;
    int s = gptr[g], e = gptr[g + 1];
    int len = e - s;
    int per = (len + PCH - 1) / PCH;
    int lo = s + ch * per;
    int hi = min(lo + per, e);
    int c = threadIdx.x;
    float sm = 0.f, mx = -INFINITY;
    for (int i = lo; i < hi; ++i) {
        float v = bfu2f(x[(size_t)i * HH + c]);
        sm += v; mx = fmaxf(mx, v);
    }
    psum[(size_t)blockIdx.x * HH + c] = sm;
    pmax[(size_t)blockIdx.x * HH + c] = mx;
}

// pool finalize + classifier layer 1 fused (one block per graph)
__global__ __launch_bounds__(128) void k_pool_cls1(const float* __restrict__ psum, const float* __restrict__ pmax,
                                                   const int* __restrict__ gptr, const float* __restrict__ g0,
                                                   const float* __restrict__ cw1, const float* __restrict__ cb1,
                                                   float* __restrict__ z1) {
    __shared__ float zr[264];
    int g = blockIdx.x, c = threadIdx.x;
    float sm = 0.f, mx = -INFINITY;
    for (int ch = 0; ch < PCH; ++ch) {
        sm += psum[(size_t)(g * PCH + ch) * HH + c];
        mx = fmaxf(mx, pmax[(size_t)(g * PCH + ch) * HH + c]);
    }
    int cntn = gptr[g + 1] - gptr[g];
    zr[c] = sm / (float)max(cntn, 1);
    zr[128 + c] = mx;
    if (c < GG) zr[256 + c] = g0[g * GG + c];
    __syncthreads();
    float acc = cb1[c];
    for (int k = 0; k < 264; ++k) acc = fmaf(zr[k], cw1[k * HH + c], acc);
    z1[g * HH + c] = elu01f(acc);
}

__global__ __launch_bounds__(128) void k_cls2(const float* __restrict__ z1, const float* __restrict__ cgm,
                                              const float* __restrict__ cbt, const float* __restrict__ cw2,
                                              const float* __restrict__ cb2, float* __restrict__ outp) {
    __shared__ float zn[HH * 65];
    int c = threadIdx.x;
    float s = 0.f, s2 = 0.f;
    for (int g = 0; g < BB; ++g) {
        float v = z1[g * HH + c];
        s += v; s2 = fmaf(v, v, s2);
    }
    float mu = s * (1.f / BB);
    float var = fmaxf(s2 * (1.f / BB) - mu * mu, 0.f);
    float a = cgm[c] * rsqrtf(var + BN_EPS);
    float sh = fmaf(-mu, a, cbt[c]);
    for (int g = 0; g < BB; ++g) zn[c * 65 + g] = fmaf(z1[g * HH + c], a, sh);
    __syncthreads();
    if (c < BB) {
        float l0 = cb2[0], l1 = cb2[1];
        for (int k = 0; k < HH; ++k) {
            float v = zn[k * 65 + c];
            l0 = fmaf(v, cw2[k * 2 + 0], l0);
            l1 = fmaf(v, cw2[k * 2 + 1], l1);
        }
        float m = fmaxf(l0, l1);
        float e0 = __expf(l0 - m), e1 = __expf(l1 - m);
        float inv = 1.f / (e0 + e1);
        outp[c * 2 + 0] = e0 * inv;
        outp[c * 2 + 1] = e1 * inv;
    }
}

extern "C" void kernel_launch(void* const* d_in, const int* in_sizes, int n_in,
                              void* d_out, int out_size, void* d_ws, size_t ws_size,
                              hipStream_t stream) {
    (void)in_sizes; (void)n_in; (void)out_size; (void)ws_size;
    const float* h0     = (const float*)d_in[0];
    const float* coord0 = (const float*)d_in[1];
    const float* g0     = (const float*)d_in[2];
    const int*   eidx   = (const int*)d_in[3];
    const int*   batch  = (const int*)d_in[4];
    const float* w1_0   = (const float*)d_in[5];
    const float* b1_0   = (const float*)d_in[6];
    const float* gm_0   = (const float*)d_in[7];
    const float* bt_0   = (const float*)d_in[8];
    const float* w2_0   = (const float*)d_in[9];
    const float* b2_0   = (const float*)d_in[10];
    const float* w1_r   = (const float*)d_in[11];
    const float* b1_r   = (const float*)d_in[12];
    const float* gm_r   = (const float*)d_in[13];
    const float* bt_r   = (const float*)d_in[14];
    const float* w2_r   = (const float*)d_in[15];
    const float* b2_r   = (const float*)d_in[16];
    const float* cw1    = (const float*)d_in[17];
    const float* cb1    = (const float*)d_in[18];
    const float* cgm    = (const float*)d_in[19];
    const float* cbt    = (const float*)d_in[20];
    const float* cw2    = (const float*)d_in[21];
    const float* cb2    = (const float*)d_in[22];
    float* outp = (float*)d_out;

    const int* esrc = eidx;
    const int* edst = eidx + EE;

    char* p = (char*)d_ws;
    auto alloc = [&](size_t bytes) { void* r = (void*)p; p += (bytes + 255) & ~(size_t)255; return r; };
    unsigned short* x0bf     = (unsigned short*)alloc((size_t)NN * 32 * 2);   // [NN][32] bf16
    unsigned short* y19bf    = (unsigned short*)alloc((size_t)NN * 32 * 2);
    unsigned short* hbf      = (unsigned short*)alloc((size_t)NN * HH * 2);
    unsigned*       xbf      = (unsigned*)alloc((size_t)NN * 64 * 4);
    unsigned*       ybf      = (unsigned*)alloc((size_t)NN * 64 * 4);
    int*            rp       = (int*)alloc((size_t)(NN + 1) * 4);
    int*            srcs     = (int*)alloc((size_t)EE * 4);
    int*            bincnt   = (int*)alloc((size_t)NBINS * 4);
    int*            binstart = (int*)alloc((size_t)NBINS * 4);
    int*            gptr     = (int*)alloc((BB + 1) * 4);
    short*          wt       = (short*)alloc((size_t)5 * HH * HH * 2);
    float*          part     = (float*)alloc((size_t)3125 * 256 * 4);
    float*          part2    = (float*)alloc((size_t)64 * 256 * 4);
    float*          bnscale  = (float*)alloc(HH * 4);
    float*          bnshift  = (float*)alloc(HH * 4);
    float*          psum     = (float*)alloc((size_t)BB * PCH * HH * 4);
    float*          pmax     = (float*)alloc((size_t)BB * PCH * HH * 4);
    float*          z1b      = (float*)alloc((size_t)BB * HH * 4);
    uint2*          binbuf   = (uint2*)alloc((size_t)NBINS * BCAP * 8);   // 25.7 MB, own region

    const int NB_A = (EE + ACH - 1) / ACH;          // 782
    const int NB_AGG = (NN * 64 + 255) / 256;       // 25000
    const int NB_G32 = NN / 32;                     // 3125
    const int NB_G64 = (NN + 63) / 64;              // 1563
    const int NB_X0 = (NN * 32 + 255) / 256;        // 12500
    const int NB_WP = (5 * HH * HH + 255) / 256;    // 320

    // CSR build (LDS counting sort) + weight prep
    hipMemsetAsync(bincnt, 0, (size_t)NBINS * 4, stream);
    k_binA<<<NB_A, 256, 0, stream>>>(esrc, edst, bincnt, binbuf);
    k_binscan<<<1, 512, 0, stream>>>(bincnt, binstart, rp, batch, gptr);
    k_binB<<<NBINS, 256, 0, stream>>>(binbuf, bincnt, binstart, rp, srcs);
    k_wprep<<<NB_WP, 256, 0, stream>>>(w2_0, w1_r, w2_r, wt);

    // layer 0 (bf16 19-dim path, fp32 accumulate)
    k_buildx0<<<NB_X0, 256, 0, stream>>>(h0, coord0, x0bf);
    k_agg_small<<<NB_AGG, 256, 0, stream>>>((const uint4*)x0bf, rp, srcs, (uint4*)y19bf);
    k_gemm_small<K0, true><<<NB_G32, 256, 0, stream>>>(y19bf, w1_0, b1_0, hbf, part);
    k_statred<<<64, 256, 0, stream>>>(part, part2, NB_G32);
    k_bnfin<<<1, 128, 0, stream>>>(part2, gm_0, bt_0, bnscale, bnshift);
    k_gemm_mfma<false, true, true><<<NB_G64, 256, 0, stream>>>(hbf, wt, b2_0, bnscale, bnshift,
                                                               (unsigned short*)xbf, nullptr);

    // layers 1..2 (bf16 activations + bf16 hidden)
    for (int i = 0; i < 2; ++i) {
        k_agg128_bf<<<NB_AGG, 256, 0, stream>>>(xbf, rp, srcs, ybf);
        k_gemm_mfma<true, false, false><<<NB_G64, 256, 0, stream>>>((const unsigned short*)ybf,
                wt + (size_t)(1 + i) * HH * HH, b1_r + i * HH, nullptr, nullptr, hbf, part);
        k_statred<<<64, 256, 0, stream>>>(part, part2, NB_G64);
        k_bnfin<<<1, 128, 0, stream>>>(part2, gm_r + i * HH, bt_r + i * HH, bnscale, bnshift);
        k_gemm_mfma<false, true, true><<<NB_G64, 256, 0, stream>>>(hbf,
                wt + (size_t)(3 + i) * HH * HH, b2_r + i * HH, bnscale, bnshift,
                (unsigned short*)xbf, nullptr);
    }

    // pooling + classifier
    k_pool_part<<<BB * PCH, 128, 0, stream>>>((const unsigned short*)xbf, gptr, psum, pmax);
    k_pool_cls1<<<BB, 128, 0, stream>>>(psum, pmax, gptr, g0, cw1, cb1, z1b);
    k_cls2<<<1, 128, 0, stream>>>(z1b, cgm, cbt, cw2, cb2, outp);
}